// Round 10
// baseline (241.779 us; speedup 1.0000x reference)
//
#include <hip/hip_runtime.h>

namespace {
constexpr int kNDrug = 50000;
constexpr int kNDis  = 50000;
constexpr int kE     = 800000;
constexpr int kR     = 2;
constexpr int kIn    = 2048;   // IN_UNITS
constexpr int kMsg   = 32;     // AGG_UNITS / 3
constexpr int kAgg   = 96;     // AGG_UNITS
constexpr int kOut   = 64;     // OUT_UNITS
constexpr int kBasis = 4;
constexpr float kSlope = 0.1f; // LeakyReLU slope
constexpr int kNTot  = kNDis + kNDrug;            // [0,kNDis)=dis nodes, rest drug nodes
constexpr int kBN    = 102;                       // nodes per bucket -> 981 blocks
constexpr int kNBuck = (kNTot + kBN - 1) / kBN;   // 981
constexpr int kSegCap = 3536;                     // entries/bucket (mean 3264, +4.8 sigma), 16-mult
constexpr int kFifoCap = 37;                      // LDS FIFO depth per bucket in bin_pass
constexpr int kFlushThr = 16;                     // flush unit = 16 entries = 64B; slack 21 -> ovf
                                                  // statistically never (round-7/8 lesson)
constexpr int kBinBlocks = 64;                    // binning blocks (1024 thr each)
constexpr int kOvfCap = 4096;                     // overflow list capacity
constexpr int kNPW   = 13;                        // ceil(kBN/8) nodes per wave in gather
constexpr int kSent  = 16;                        // sentinel pad (covers dual-chain lookahead)
}

// ---------------- one-shot init: W = att@basis, cursors ----------------
__global__ __launch_bounds__(256) void setup_all(const float* __restrict__ att,
                                                 const float* __restrict__ basis,
                                                 float* __restrict__ W,
                                                 int* __restrict__ bcur,
                                                 int* __restrict__ ovfCnt) {
    constexpr int per_r = kIn * kMsg;
    const int blk = blockIdx.x;
    const int t = threadIdx.x;
    if (blk < 512) {                       // W: 2*2048*32 = 131072 elems
        int idx = blk * 256 + t;
        int r = idx / per_r;
        int ic = idx - r * per_r;
        float acc = 0.f;
#pragma unroll
        for (int b = 0; b < kBasis; ++b)
            acc += att[r * kBasis + b] * basis[b * per_r + ic];
        W[idx] = acc;
    } else {                               // blocks 512..515: bcur init; 512/t0: ovfCnt
        int i = (blk - 512) * 256 + t;
        if (i < kNBuck) bcur[i] = i * kSegCap;
        if (blk == 512 && t == 0) *ovfCnt = 0;
    }
}

// ---------------- packed node table: pk[g] = {i0*32, i1*32, i2*32, bits(cj)} ----------------
// One 16B dwordx4 load per entry in the gather replaces 3 fidx loads + 1 cj load.
__global__ __launch_bounds__(256) void pack_nodes(const int* __restrict__ drug_idx,
                                                  const int* __restrict__ dis_idx,
                                                  const float* __restrict__ cj_drug,
                                                  const float* __restrict__ cj_dis,
                                                  uint4* __restrict__ pk_drug,
                                                  uint4* __restrict__ pk_dis) {
    int g = blockIdx.x * 256 + threadIdx.x;
    if (g < kNDrug) {
        pk_drug[g] = make_uint4((unsigned)drug_idx[3 * g] << 5,
                                (unsigned)drug_idx[3 * g + 1] << 5,
                                (unsigned)drug_idx[3 * g + 2] << 5,
                                __float_as_uint(cj_drug[g]));
    }
    if (g < kNDis) {
        pk_dis[g] = make_uint4((unsigned)dis_idx[3 * g] << 5,
                               (unsigned)dis_idx[3 * g + 1] << 5,
                               (unsigned)dis_idx[3 * g + 2] << 5,
                               __float_as_uint(cj_dis[g]));
    }
}

// ---------------- LDS-FIFO binning (64 blocks x 1024 threads) ----------------
// entry = gnode (16b) | rating (bit16) | node-rel-in-bucket (bits 17..23)
__global__ __launch_bounds__(1024) void bin_pass(const int* __restrict__ esrc,
                                                 const int* __restrict__ edst,
                                                 int* __restrict__ bcur,
                                                 unsigned* __restrict__ bin,
                                                 int* __restrict__ ovfCnt,
                                                 unsigned* __restrict__ ovfE,
                                                 int* __restrict__ ovfB) {
    __shared__ unsigned fifo[kNBuck][kFifoCap];  // 145.2 KB
    __shared__ int fcnt[kNBuck];
    __shared__ int flList[kNBuck], flAmt[kNBuck], flPos[kNBuck];
    __shared__ int nFl;

    const int t = threadIdx.x;
    for (int i = t; i < kNBuck; i += 1024) fcnt[i] = 0;

    const int total = kR * kE;
    const int per = (total + kBinBlocks - 1) / kBinBlocks;   // 25000 edges
    const int e0 = blockIdx.x * per;
    const int e1 = (e0 + per < total) ? e0 + per : total;
    __syncthreads();

    auto place = [&](int node, int gn, int r) {
        int bb = node / kBN;
        int rel = node - bb * kBN;
        unsigned ent = (unsigned)gn | ((unsigned)r << 16) | ((unsigned)rel << 17);
        int pos = atomicAdd(&fcnt[bb], 1);
        if (pos < kFifoCap) {
            fifo[bb][pos] = ent;
        } else {  // statistically never (slack 21)
            int s = atomicAdd(ovfCnt, 1);
            if (s < kOvfCap) { ovfE[s] = ent; ovfB[s] = bb; }
        }
    };

    for (int base = e0; base < e1; base += 1024) {
        int idx = base + t;
        if (idx < e1) {
            int r = (idx >= kE) ? 1 : 0;
            int src = esrc[idx], dst = edst[idx];
            place(dst, src, r);            // dis-side entry
            place(kNDis + src, dst, r);    // drug-side entry
        }
        if (t == 0) nFl = 0;
        __syncthreads();
        for (int bb = t; bb < kNBuck; bb += 1024) {
            int c = fcnt[bb]; if (c > kFifoCap) c = kFifoCap;
            if (c >= kFlushThr) {
                int slot = atomicAdd(&nFl, 1);
                flList[slot] = bb;
                flPos[slot] = atomicAdd(&bcur[bb], kFlushThr);   // stays 16-aligned
            }
        }
        __syncthreads();
        {   // 64B-unit copies LDS -> bin (16-lane groups)
            const int n = nFl;
            const int grp = t >> 4, ln = t & 15;
            for (int it = grp; it < n; it += 64) {
                int bb = flList[it], gp = flPos[it];
                int capEnd = bb * kSegCap + kSegCap;
                unsigned ent = fifo[bb][ln];
                int d = gp + ln;
                if (d < capEnd) bin[d] = ent;
                else { int s = atomicAdd(ovfCnt, 1);
                       if (s < kOvfCap) { ovfE[s] = ent; ovfB[s] = bb; } }
            }
        }
        __syncthreads();
        for (int bb = t; bb < kNBuck; bb += 1024) {
            int c = fcnt[bb]; if (c > kFifoCap) c = kFifoCap;
            if (c >= kFlushThr) {
                for (int j = kFlushThr; j < c; ++j) fifo[bb][j - kFlushThr] = fifo[bb][j];
                fcnt[bb] = c - kFlushThr;
            } else {
                fcnt[bb] = c;
            }
        }
        __syncthreads();
    }

    // final drain: partial flushes of the <=kFifoCap-entry tails
    if (t == 0) nFl = 0;
    __syncthreads();
    for (int bb = t; bb < kNBuck; bb += 1024) {
        int c = fcnt[bb]; if (c > kFifoCap) c = kFifoCap;
        if (c) {
            int slot = atomicAdd(&nFl, 1);
            flList[slot] = bb; flAmt[slot] = c;
            flPos[slot] = atomicAdd(&bcur[bb], c);
        }
    }
    __syncthreads();
    const int n = nFl;
    const int grp = t >> 4, ln = t & 15;
    for (int it = grp; it < n; it += 64) {
        int bb = flList[it], f = flAmt[it], gp = flPos[it];
        int capEnd = bb * kSegCap + kSegCap;
        for (int j = ln; j < f; j += 16) {
            unsigned ent = fifo[bb][j];
            int d = gp + j;
            if (d < capEnd) bin[d] = ent;
            else { int s = atomicAdd(ovfCnt, 1);
                   if (s < kOvfCap) { ovfE[s] = ent; ovfB[s] = bb; } }
        }
    }
}

// ---------------- re-insert overflow entries into bin where room remains ----------------
__global__ __launch_bounds__(256) void ovf_drain(int* __restrict__ bcur,
                                                 unsigned* __restrict__ bin,
                                                 const int* __restrict__ ovfCnt,
                                                 const unsigned* __restrict__ ovfE,
                                                 int* __restrict__ ovfB) {
    int n = *ovfCnt; if (n > kOvfCap) n = kOvfCap;
    int i = blockIdx.x * 256 + threadIdx.x;
    if (i >= n) return;
    int bb = ovfB[i];
    int pos = atomicAdd(&bcur[bb], 1);
    if (pos < bb * kSegCap + kSegCap) { bin[pos] = ovfE[i]; ovfB[i] = -1; }
}

// ---- packed dual-chain 4-stage pipeline pieces (stride 4 in sp-index, offsets 0 / 2) ----
#define PK_PRO(sp_, OFS_, e1_, e2_, P1_, c0_, c1_, w00_, w01_, w02_)                    \
  { unsigned e0_ = (sp_)[OFS_]; e1_ = (sp_)[(OFS_) + 4]; e2_ = (sp_)[(OFS_) + 8];       \
    uint4 P0_ = pkp[e0_ & 0xffffu];                                                     \
    c0_ = __uint_as_float(P0_.w);                                                       \
    P1_ = pkp[e1_ & 0xffffu];                                                           \
    c1_ = __uint_as_float(P1_.w);                                                       \
    const float* W0_ = W + (((e0_ >> 16) & 1u) * (unsigned)(kIn * kMsg));               \
    w00_ = W0_[P0_.x + fl]; w01_ = W0_[P0_.y + fl]; w02_ = W0_[P0_.z + fl]; }

#define PK_BODY(sp_, OFS_, tt_, e1_, e2_, P1_, c0_, c1_, w00_, w01_, w02_, a0_, a1_, a2_) \
  { unsigned e3_ = (sp_)[(OFS_) + 4*(tt_) + 12];                                        \
    uint4 P2_ = pkp[e2_ & 0xffffu];                                                     \
    float c2_ = __uint_as_float(P2_.w);                                                 \
    const float* W1_ = W + (((e1_ >> 16) & 1u) * (unsigned)(kIn * kMsg));               \
    float w10_ = W1_[P1_.x + fl];                                                       \
    float w11_ = W1_[P1_.y + fl];                                                       \
    float w12_ = W1_[P1_.z + fl];                                                       \
    a0_ = fmaf(w00_, c0_, a0_); a1_ = fmaf(w01_, c0_, a1_); a2_ = fmaf(w02_, c0_, a2_); \
    e1_ = e2_; e2_ = e3_; P1_ = P2_;                                                    \
    c0_ = c1_; c1_ = c2_; w00_ = w10_; w01_ = w11_; w02_ = w12_; }

// ---------------- pk gather: 4 VMEM/entry instead of 7 ----------------
__global__ __launch_bounds__(512, 6) void gather_pk(
        const unsigned* __restrict__ bin,
        const int* __restrict__ bcur,
        const int* __restrict__ ovfCnt,
        const unsigned* __restrict__ ovfE,
        const int* __restrict__ ovfB,
        const float* __restrict__ W,
        const uint4* __restrict__ pk_drug, const uint4* __restrict__ pk_dis,
        const float* __restrict__ ci_drug, const float* __restrict__ ci_dis,
        const float* __restrict__ w_fc, const float* __restrict__ b_fc,
        float* __restrict__ out) {
    __shared__ float ws[kAgg * kOut];              // 24 KB
    __shared__ float bs[kOut];
    __shared__ unsigned stage[kSegCap + kSent];    // 13.9 KB
    __shared__ int h[kBN], lb[kBN];
    __shared__ int sbuf[kBN];
    __shared__ int sOvf;

    const int t = threadIdx.x;
    const int b = blockIdx.x;
    for (int i = t; i < kAgg * kOut; i += 512) ws[i] = w_fc[i];
    if (t < kOut) bs[t] = b_fc[t];
    if (t < kBN) h[t] = 0;
    if (t == 0) sOvf = (ovfCnt[0] < kOvfCap) ? ovfCnt[0] : kOvfCap;

    const int sb = b * kSegCap;
    __syncthreads();
    int seg = bcur[b] - sb;
    if (seg > kSegCap) seg = kSegCap;

    for (int i = t; i < seg; i += 512)
        atomicAdd(&h[bin[sb + i] >> 17], 1);
    __syncthreads();
    if (t < kBN) sbuf[t] = h[t];
    __syncthreads();
    for (int o = 1; o < kBN; o <<= 1) {
        int x = 0;
        if (t < kBN && t >= o) x = sbuf[t - o];
        __syncthreads();
        if (t < kBN) sbuf[t] += x;
        __syncthreads();
    }
    if (t < kBN) { int ex = sbuf[t] - h[t]; lb[t] = ex; sbuf[t] = ex; }
    if (t < kSent) stage[seg + t] = 0;   // sentinel entries (loaded, never FMA'd)
    __syncthreads();
    for (int i = t; i < seg; i += 512) {
        unsigned e = bin[sb + i];
        int pos = atomicAdd(&sbuf[e >> 17], 1);
        stage[pos] = e;
    }
    __syncthreads();

    const int wid  = t >> 6;
    const int lane = t & 63;
    const int half = lane >> 5;
    const int fl   = lane & 31;

    for (int i = 0; i < kNPW; ++i) {
        const int nl = wid * kNPW + i;
        if (nl >= kBN) break;    // wave-uniform
        const int g  = b * kBN + nl;
        if (g >= kNTot) break;   // wave-uniform; no block syncs below

        const uint4* pkp;
        float civ;
        size_t orow;
        if (g < kNDis) {         // dis dst node: gathers DRUG feats
            pkp = pk_drug; civ = ci_dis[g];
            orow = (size_t)(kNDrug + g);
        } else {                 // drug dst node: gathers DIS feats
            pkp = pk_dis;  civ = ci_drug[g - kNDis];
            orow = (size_t)(g - kNDis);
        }

        const int base = lb[nl];
        const int deg  = h[nl];
        const unsigned* sp = stage + base + half;
        const int n  = (deg - half + 1) >> 1;   // this half's entry count
        const int nA = (n + 1) >> 1;            // chain A: half-entries 0,2,4,..
        const int nB = n >> 1;                  // chain B: half-entries 1,3,5,..

        float a0A = 0.f, a1A = 0.f, a2A = 0.f;
        float a0B = 0.f, a1B = 0.f, a2B = 0.f;
        unsigned eA1, eA2, eB1, eB2;
        uint4 PA1, PB1;
        float cA0, cA1, cB0, cB1;
        float wA0, wA1, wA2, wB0, wB1, wB2;

        PK_PRO(sp, 0, eA1, eA2, PA1, cA0, cA1, wA0, wA1, wA2);
        PK_PRO(sp, 2, eB1, eB2, PB1, cB0, cB1, wB0, wB1, wB2);

        int tt = 0;
        for (; tt < nB; ++tt) {
            PK_BODY(sp, 0, tt, eA1, eA2, PA1, cA0, cA1, wA0, wA1, wA2, a0A, a1A, a2A);
            PK_BODY(sp, 2, tt, eB1, eB2, PB1, cB0, cB1, wB0, wB1, wB2, a0B, a1B, a2B);
        }
        if (tt < nA) {
            PK_BODY(sp, 0, tt, eA1, eA2, PA1, cA0, cA1, wA0, wA1, wA2, a0A, a1A, a2A);
        }

        float a0 = a0A + a0B, a1 = a1A + a1B, a2 = a2A + a2B;

        if (sOvf > 0) {          // statistically never non-zero
            for (int j = half; j < sOvf; j += 2) {
                int bb = ovfB[j];
                if (bb == b && (int)(ovfE[j] >> 17) == nl) {
                    unsigned e = ovfE[j];
                    uint4 P = pkp[e & 0xffffu];
                    const float* Wr = W + (((e >> 16) & 1u) * (unsigned)(kIn * kMsg));
                    float c = __uint_as_float(P.w);
                    a0 = fmaf(Wr[P.x + fl], c, a0);
                    a1 = fmaf(Wr[P.y + fl], c, a1);
                    a2 = fmaf(Wr[P.z + fl], c, a2);
                }
            }
        }

        a0 += __shfl_xor(a0, 32);
        a1 += __shfl_xor(a1, 32);
        a2 += __shfl_xor(a2, 32);

        a0 *= civ; a1 *= civ; a2 *= civ;
        a0 = (a0 >= 0.f) ? a0 : kSlope * a0;
        a1 = (a1 >= 0.f) ? a1 : kSlope * a1;
        a2 = (a2 >= 0.f) ? a2 : kSlope * a2;

        float acc = bs[lane];
#pragma unroll
        for (int k = 0; k < 32; ++k)
            acc = fmaf(__shfl(a0, k), ws[k * kOut + lane], acc);
#pragma unroll
        for (int k = 0; k < 32; ++k)
            acc = fmaf(__shfl(a1, k), ws[(32 + k) * kOut + lane], acc);
#pragma unroll
        for (int k = 0; k < 32; ++k)
            acc = fmaf(__shfl(a2, k), ws[(64 + k) * kOut + lane], acc);
        out[orow * kOut + lane] = acc;
    }
}

// ---- round-9 (unpacked) dual-chain pieces, for the mid-tier path ----
#define ACC_PRO(sp_, OFS_, e1_, e2_, i10_, i11_, i12_, c0_, c1_, w00_, w01_, w02_)      \
  { unsigned e0_ = (sp_)[OFS_]; e1_ = (sp_)[(OFS_) + 4]; e2_ = (sp_)[(OFS_) + 8];       \
    int g0_ = (int)(e0_ & 0xffffu);                                                     \
    int j0_ = fidxp[g0_*3], j1_ = fidxp[g0_*3+1], j2_ = fidxp[g0_*3+2];                 \
    c0_ = cjp[g0_];                                                                     \
    int g1_ = (int)(e1_ & 0xffffu);                                                     \
    i10_ = fidxp[g1_*3]; i11_ = fidxp[g1_*3+1]; i12_ = fidxp[g1_*3+2];                  \
    c1_ = cjp[g1_];                                                                     \
    const float* W0_ = W + (((e0_ >> 16) & 1u) * (unsigned)(kIn * kMsg));               \
    w00_ = W0_[(j0_ << 5) + fl]; w01_ = W0_[(j1_ << 5) + fl]; w02_ = W0_[(j2_ << 5) + fl]; }

#define ACC_BODY(sp_, OFS_, tt_, e1_, e2_, i10_, i11_, i12_, c0_, c1_, w00_, w01_, w02_, a0_, a1_, a2_) \
  { unsigned e3_ = (sp_)[(OFS_) + 4*(tt_) + 12];                                        \
    int g2_ = (int)(e2_ & 0xffffu);                                                     \
    int i20_ = fidxp[g2_*3], i21_ = fidxp[g2_*3+1], i22_ = fidxp[g2_*3+2];              \
    float c2_ = cjp[g2_];                                                               \
    const float* W1_ = W + (((e1_ >> 16) & 1u) * (unsigned)(kIn * kMsg));               \
    float w10_ = W1_[(i10_ << 5) + fl];                                                 \
    float w11_ = W1_[(i11_ << 5) + fl];                                                 \
    float w12_ = W1_[(i12_ << 5) + fl];                                                 \
    a0_ = fmaf(w00_, c0_, a0_); a1_ = fmaf(w01_, c0_, a1_); a2_ = fmaf(w02_, c0_, a2_); \
    e1_ = e2_; e2_ = e3_; i10_ = i20_; i11_ = i21_; i12_ = i22_;                        \
    c0_ = c1_; c1_ = c2_; w00_ = w10_; w01_ = w11_; w02_ = w12_; }

__global__ __launch_bounds__(512, 6) void gather_fused(
        const unsigned* __restrict__ bin,
        const int* __restrict__ bcur,
        const int* __restrict__ ovfCnt,
        const unsigned* __restrict__ ovfE,
        const int* __restrict__ ovfB,
        const float* __restrict__ W,
        const int* __restrict__ drug_idx, const int* __restrict__ dis_idx,
        const float* __restrict__ cj_drug, const float* __restrict__ cj_dis,
        const float* __restrict__ ci_drug, const float* __restrict__ ci_dis,
        const float* __restrict__ w_fc, const float* __restrict__ b_fc,
        float* __restrict__ out) {
    __shared__ float ws[kAgg * kOut];
    __shared__ float bs[kOut];
    __shared__ unsigned stage[kSegCap + kSent];
    __shared__ int h[kBN], lb[kBN];
    __shared__ int sbuf[kBN];
    __shared__ int sOvf;

    const int t = threadIdx.x;
    const int b = blockIdx.x;
    for (int i = t; i < kAgg * kOut; i += 512) ws[i] = w_fc[i];
    if (t < kOut) bs[t] = b_fc[t];
    if (t < kBN) h[t] = 0;
    if (t == 0) sOvf = (ovfCnt[0] < kOvfCap) ? ovfCnt[0] : kOvfCap;

    const int sb = b * kSegCap;
    __syncthreads();
    int seg = bcur[b] - sb;
    if (seg > kSegCap) seg = kSegCap;

    for (int i = t; i < seg; i += 512)
        atomicAdd(&h[bin[sb + i] >> 17], 1);
    __syncthreads();
    if (t < kBN) sbuf[t] = h[t];
    __syncthreads();
    for (int o = 1; o < kBN; o <<= 1) {
        int x = 0;
        if (t < kBN && t >= o) x = sbuf[t - o];
        __syncthreads();
        if (t < kBN) sbuf[t] += x;
        __syncthreads();
    }
    if (t < kBN) { int ex = sbuf[t] - h[t]; lb[t] = ex; sbuf[t] = ex; }
    if (t < kSent) stage[seg + t] = 0;
    __syncthreads();
    for (int i = t; i < seg; i += 512) {
        unsigned e = bin[sb + i];
        int pos = atomicAdd(&sbuf[e >> 17], 1);
        stage[pos] = e;
    }
    __syncthreads();

    const int wid  = t >> 6;
    const int lane = t & 63;
    const int half = lane >> 5;
    const int fl   = lane & 31;

    for (int i = 0; i < kNPW; ++i) {
        const int nl = wid * kNPW + i;
        if (nl >= kBN) break;
        const int g  = b * kBN + nl;
        if (g >= kNTot) break;

        const int* fidxp;
        const float* cjp;
        float civ;
        size_t orow;
        if (g < kNDis) {
            fidxp = drug_idx; cjp = cj_drug; civ = ci_dis[g];
            orow = (size_t)(kNDrug + g);
        } else {
            fidxp = dis_idx;  cjp = cj_dis;  civ = ci_drug[g - kNDis];
            orow = (size_t)(g - kNDis);
        }

        const int base = lb[nl];
        const int deg  = h[nl];
        const unsigned* sp = stage + base + half;
        const int n  = (deg - half + 1) >> 1;
        const int nA = (n + 1) >> 1;
        const int nB = n >> 1;

        float a0A = 0.f, a1A = 0.f, a2A = 0.f;
        float a0B = 0.f, a1B = 0.f, a2B = 0.f;
        unsigned eA1, eA2, eB1, eB2;
        int iA0, iA1, iA2, iB0, iB1, iB2;
        float cA0, cA1, cB0, cB1;
        float wA0, wA1, wA2, wB0, wB1, wB2;

        ACC_PRO(sp, 0, eA1, eA2, iA0, iA1, iA2, cA0, cA1, wA0, wA1, wA2);
        ACC_PRO(sp, 2, eB1, eB2, iB0, iB1, iB2, cB0, cB1, wB0, wB1, wB2);

        int tt = 0;
        for (; tt < nB; ++tt) {
            ACC_BODY(sp, 0, tt, eA1, eA2, iA0, iA1, iA2, cA0, cA1, wA0, wA1, wA2,
                     a0A, a1A, a2A);
            ACC_BODY(sp, 2, tt, eB1, eB2, iB0, iB1, iB2, cB0, cB1, wB0, wB1, wB2,
                     a0B, a1B, a2B);
        }
        if (tt < nA) {
            ACC_BODY(sp, 0, tt, eA1, eA2, iA0, iA1, iA2, cA0, cA1, wA0, wA1, wA2,
                     a0A, a1A, a2A);
        }

        float a0 = a0A + a0B, a1 = a1A + a1B, a2 = a2A + a2B;

        if (sOvf > 0) {
            for (int j = half; j < sOvf; j += 2) {
                int bb = ovfB[j];
                if (bb == b && (int)(ovfE[j] >> 17) == nl) {
                    unsigned e = ovfE[j];
                    int gg = (int)(e & 0xffffu);
                    const float* Wr = W + (((e >> 16) & 1u) * (unsigned)(kIn * kMsg));
                    float c = cjp[gg];
                    a0 = fmaf(Wr[(fidxp[gg * 3]     << 5) + fl], c, a0);
                    a1 = fmaf(Wr[(fidxp[gg * 3 + 1] << 5) + fl], c, a1);
                    a2 = fmaf(Wr[(fidxp[gg * 3 + 2] << 5) + fl], c, a2);
                }
            }
        }

        a0 += __shfl_xor(a0, 32);
        a1 += __shfl_xor(a1, 32);
        a2 += __shfl_xor(a2, 32);

        a0 *= civ; a1 *= civ; a2 *= civ;
        a0 = (a0 >= 0.f) ? a0 : kSlope * a0;
        a1 = (a1 >= 0.f) ? a1 : kSlope * a1;
        a2 = (a2 >= 0.f) ? a2 : kSlope * a2;

        float acc = bs[lane];
#pragma unroll
        for (int k = 0; k < 32; ++k)
            acc = fmaf(__shfl(a0, k), ws[k * kOut + lane], acc);
#pragma unroll
        for (int k = 0; k < 32; ++k)
            acc = fmaf(__shfl(a1, k), ws[(32 + k) * kOut + lane], acc);
#pragma unroll
        for (int k = 0; k < 32; ++k)
            acc = fmaf(__shfl(a2, k), ws[(64 + k) * kOut + lane], acc);
        out[orow * kOut + lane] = acc;
    }
}

// ---------------- fallback path (R1 atomic scatter, tiny-ws only) ----------------
__global__ __launch_bounds__(256) void build_W_fb(const float* __restrict__ att,
                                                  const float* __restrict__ basis,
                                                  float* __restrict__ W) {
    constexpr int per_r = kIn * kMsg;
    int idx = blockIdx.x * blockDim.x + threadIdx.x;
    if (idx >= kR * per_r) return;
    int r = idx / per_r;
    int ic = idx - r * per_r;
    float acc = 0.f;
#pragma unroll
    for (int b = 0; b < kBasis; ++b)
        acc += att[r * kBasis + b] * basis[b * per_r + ic];
    W[idx] = acc;
}

__global__ __launch_bounds__(256) void edge_scatter(
        const float* __restrict__ W,
        const int* __restrict__ gnode,
        const int* __restrict__ snode,
        const int* __restrict__ fidx,
        const float* __restrict__ cj,
        float* __restrict__ h) {
    const int r = blockIdx.y;
    long tid = (long)blockIdx.x * blockDim.x + threadIdx.x;
    const int lane = (int)(tid & 31);
    const long e = tid >> 5;
    if (e >= kE) return;
    const int g = gnode[(long)r * kE + e];
    const int s = snode[(long)r * kE + e];
    const int i0 = fidx[g * 3 + 0];
    const int i1 = fidx[g * 3 + 1];
    const int i2 = fidx[g * 3 + 2];
    const float c = cj[g];
    const float* Wr = W + (size_t)r * kIn * kMsg;
    float* outp = h + (size_t)s * kAgg;
    atomicAdd(&outp[lane],            Wr[(size_t)i0 * kMsg + lane] * c);
    atomicAdd(&outp[kMsg + lane],     Wr[(size_t)i1 * kMsg + lane] * c);
    atomicAdd(&outp[2 * kMsg + lane], Wr[(size_t)i2 * kMsg + lane] * c);
}

__global__ __launch_bounds__(256) void fc_fused(const float* __restrict__ h,
                                                const float* __restrict__ ci,
                                                const float* __restrict__ w_fc,
                                                const float* __restrict__ b_fc,
                                                float* __restrict__ out, int nrows) {
    __shared__ float ws[kAgg * kOut];
    __shared__ float bs[kOut];
    const int lt = threadIdx.y * blockDim.x + threadIdx.x;
    for (int i = lt; i < kAgg * kOut; i += blockDim.x * blockDim.y)
        ws[i] = w_fc[i];
    if (lt < kOut) bs[lt] = b_fc[lt];
    __syncthreads();
    const int row = blockIdx.x * blockDim.y + threadIdx.y;
    if (row >= nrows) return;
    const int col = threadIdx.x;
    const float c = ci[row];
    const float* hr = h + (size_t)row * kAgg;
    float acc = bs[col];
#pragma unroll 8
    for (int k = 0; k < kAgg; ++k) {
        float a = hr[k] * c;
        a = (a >= 0.f) ? a : kSlope * a;
        acc += a * ws[k * kOut + col];
    }
    out[(size_t)row * kOut + col] = acc;
}

extern "C" void kernel_launch(void* const* d_in, const int* in_sizes, int n_in,
                              void* d_out, int out_size, void* d_ws, size_t ws_size,
                              hipStream_t stream) {
    const int*   drug_idx = (const int*)d_in[0];
    const int*   dis_idx  = (const int*)d_in[1];
    const int*   edge_src = (const int*)d_in[2];
    const int*   edge_dst = (const int*)d_in[3];
    const float* cj_drug  = (const float*)d_in[4];
    const float* ci_drug  = (const float*)d_in[5];
    const float* cj_dis   = (const float*)d_in[6];
    const float* ci_dis   = (const float*)d_in[7];
    const float* att      = (const float*)d_in[8];
    const float* basis    = (const float*)d_in[9];
    const float* w_fc     = (const float*)d_in[10];
    const float* b_fc     = (const float*)d_in[11];
    float* out = (float*)d_out;

    auto align256 = [](size_t x) { return (x + 255) & ~(size_t)255; };
    const size_t Wb    = align256((size_t)kR * kIn * kMsg * sizeof(float));     // 512 KB
    const size_t pkB   = align256((size_t)kNDrug * sizeof(uint4));              // 800 KB each
    const size_t bcB   = align256((size_t)kNBuck * sizeof(int));
    const size_t ocB   = align256(sizeof(int));
    const size_t oeB   = align256((size_t)kOvfCap * sizeof(unsigned));          // 16 KB
    const size_t obB   = align256((size_t)kOvfCap * sizeof(int));               // 16 KB
    const size_t binB  = align256((size_t)kNBuck * kSegCap * sizeof(unsigned)); // ~13.88 MB
    const size_t needBase = Wb + bcB + ocB + oeB + obB + binB;                  // ~14.44 MB
    const size_t needPk   = needBase + 2 * pkB;                                 // ~16.04 MB

    if (ws_size >= needBase) {
        const bool usePk = (ws_size >= needPk);
        char* p = (char*)d_ws;
        float*    W       = (float*)p;     p += Wb;
        uint4*    pk_drug = nullptr;
        uint4*    pk_dis  = nullptr;
        if (usePk) { pk_drug = (uint4*)p;  p += pkB;
                     pk_dis  = (uint4*)p;  p += pkB; }
        int*      bcur   = (int*)p;        p += bcB;
        int*      ovfCnt = (int*)p;        p += ocB;
        unsigned* ovfE   = (unsigned*)p;   p += oeB;
        int*      ovfB   = (int*)p;        p += obB;
        unsigned* bin    = (unsigned*)p;

        setup_all<<<dim3(516), 256, 0, stream>>>(att, basis, W, bcur, ovfCnt);
        if (usePk)
            pack_nodes<<<dim3((kNDrug + 255) / 256), 256, 0, stream>>>(
                drug_idx, dis_idx, cj_drug, cj_dis, pk_drug, pk_dis);
        bin_pass<<<dim3(kBinBlocks), 1024, 0, stream>>>(edge_src, edge_dst,
                                                        bcur, bin, ovfCnt, ovfE, ovfB);
        ovf_drain<<<dim3((kOvfCap + 255) / 256), 256, 0, stream>>>(bcur, bin,
                                                                   ovfCnt, ovfE, ovfB);
        if (usePk)
            gather_pk<<<dim3(kNBuck), 512, 0, stream>>>(bin, bcur, ovfCnt, ovfE, ovfB,
                                                        W, pk_drug, pk_dis,
                                                        ci_drug, ci_dis,
                                                        w_fc, b_fc, out);
        else
            gather_fused<<<dim3(kNBuck), 512, 0, stream>>>(bin, bcur, ovfCnt, ovfE, ovfB,
                                                           W, drug_idx, dis_idx,
                                                           cj_drug, cj_dis,
                                                           ci_drug, ci_dis,
                                                           w_fc, b_fc, out);
    } else {
        // fallback: R1 phased atomic-scatter path
        char* p = (char*)d_ws;
        float* W = (float*)p;
        build_W_fb<<<dim3((kR * kIn * kMsg + 255) / 256), 256, 0, stream>>>(att, basis, W);
        const size_t hB = (size_t)kNDrug * kAgg * sizeof(float);
        float* h = (float*)((char*)d_ws + Wb);
        const int scat_blocks = (int)(((long)kE * 32 + 255) / 256);
        const dim3 scat_grid(scat_blocks, kR);
        hipMemsetAsync(h, 0, hB, stream);
        edge_scatter<<<scat_grid, 256, 0, stream>>>(W, edge_dst, edge_src,
                                                    dis_idx, cj_dis, h);
        fc_fused<<<dim3((kNDrug + 3) / 4), dim3(64, 4), 0, stream>>>(
            h, ci_drug, w_fc, b_fc, out, kNDrug);
        hipMemsetAsync(h, 0, hB, stream);
        edge_scatter<<<scat_grid, 256, 0, stream>>>(W, edge_src, edge_dst,
                                                    drug_idx, cj_drug, h);
        fc_fused<<<dim3((kNDis + 3) / 4), dim3(64, 4), 0, stream>>>(
            h, ci_dis, w_fc, b_fc, out + (size_t)kNDrug * kOut, kNDis);
    }
}

// Round 11
// 221.780 us; speedup vs baseline: 1.0902x; 1.0902x over previous
//
#include <hip/hip_runtime.h>

namespace {
constexpr int kNDrug = 50000;
constexpr int kNDis  = 50000;
constexpr int kE     = 800000;
constexpr int kR     = 2;
constexpr int kIn    = 2048;   // IN_UNITS
constexpr int kMsg   = 32;     // AGG_UNITS / 3
constexpr int kAgg   = 96;     // AGG_UNITS
constexpr int kOut   = 64;     // OUT_UNITS
constexpr int kBasis = 4;
constexpr float kSlope = 0.1f; // LeakyReLU slope
constexpr int kNTot  = kNDis + kNDrug;            // [0,kNDis)=dis nodes, rest drug nodes
constexpr int kBN    = 102;                       // nodes per bucket -> 981 blocks
constexpr int kNBuck = (kNTot + kBN - 1) / kBN;   // 981
constexpr int kSegCap = 3536;                     // entries/bucket (mean 3264, +4.8 sigma), 16-mult
constexpr int kFifoCap = 37;                      // LDS FIFO depth per bucket in bin_pass
constexpr int kFlushThr = 16;                     // flush unit = 16 entries = 64B; slack 21 -> ovf
                                                  // statistically never (round-7/8 lesson)
constexpr int kBinBlocks = 128;                   // binning blocks (1024 thr each; 12.5K edges ea)
constexpr int kOvfCap = 4096;                     // overflow list capacity
constexpr int kNPW   = 13;                        // ceil(kBN/8) nodes per wave in gather
constexpr int kSent  = 20;                        // sentinel pad (covers 5-stage dual-chain lookahead)
}

// ---------------- one-shot init: W = att@basis, cursors ----------------
__global__ __launch_bounds__(256) void setup_all(const float* __restrict__ att,
                                                 const float* __restrict__ basis,
                                                 float* __restrict__ W,
                                                 int* __restrict__ bcur,
                                                 int* __restrict__ ovfCnt) {
    constexpr int per_r = kIn * kMsg;
    const int blk = blockIdx.x;
    const int t = threadIdx.x;
    if (blk < 512) {                       // W: 2*2048*32 = 131072 elems
        int idx = blk * 256 + t;
        int r = idx / per_r;
        int ic = idx - r * per_r;
        float acc = 0.f;
#pragma unroll
        for (int b = 0; b < kBasis; ++b)
            acc += att[r * kBasis + b] * basis[b * per_r + ic];
        W[idx] = acc;
    } else {                               // blocks 512..515: bcur init; 512/t0: ovfCnt
        int i = (blk - 512) * 256 + t;
        if (i < kNBuck) bcur[i] = i * kSegCap;
        if (blk == 512 && t == 0) *ovfCnt = 0;
    }
}

// ---------------- packed node table: pk[g] = {i0*32, i1*32, i2*32, bits(cj)} ----------------
__global__ __launch_bounds__(256) void pack_nodes(const int* __restrict__ drug_idx,
                                                  const int* __restrict__ dis_idx,
                                                  const float* __restrict__ cj_drug,
                                                  const float* __restrict__ cj_dis,
                                                  uint4* __restrict__ pk_drug,
                                                  uint4* __restrict__ pk_dis) {
    int g = blockIdx.x * 256 + threadIdx.x;
    if (g < kNDrug) {
        pk_drug[g] = make_uint4((unsigned)drug_idx[3 * g] << 5,
                                (unsigned)drug_idx[3 * g + 1] << 5,
                                (unsigned)drug_idx[3 * g + 2] << 5,
                                __float_as_uint(cj_drug[g]));
    }
    if (g < kNDis) {
        pk_dis[g] = make_uint4((unsigned)dis_idx[3 * g] << 5,
                               (unsigned)dis_idx[3 * g + 1] << 5,
                               (unsigned)dis_idx[3 * g + 2] << 5,
                               __float_as_uint(cj_dis[g]));
    }
}

// ---------------- LDS-FIFO binning (128 blocks x 1024 threads) ----------------
// entry = gnode (16b) | rating (bit16) | node-rel-in-bucket (bits 17..23)
__global__ __launch_bounds__(1024) void bin_pass(const int* __restrict__ esrc,
                                                 const int* __restrict__ edst,
                                                 int* __restrict__ bcur,
                                                 unsigned* __restrict__ bin,
                                                 int* __restrict__ ovfCnt,
                                                 unsigned* __restrict__ ovfE,
                                                 int* __restrict__ ovfB) {
    __shared__ unsigned fifo[kNBuck][kFifoCap];  // 145.2 KB
    __shared__ int fcnt[kNBuck];
    __shared__ int flList[kNBuck], flAmt[kNBuck], flPos[kNBuck];
    __shared__ int nFl;

    const int t = threadIdx.x;
    for (int i = t; i < kNBuck; i += 1024) fcnt[i] = 0;

    const int total = kR * kE;
    const int per = (total + kBinBlocks - 1) / kBinBlocks;   // 12500 edges
    const int e0 = blockIdx.x * per;
    const int e1 = (e0 + per < total) ? e0 + per : total;
    __syncthreads();

    auto place = [&](int node, int gn, int r) {
        int bb = node / kBN;
        int rel = node - bb * kBN;
        unsigned ent = (unsigned)gn | ((unsigned)r << 16) | ((unsigned)rel << 17);
        int pos = atomicAdd(&fcnt[bb], 1);
        if (pos < kFifoCap) {
            fifo[bb][pos] = ent;
        } else {  // statistically never (slack 21)
            int s = atomicAdd(ovfCnt, 1);
            if (s < kOvfCap) { ovfE[s] = ent; ovfB[s] = bb; }
        }
    };

    for (int base = e0; base < e1; base += 1024) {
        int idx = base + t;
        if (idx < e1) {
            int r = (idx >= kE) ? 1 : 0;
            int src = esrc[idx], dst = edst[idx];
            place(dst, src, r);            // dis-side entry
            place(kNDis + src, dst, r);    // drug-side entry
        }
        if (t == 0) nFl = 0;
        __syncthreads();
        for (int bb = t; bb < kNBuck; bb += 1024) {
            int c = fcnt[bb]; if (c > kFifoCap) c = kFifoCap;
            if (c >= kFlushThr) {
                int slot = atomicAdd(&nFl, 1);
                flList[slot] = bb;
                flPos[slot] = atomicAdd(&bcur[bb], kFlushThr);   // stays 16-aligned
            }
        }
        __syncthreads();
        {   // 64B-unit copies LDS -> bin (16-lane groups)
            const int n = nFl;
            const int grp = t >> 4, ln = t & 15;
            for (int it = grp; it < n; it += 64) {
                int bb = flList[it], gp = flPos[it];
                int capEnd = bb * kSegCap + kSegCap;
                unsigned ent = fifo[bb][ln];
                int d = gp + ln;
                if (d < capEnd) bin[d] = ent;
                else { int s = atomicAdd(ovfCnt, 1);
                       if (s < kOvfCap) { ovfE[s] = ent; ovfB[s] = bb; } }
            }
        }
        __syncthreads();
        for (int bb = t; bb < kNBuck; bb += 1024) {
            int c = fcnt[bb]; if (c > kFifoCap) c = kFifoCap;
            if (c >= kFlushThr) {
                for (int j = kFlushThr; j < c; ++j) fifo[bb][j - kFlushThr] = fifo[bb][j];
                fcnt[bb] = c - kFlushThr;
            } else {
                fcnt[bb] = c;
            }
        }
        __syncthreads();
    }

    // final drain: partial flushes of the <=kFifoCap-entry tails
    if (t == 0) nFl = 0;
    __syncthreads();
    for (int bb = t; bb < kNBuck; bb += 1024) {
        int c = fcnt[bb]; if (c > kFifoCap) c = kFifoCap;
        if (c) {
            int slot = atomicAdd(&nFl, 1);
            flList[slot] = bb; flAmt[slot] = c;
            flPos[slot] = atomicAdd(&bcur[bb], c);
        }
    }
    __syncthreads();
    const int n = nFl;
    const int grp = t >> 4, ln = t & 15;
    for (int it = grp; it < n; it += 64) {
        int bb = flList[it], f = flAmt[it], gp = flPos[it];
        int capEnd = bb * kSegCap + kSegCap;
        for (int j = ln; j < f; j += 16) {
            unsigned ent = fifo[bb][j];
            int d = gp + j;
            if (d < capEnd) bin[d] = ent;
            else { int s = atomicAdd(ovfCnt, 1);
                   if (s < kOvfCap) { ovfE[s] = ent; ovfB[s] = bb; } }
        }
    }
}

// ---------------- re-insert overflow entries into bin where room remains ----------------
__global__ __launch_bounds__(256) void ovf_drain(int* __restrict__ bcur,
                                                 unsigned* __restrict__ bin,
                                                 const int* __restrict__ ovfCnt,
                                                 const unsigned* __restrict__ ovfE,
                                                 int* __restrict__ ovfB) {
    int n = *ovfCnt; if (n > kOvfCap) n = kOvfCap;
    int i = blockIdx.x * 256 + threadIdx.x;
    if (i >= n) return;
    int bb = ovfB[i];
    int pos = atomicAdd(&bcur[bb], 1);
    if (pos < bb * kSegCap + kSegCap) { bin[pos] = ovfE[i]; ovfB[i] = -1; }
}

// ---- packed dual-chain 5-STAGE pipeline (W lookahead = 2 iterations) ----
// State per chain entering iter tt: e2_,e3_ = entries tt+2,tt+3; P2_ = pk(tt+2);
// c0_,c1_ = cj(tt),cj(tt+1); w0x = W-row(tt) [FMA now]; w1x = W-row(tt+1).
// Body: fetch e(tt+4); pk(tt+3); W-row(tt+2); FMA entry tt. The W-row consumed
// by an FMA was loaded TWO iterations earlier (~100 own-issue cycles; x waves
// interleave -> L2 latency fully covered -- the round-10 wall was 1-iter lookahead).
#define PK_PRO(sp_, OFS_, e2_, e3_, P2_, c0_, c1_, w00_, w01_, w02_, w10_, w11_, w12_)  \
  { unsigned e0_ = (sp_)[OFS_];                                                         \
    unsigned e1_ = (sp_)[(OFS_) + 4];                                                   \
    e2_ = (sp_)[(OFS_) + 8];                                                            \
    e3_ = (sp_)[(OFS_) + 12];                                                           \
    uint4 P0_ = pkp[e0_ & 0xffffu];                                                     \
    uint4 P1_ = pkp[e1_ & 0xffffu];                                                     \
    P2_ = pkp[e2_ & 0xffffu];                                                           \
    c0_ = __uint_as_float(P0_.w);                                                       \
    c1_ = __uint_as_float(P1_.w);                                                       \
    const float* W0_ = W + (((e0_ >> 16) & 1u) * (unsigned)(kIn * kMsg));               \
    const float* W1_ = W + (((e1_ >> 16) & 1u) * (unsigned)(kIn * kMsg));               \
    w00_ = W0_[P0_.x + fl]; w01_ = W0_[P0_.y + fl]; w02_ = W0_[P0_.z + fl];             \
    w10_ = W1_[P1_.x + fl]; w11_ = W1_[P1_.y + fl]; w12_ = W1_[P1_.z + fl]; }

#define PK_BODY(sp_, OFS_, tt_, e2_, e3_, P2_, c0_, c1_, w00_, w01_, w02_, w10_, w11_, w12_, a0_, a1_, a2_) \
  { unsigned e4_ = (sp_)[(OFS_) + 4*(tt_) + 16];                                        \
    uint4 P3_ = pkp[e3_ & 0xffffu];                                                     \
    const float* W2_ = W + (((e2_ >> 16) & 1u) * (unsigned)(kIn * kMsg));               \
    float w20_ = W2_[P2_.x + fl];                                                       \
    float w21_ = W2_[P2_.y + fl];                                                       \
    float w22_ = W2_[P2_.z + fl];                                                       \
    float c2_ = __uint_as_float(P2_.w);                                                 \
    a0_ = fmaf(w00_, c0_, a0_); a1_ = fmaf(w01_, c0_, a1_); a2_ = fmaf(w02_, c0_, a2_); \
    e2_ = e3_; e3_ = e4_; P2_ = P3_;                                                    \
    c0_ = c1_; c1_ = c2_;                                                               \
    w00_ = w10_; w01_ = w11_; w02_ = w12_;                                              \
    w10_ = w20_; w11_ = w21_; w12_ = w22_; }

// ---------------- pk gather: 4 VMEM/entry, 5-stage dual-chain ----------------
__global__ __launch_bounds__(512, 6) void gather_pk(
        const unsigned* __restrict__ bin,
        const int* __restrict__ bcur,
        const int* __restrict__ ovfCnt,
        const unsigned* __restrict__ ovfE,
        const int* __restrict__ ovfB,
        const float* __restrict__ W,
        const uint4* __restrict__ pk_drug, const uint4* __restrict__ pk_dis,
        const float* __restrict__ ci_drug, const float* __restrict__ ci_dis,
        const float* __restrict__ w_fc, const float* __restrict__ b_fc,
        float* __restrict__ out) {
    __shared__ float ws[kAgg * kOut];              // 24 KB
    __shared__ float bs[kOut];
    __shared__ unsigned stage[kSegCap + kSent];    // 13.9 KB
    __shared__ int h[kBN], lb[kBN];
    __shared__ int sbuf[kBN];
    __shared__ int sOvf;

    const int t = threadIdx.x;
    const int b = blockIdx.x;
    for (int i = t; i < kAgg * kOut; i += 512) ws[i] = w_fc[i];
    if (t < kOut) bs[t] = b_fc[t];
    if (t < kBN) h[t] = 0;
    if (t == 0) sOvf = (ovfCnt[0] < kOvfCap) ? ovfCnt[0] : kOvfCap;

    const int sb = b * kSegCap;
    __syncthreads();
    int seg = bcur[b] - sb;
    if (seg > kSegCap) seg = kSegCap;

    for (int i = t; i < seg; i += 512)
        atomicAdd(&h[bin[sb + i] >> 17], 1);
    __syncthreads();
    if (t < kBN) sbuf[t] = h[t];
    __syncthreads();
    for (int o = 1; o < kBN; o <<= 1) {
        int x = 0;
        if (t < kBN && t >= o) x = sbuf[t - o];
        __syncthreads();
        if (t < kBN) sbuf[t] += x;
        __syncthreads();
    }
    if (t < kBN) { int ex = sbuf[t] - h[t]; lb[t] = ex; sbuf[t] = ex; }
    if (t < kSent) stage[seg + t] = 0;   // sentinel entries (loaded, never FMA'd)
    __syncthreads();
    for (int i = t; i < seg; i += 512) {
        unsigned e = bin[sb + i];
        int pos = atomicAdd(&sbuf[e >> 17], 1);
        stage[pos] = e;
    }
    __syncthreads();

    const int wid  = t >> 6;
    const int lane = t & 63;
    const int half = lane >> 5;
    const int fl   = lane & 31;

    for (int i = 0; i < kNPW; ++i) {
        const int nl = wid * kNPW + i;
        if (nl >= kBN) break;    // wave-uniform
        const int g  = b * kBN + nl;
        if (g >= kNTot) break;   // wave-uniform; no block syncs below

        const uint4* pkp;
        float civ;
        size_t orow;
        if (g < kNDis) {         // dis dst node: gathers DRUG feats
            pkp = pk_drug; civ = ci_dis[g];
            orow = (size_t)(kNDrug + g);
        } else {                 // drug dst node: gathers DIS feats
            pkp = pk_dis;  civ = ci_drug[g - kNDis];
            orow = (size_t)(g - kNDis);
        }

        const int base = lb[nl];
        const int deg  = h[nl];
        const unsigned* sp = stage + base + half;
        const int n  = (deg - half + 1) >> 1;   // this half's entry count
        const int nA = (n + 1) >> 1;            // chain A: half-entries 0,2,4,..
        const int nB = n >> 1;                  // chain B: half-entries 1,3,5,..

        float a0A = 0.f, a1A = 0.f, a2A = 0.f;
        float a0B = 0.f, a1B = 0.f, a2B = 0.f;
        unsigned eA2, eA3, eB2, eB3;
        uint4 PA2, PB2;
        float cA0, cA1, cB0, cB1;
        float wA00, wA01, wA02, wA10, wA11, wA12;
        float wB00, wB01, wB02, wB10, wB11, wB12;

        PK_PRO(sp, 0, eA2, eA3, PA2, cA0, cA1, wA00, wA01, wA02, wA10, wA11, wA12);
        PK_PRO(sp, 2, eB2, eB3, PB2, cB0, cB1, wB00, wB01, wB02, wB10, wB11, wB12);

        int tt = 0;
        for (; tt < nB; ++tt) {
            PK_BODY(sp, 0, tt, eA2, eA3, PA2, cA0, cA1,
                    wA00, wA01, wA02, wA10, wA11, wA12, a0A, a1A, a2A);
            PK_BODY(sp, 2, tt, eB2, eB3, PB2, cB0, cB1,
                    wB00, wB01, wB02, wB10, wB11, wB12, a0B, a1B, a2B);
        }
        if (tt < nA) {
            PK_BODY(sp, 0, tt, eA2, eA3, PA2, cA0, cA1,
                    wA00, wA01, wA02, wA10, wA11, wA12, a0A, a1A, a2A);
        }

        float a0 = a0A + a0B, a1 = a1A + a1B, a2 = a2A + a2B;

        if (sOvf > 0) {          // statistically never non-zero
            for (int j = half; j < sOvf; j += 2) {
                int bb = ovfB[j];
                if (bb == b && (int)(ovfE[j] >> 17) == nl) {
                    unsigned e = ovfE[j];
                    uint4 P = pkp[e & 0xffffu];
                    const float* Wr = W + (((e >> 16) & 1u) * (unsigned)(kIn * kMsg));
                    float c = __uint_as_float(P.w);
                    a0 = fmaf(Wr[P.x + fl], c, a0);
                    a1 = fmaf(Wr[P.y + fl], c, a1);
                    a2 = fmaf(Wr[P.z + fl], c, a2);
                }
            }
        }

        a0 += __shfl_xor(a0, 32);
        a1 += __shfl_xor(a1, 32);
        a2 += __shfl_xor(a2, 32);

        a0 *= civ; a1 *= civ; a2 *= civ;
        a0 = (a0 >= 0.f) ? a0 : kSlope * a0;
        a1 = (a1 >= 0.f) ? a1 : kSlope * a1;
        a2 = (a2 >= 0.f) ? a2 : kSlope * a2;

        float acc = bs[lane];
#pragma unroll
        for (int k = 0; k < 32; ++k)
            acc = fmaf(__shfl(a0, k), ws[k * kOut + lane], acc);
#pragma unroll
        for (int k = 0; k < 32; ++k)
            acc = fmaf(__shfl(a1, k), ws[(32 + k) * kOut + lane], acc);
#pragma unroll
        for (int k = 0; k < 32; ++k)
            acc = fmaf(__shfl(a2, k), ws[(64 + k) * kOut + lane], acc);
        out[orow * kOut + lane] = acc;
    }
}

// ---- round-9 (unpacked) dual-chain pieces, for the mid-tier path ----
#define ACC_PRO(sp_, OFS_, e1_, e2_, i10_, i11_, i12_, c0_, c1_, w00_, w01_, w02_)      \
  { unsigned e0_ = (sp_)[OFS_]; e1_ = (sp_)[(OFS_) + 4]; e2_ = (sp_)[(OFS_) + 8];       \
    int g0_ = (int)(e0_ & 0xffffu);                                                     \
    int j0_ = fidxp[g0_*3], j1_ = fidxp[g0_*3+1], j2_ = fidxp[g0_*3+2];                 \
    c0_ = cjp[g0_];                                                                     \
    int g1_ = (int)(e1_ & 0xffffu);                                                     \
    i10_ = fidxp[g1_*3]; i11_ = fidxp[g1_*3+1]; i12_ = fidxp[g1_*3+2];                  \
    c1_ = cjp[g1_];                                                                     \
    const float* W0_ = W + (((e0_ >> 16) & 1u) * (unsigned)(kIn * kMsg));               \
    w00_ = W0_[(j0_ << 5) + fl]; w01_ = W0_[(j1_ << 5) + fl]; w02_ = W0_[(j2_ << 5) + fl]; }

#define ACC_BODY(sp_, OFS_, tt_, e1_, e2_, i10_, i11_, i12_, c0_, c1_, w00_, w01_, w02_, a0_, a1_, a2_) \
  { unsigned e3_ = (sp_)[(OFS_) + 4*(tt_) + 12];                                        \
    int g2_ = (int)(e2_ & 0xffffu);                                                     \
    int i20_ = fidxp[g2_*3], i21_ = fidxp[g2_*3+1], i22_ = fidxp[g2_*3+2];              \
    float c2_ = cjp[g2_];                                                               \
    const float* W1_ = W + (((e1_ >> 16) & 1u) * (unsigned)(kIn * kMsg));               \
    float w10_ = W1_[(i10_ << 5) + fl];                                                 \
    float w11_ = W1_[(i11_ << 5) + fl];                                                 \
    float w12_ = W1_[(i12_ << 5) + fl];                                                 \
    a0_ = fmaf(w00_, c0_, a0_); a1_ = fmaf(w01_, c0_, a1_); a2_ = fmaf(w02_, c0_, a2_); \
    e1_ = e2_; e2_ = e3_; i10_ = i20_; i11_ = i21_; i12_ = i22_;                        \
    c0_ = c1_; c1_ = c2_; w00_ = w10_; w01_ = w11_; w02_ = w12_; }

__global__ __launch_bounds__(512, 6) void gather_fused(
        const unsigned* __restrict__ bin,
        const int* __restrict__ bcur,
        const int* __restrict__ ovfCnt,
        const unsigned* __restrict__ ovfE,
        const int* __restrict__ ovfB,
        const float* __restrict__ W,
        const int* __restrict__ drug_idx, const int* __restrict__ dis_idx,
        const float* __restrict__ cj_drug, const float* __restrict__ cj_dis,
        const float* __restrict__ ci_drug, const float* __restrict__ ci_dis,
        const float* __restrict__ w_fc, const float* __restrict__ b_fc,
        float* __restrict__ out) {
    __shared__ float ws[kAgg * kOut];
    __shared__ float bs[kOut];
    __shared__ unsigned stage[kSegCap + kSent];
    __shared__ int h[kBN], lb[kBN];
    __shared__ int sbuf[kBN];
    __shared__ int sOvf;

    const int t = threadIdx.x;
    const int b = blockIdx.x;
    for (int i = t; i < kAgg * kOut; i += 512) ws[i] = w_fc[i];
    if (t < kOut) bs[t] = b_fc[t];
    if (t < kBN) h[t] = 0;
    if (t == 0) sOvf = (ovfCnt[0] < kOvfCap) ? ovfCnt[0] : kOvfCap;

    const int sb = b * kSegCap;
    __syncthreads();
    int seg = bcur[b] - sb;
    if (seg > kSegCap) seg = kSegCap;

    for (int i = t; i < seg; i += 512)
        atomicAdd(&h[bin[sb + i] >> 17], 1);
    __syncthreads();
    if (t < kBN) sbuf[t] = h[t];
    __syncthreads();
    for (int o = 1; o < kBN; o <<= 1) {
        int x = 0;
        if (t < kBN && t >= o) x = sbuf[t - o];
        __syncthreads();
        if (t < kBN) sbuf[t] += x;
        __syncthreads();
    }
    if (t < kBN) { int ex = sbuf[t] - h[t]; lb[t] = ex; sbuf[t] = ex; }
    if (t < kSent) stage[seg + t] = 0;
    __syncthreads();
    for (int i = t; i < seg; i += 512) {
        unsigned e = bin[sb + i];
        int pos = atomicAdd(&sbuf[e >> 17], 1);
        stage[pos] = e;
    }
    __syncthreads();

    const int wid  = t >> 6;
    const int lane = t & 63;
    const int half = lane >> 5;
    const int fl   = lane & 31;

    for (int i = 0; i < kNPW; ++i) {
        const int nl = wid * kNPW + i;
        if (nl >= kBN) break;
        const int g  = b * kBN + nl;
        if (g >= kNTot) break;

        const int* fidxp;
        const float* cjp;
        float civ;
        size_t orow;
        if (g < kNDis) {
            fidxp = drug_idx; cjp = cj_drug; civ = ci_dis[g];
            orow = (size_t)(kNDrug + g);
        } else {
            fidxp = dis_idx;  cjp = cj_dis;  civ = ci_drug[g - kNDis];
            orow = (size_t)(g - kNDis);
        }

        const int base = lb[nl];
        const int deg  = h[nl];
        const unsigned* sp = stage + base + half;
        const int n  = (deg - half + 1) >> 1;
        const int nA = (n + 1) >> 1;
        const int nB = n >> 1;

        float a0A = 0.f, a1A = 0.f, a2A = 0.f;
        float a0B = 0.f, a1B = 0.f, a2B = 0.f;
        unsigned eA1, eA2, eB1, eB2;
        int iA0, iA1, iA2, iB0, iB1, iB2;
        float cA0, cA1, cB0, cB1;
        float wA0, wA1, wA2, wB0, wB1, wB2;

        ACC_PRO(sp, 0, eA1, eA2, iA0, iA1, iA2, cA0, cA1, wA0, wA1, wA2);
        ACC_PRO(sp, 2, eB1, eB2, iB0, iB1, iB2, cB0, cB1, wB0, wB1, wB2);

        int tt = 0;
        for (; tt < nB; ++tt) {
            ACC_BODY(sp, 0, tt, eA1, eA2, iA0, iA1, iA2, cA0, cA1, wA0, wA1, wA2,
                     a0A, a1A, a2A);
            ACC_BODY(sp, 2, tt, eB1, eB2, iB0, iB1, iB2, cB0, cB1, wB0, wB1, wB2,
                     a0B, a1B, a2B);
        }
        if (tt < nA) {
            ACC_BODY(sp, 0, tt, eA1, eA2, iA0, iA1, iA2, cA0, cA1, wA0, wA1, wA2,
                     a0A, a1A, a2A);
        }

        float a0 = a0A + a0B, a1 = a1A + a1B, a2 = a2A + a2B;

        if (sOvf > 0) {
            for (int j = half; j < sOvf; j += 2) {
                int bb = ovfB[j];
                if (bb == b && (int)(ovfE[j] >> 17) == nl) {
                    unsigned e = ovfE[j];
                    int gg = (int)(e & 0xffffu);
                    const float* Wr = W + (((e >> 16) & 1u) * (unsigned)(kIn * kMsg));
                    float c = cjp[gg];
                    a0 = fmaf(Wr[(fidxp[gg * 3]     << 5) + fl], c, a0);
                    a1 = fmaf(Wr[(fidxp[gg * 3 + 1] << 5) + fl], c, a1);
                    a2 = fmaf(Wr[(fidxp[gg * 3 + 2] << 5) + fl], c, a2);
                }
            }
        }

        a0 += __shfl_xor(a0, 32);
        a1 += __shfl_xor(a1, 32);
        a2 += __shfl_xor(a2, 32);

        a0 *= civ; a1 *= civ; a2 *= civ;
        a0 = (a0 >= 0.f) ? a0 : kSlope * a0;
        a1 = (a1 >= 0.f) ? a1 : kSlope * a1;
        a2 = (a2 >= 0.f) ? a2 : kSlope * a2;

        float acc = bs[lane];
#pragma unroll
        for (int k = 0; k < 32; ++k)
            acc = fmaf(__shfl(a0, k), ws[k * kOut + lane], acc);
#pragma unroll
        for (int k = 0; k < 32; ++k)
            acc = fmaf(__shfl(a1, k), ws[(32 + k) * kOut + lane], acc);
#pragma unroll
        for (int k = 0; k < 32; ++k)
            acc = fmaf(__shfl(a2, k), ws[(64 + k) * kOut + lane], acc);
        out[orow * kOut + lane] = acc;
    }
}

// ---------------- fallback path (R1 atomic scatter, tiny-ws only) ----------------
__global__ __launch_bounds__(256) void build_W_fb(const float* __restrict__ att,
                                                  const float* __restrict__ basis,
                                                  float* __restrict__ W) {
    constexpr int per_r = kIn * kMsg;
    int idx = blockIdx.x * blockDim.x + threadIdx.x;
    if (idx >= kR * per_r) return;
    int r = idx / per_r;
    int ic = idx - r * per_r;
    float acc = 0.f;
#pragma unroll
    for (int b = 0; b < kBasis; ++b)
        acc += att[r * kBasis + b] * basis[b * per_r + ic];
    W[idx] = acc;
}

__global__ __launch_bounds__(256) void edge_scatter(
        const float* __restrict__ W,
        const int* __restrict__ gnode,
        const int* __restrict__ snode,
        const int* __restrict__ fidx,
        const float* __restrict__ cj,
        float* __restrict__ h) {
    const int r = blockIdx.y;
    long tid = (long)blockIdx.x * blockDim.x + threadIdx.x;
    const int lane = (int)(tid & 31);
    const long e = tid >> 5;
    if (e >= kE) return;
    const int g = gnode[(long)r * kE + e];
    const int s = snode[(long)r * kE + e];
    const int i0 = fidx[g * 3 + 0];
    const int i1 = fidx[g * 3 + 1];
    const int i2 = fidx[g * 3 + 2];
    const float c = cj[g];
    const float* Wr = W + (size_t)r * kIn * kMsg;
    float* outp = h + (size_t)s * kAgg;
    atomicAdd(&outp[lane],            Wr[(size_t)i0 * kMsg + lane] * c);
    atomicAdd(&outp[kMsg + lane],     Wr[(size_t)i1 * kMsg + lane] * c);
    atomicAdd(&outp[2 * kMsg + lane], Wr[(size_t)i2 * kMsg + lane] * c);
}

__global__ __launch_bounds__(256) void fc_fused(const float* __restrict__ h,
                                                const float* __restrict__ ci,
                                                const float* __restrict__ w_fc,
                                                const float* __restrict__ b_fc,
                                                float* __restrict__ out, int nrows) {
    __shared__ float ws[kAgg * kOut];
    __shared__ float bs[kOut];
    const int lt = threadIdx.y * blockDim.x + threadIdx.x;
    for (int i = lt; i < kAgg * kOut; i += blockDim.x * blockDim.y)
        ws[i] = w_fc[i];
    if (lt < kOut) bs[lt] = b_fc[lt];
    __syncthreads();
    const int row = blockIdx.x * blockDim.y + threadIdx.y;
    if (row >= nrows) return;
    const int col = threadIdx.x;
    const float c = ci[row];
    const float* hr = h + (size_t)row * kAgg;
    float acc = bs[col];
#pragma unroll 8
    for (int k = 0; k < kAgg; ++k) {
        float a = hr[k] * c;
        a = (a >= 0.f) ? a : kSlope * a;
        acc += a * ws[k * kOut + col];
    }
    out[(size_t)row * kOut + col] = acc;
}

extern "C" void kernel_launch(void* const* d_in, const int* in_sizes, int n_in,
                              void* d_out, int out_size, void* d_ws, size_t ws_size,
                              hipStream_t stream) {
    const int*   drug_idx = (const int*)d_in[0];
    const int*   dis_idx  = (const int*)d_in[1];
    const int*   edge_src = (const int*)d_in[2];
    const int*   edge_dst = (const int*)d_in[3];
    const float* cj_drug  = (const float*)d_in[4];
    const float* ci_drug  = (const float*)d_in[5];
    const float* cj_dis   = (const float*)d_in[6];
    const float* ci_dis   = (const float*)d_in[7];
    const float* att      = (const float*)d_in[8];
    const float* basis    = (const float*)d_in[9];
    const float* w_fc     = (const float*)d_in[10];
    const float* b_fc     = (const float*)d_in[11];
    float* out = (float*)d_out;

    auto align256 = [](size_t x) { return (x + 255) & ~(size_t)255; };
    const size_t Wb    = align256((size_t)kR * kIn * kMsg * sizeof(float));     // 512 KB
    const size_t pkB   = align256((size_t)kNDrug * sizeof(uint4));              // 800 KB each
    const size_t bcB   = align256((size_t)kNBuck * sizeof(int));
    const size_t ocB   = align256(sizeof(int));
    const size_t oeB   = align256((size_t)kOvfCap * sizeof(unsigned));          // 16 KB
    const size_t obB   = align256((size_t)kOvfCap * sizeof(int));               // 16 KB
    const size_t binB  = align256((size_t)kNBuck * kSegCap * sizeof(unsigned)); // ~13.88 MB
    const size_t needBase = Wb + bcB + ocB + oeB + obB + binB;                  // ~14.44 MB
    const size_t needPk   = needBase + 2 * pkB;                                 // ~16.04 MB

    if (ws_size >= needBase) {
        const bool usePk = (ws_size >= needPk);
        char* p = (char*)d_ws;
        float*    W       = (float*)p;     p += Wb;
        uint4*    pk_drug = nullptr;
        uint4*    pk_dis  = nullptr;
        if (usePk) { pk_drug = (uint4*)p;  p += pkB;
                     pk_dis  = (uint4*)p;  p += pkB; }
        int*      bcur   = (int*)p;        p += bcB;
        int*      ovfCnt = (int*)p;        p += ocB;
        unsigned* ovfE   = (unsigned*)p;   p += oeB;
        int*      ovfB   = (int*)p;        p += obB;
        unsigned* bin    = (unsigned*)p;

        setup_all<<<dim3(516), 256, 0, stream>>>(att, basis, W, bcur, ovfCnt);
        if (usePk)
            pack_nodes<<<dim3((kNDrug + 255) / 256), 256, 0, stream>>>(
                drug_idx, dis_idx, cj_drug, cj_dis, pk_drug, pk_dis);
        bin_pass<<<dim3(kBinBlocks), 1024, 0, stream>>>(edge_src, edge_dst,
                                                        bcur, bin, ovfCnt, ovfE, ovfB);
        ovf_drain<<<dim3((kOvfCap + 255) / 256), 256, 0, stream>>>(bcur, bin,
                                                                   ovfCnt, ovfE, ovfB);
        if (usePk)
            gather_pk<<<dim3(kNBuck), 512, 0, stream>>>(bin, bcur, ovfCnt, ovfE, ovfB,
                                                        W, pk_drug, pk_dis,
                                                        ci_drug, ci_dis,
                                                        w_fc, b_fc, out);
        else
            gather_fused<<<dim3(kNBuck), 512, 0, stream>>>(bin, bcur, ovfCnt, ovfE, ovfB,
                                                           W, drug_idx, dis_idx,
                                                           cj_drug, cj_dis,
                                                           ci_drug, ci_dis,
                                                           w_fc, b_fc, out);
    } else {
        // fallback: R1 phased atomic-scatter path
        char* p = (char*)d_ws;
        float* W = (float*)p;
        build_W_fb<<<dim3((kR * kIn * kMsg + 255) / 256), 256, 0, stream>>>(att, basis, W);
        const size_t hB = (size_t)kNDrug * kAgg * sizeof(float);
        float* h = (float*)((char*)d_ws + Wb);
        const int scat_blocks = (int)(((long)kE * 32 + 255) / 256);
        const dim3 scat_grid(scat_blocks, kR);
        hipMemsetAsync(h, 0, hB, stream);
        edge_scatter<<<scat_grid, 256, 0, stream>>>(W, edge_dst, edge_src,
                                                    dis_idx, cj_dis, h);
        fc_fused<<<dim3((kNDrug + 3) / 4), dim3(64, 4), 0, stream>>>(
            h, ci_drug, w_fc, b_fc, out, kNDrug);
        hipMemsetAsync(h, 0, hB, stream);
        edge_scatter<<<scat_grid, 256, 0, stream>>>(W, edge_src, edge_dst,
                                                    drug_idx, cj_drug, h);
        fc_fused<<<dim3((kNDis + 3) / 4), dim3(64, 4), 0, stream>>>(
            h, ci_dis, w_fc, b_fc, out + (size_t)kNDrug * kOut, kNDis);
    }
}

// Round 12
// 191.159 us; speedup vs baseline: 1.2648x; 1.1602x over previous
//
#include <hip/hip_runtime.h>

namespace {
constexpr int kNDrug = 50000;
constexpr int kNDis  = 50000;
constexpr int kE     = 800000;
constexpr int kR     = 2;
constexpr int kIn    = 2048;   // IN_UNITS
constexpr int kMsg   = 32;     // AGG_UNITS / 3
constexpr int kAgg   = 96;     // AGG_UNITS
constexpr int kOut   = 64;     // OUT_UNITS
constexpr int kBasis = 4;
constexpr float kSlope = 0.1f; // LeakyReLU slope
constexpr int kNTot  = kNDis + kNDrug;            // [0,kNDis)=dis nodes, rest drug nodes
constexpr int kBN    = 102;                       // nodes per bucket -> 981 blocks
constexpr int kBNP   = 128;                       // padded counter count (wave-scan over 2/lane)
constexpr int kNBuck = (kNTot + kBN - 1) / kBN;   // 981
constexpr int kSegCap = 3536;                     // entries/bucket (mean 3264, +4.8 sigma), 16-mult
constexpr int kFifoCap = 37;                      // LDS FIFO depth per bucket in bin_pass
constexpr int kFlushThr = 16;                     // flush unit = 16 entries = 64B; slack 21 -> ovf
                                                  // statistically never (round-7/8 lesson)
constexpr int kBinBlocks = 128;                   // binning blocks (1024 thr each; 12.5K edges ea)
constexpr int kOvfCap = 4096;                     // overflow list capacity
constexpr int kNPW   = 13;                        // ceil(kBN/8) nodes per wave in gather
constexpr int kSent  = 20;                        // sentinel pad (covers 5-stage dual-chain lookahead)
constexpr unsigned kInvE = 0xFFFFFFFFu;           // invalid-entry sentinel for register staging
}

// ---------------- one-shot init: W = att@basis, cursors ----------------
__global__ __launch_bounds__(256) void setup_all(const float* __restrict__ att,
                                                 const float* __restrict__ basis,
                                                 float* __restrict__ W,
                                                 int* __restrict__ bcur,
                                                 int* __restrict__ ovfCnt) {
    constexpr int per_r = kIn * kMsg;
    const int blk = blockIdx.x;
    const int t = threadIdx.x;
    if (blk < 512) {                       // W: 2*2048*32 = 131072 elems
        int idx = blk * 256 + t;
        int r = idx / per_r;
        int ic = idx - r * per_r;
        float acc = 0.f;
#pragma unroll
        for (int b = 0; b < kBasis; ++b)
            acc += att[r * kBasis + b] * basis[b * per_r + ic];
        W[idx] = acc;
    } else {                               // blocks 512..515: bcur init; 512/t0: ovfCnt
        int i = (blk - 512) * 256 + t;
        if (i < kNBuck) bcur[i] = i * kSegCap;
        if (blk == 512 && t == 0) *ovfCnt = 0;
    }
}

// ---------------- packed node table: pk[g] = {i0*32, i1*32, i2*32, bits(cj)} ----------------
__global__ __launch_bounds__(256) void pack_nodes(const int* __restrict__ drug_idx,
                                                  const int* __restrict__ dis_idx,
                                                  const float* __restrict__ cj_drug,
                                                  const float* __restrict__ cj_dis,
                                                  uint4* __restrict__ pk_drug,
                                                  uint4* __restrict__ pk_dis) {
    int g = blockIdx.x * 256 + threadIdx.x;
    if (g < kNDrug) {
        pk_drug[g] = make_uint4((unsigned)drug_idx[3 * g] << 5,
                                (unsigned)drug_idx[3 * g + 1] << 5,
                                (unsigned)drug_idx[3 * g + 2] << 5,
                                __float_as_uint(cj_drug[g]));
    }
    if (g < kNDis) {
        pk_dis[g] = make_uint4((unsigned)dis_idx[3 * g] << 5,
                               (unsigned)dis_idx[3 * g + 1] << 5,
                               (unsigned)dis_idx[3 * g + 2] << 5,
                               __float_as_uint(cj_dis[g]));
    }
}

// ---------------- LDS-FIFO binning (128 blocks x 1024 threads) ----------------
// entry = gnode (16b) | rating (bit16) | node-rel-in-bucket (bits 17..23)
__global__ __launch_bounds__(1024) void bin_pass(const int* __restrict__ esrc,
                                                 const int* __restrict__ edst,
                                                 int* __restrict__ bcur,
                                                 unsigned* __restrict__ bin,
                                                 int* __restrict__ ovfCnt,
                                                 unsigned* __restrict__ ovfE,
                                                 int* __restrict__ ovfB) {
    __shared__ unsigned fifo[kNBuck][kFifoCap];  // 145.2 KB
    __shared__ int fcnt[kNBuck];
    __shared__ int flList[kNBuck], flAmt[kNBuck], flPos[kNBuck];
    __shared__ int nFl;

    const int t = threadIdx.x;
    for (int i = t; i < kNBuck; i += 1024) fcnt[i] = 0;

    const int total = kR * kE;
    const int per = (total + kBinBlocks - 1) / kBinBlocks;   // 12500 edges
    const int e0 = blockIdx.x * per;
    const int e1 = (e0 + per < total) ? e0 + per : total;
    __syncthreads();

    auto place = [&](int node, int gn, int r) {
        int bb = node / kBN;
        int rel = node - bb * kBN;
        unsigned ent = (unsigned)gn | ((unsigned)r << 16) | ((unsigned)rel << 17);
        int pos = atomicAdd(&fcnt[bb], 1);
        if (pos < kFifoCap) {
            fifo[bb][pos] = ent;
        } else {  // statistically never (slack 21)
            int s = atomicAdd(ovfCnt, 1);
            if (s < kOvfCap) { ovfE[s] = ent; ovfB[s] = bb; }
        }
    };

    for (int base = e0; base < e1; base += 1024) {
        int idx = base + t;
        if (idx < e1) {
            int r = (idx >= kE) ? 1 : 0;
            int src = esrc[idx], dst = edst[idx];
            place(dst, src, r);            // dis-side entry
            place(kNDis + src, dst, r);    // drug-side entry
        }
        if (t == 0) nFl = 0;
        __syncthreads();
        for (int bb = t; bb < kNBuck; bb += 1024) {
            int c = fcnt[bb]; if (c > kFifoCap) c = kFifoCap;
            if (c >= kFlushThr) {
                int slot = atomicAdd(&nFl, 1);
                flList[slot] = bb;
                flPos[slot] = atomicAdd(&bcur[bb], kFlushThr);   // stays 16-aligned
            }
        }
        __syncthreads();
        {   // 64B-unit copies LDS -> bin (16-lane groups)
            const int n = nFl;
            const int grp = t >> 4, ln = t & 15;
            for (int it = grp; it < n; it += 64) {
                int bb = flList[it], gp = flPos[it];
                int capEnd = bb * kSegCap + kSegCap;
                unsigned ent = fifo[bb][ln];
                int d = gp + ln;
                if (d < capEnd) bin[d] = ent;
                else { int s = atomicAdd(ovfCnt, 1);
                       if (s < kOvfCap) { ovfE[s] = ent; ovfB[s] = bb; } }
            }
        }
        __syncthreads();
        for (int bb = t; bb < kNBuck; bb += 1024) {
            int c = fcnt[bb]; if (c > kFifoCap) c = kFifoCap;
            if (c >= kFlushThr) {
                for (int j = kFlushThr; j < c; ++j) fifo[bb][j - kFlushThr] = fifo[bb][j];
                fcnt[bb] = c - kFlushThr;
            } else {
                fcnt[bb] = c;
            }
        }
        __syncthreads();
    }

    // final drain: partial flushes of the <=kFifoCap-entry tails
    if (t == 0) nFl = 0;
    __syncthreads();
    for (int bb = t; bb < kNBuck; bb += 1024) {
        int c = fcnt[bb]; if (c > kFifoCap) c = kFifoCap;
        if (c) {
            int slot = atomicAdd(&nFl, 1);
            flList[slot] = bb; flAmt[slot] = c;
            flPos[slot] = atomicAdd(&bcur[bb], c);
        }
    }
    __syncthreads();
    const int n = nFl;
    const int grp = t >> 4, ln = t & 15;
    for (int it = grp; it < n; it += 64) {
        int bb = flList[it], f = flAmt[it], gp = flPos[it];
        int capEnd = bb * kSegCap + kSegCap;
        for (int j = ln; j < f; j += 16) {
            unsigned ent = fifo[bb][j];
            int d = gp + j;
            if (d < capEnd) bin[d] = ent;
            else { int s = atomicAdd(ovfCnt, 1);
                   if (s < kOvfCap) { ovfE[s] = ent; ovfB[s] = bb; } }
        }
    }
}

// ---------------- re-insert overflow entries into bin where room remains ----------------
__global__ __launch_bounds__(256) void ovf_drain(int* __restrict__ bcur,
                                                 unsigned* __restrict__ bin,
                                                 const int* __restrict__ ovfCnt,
                                                 const unsigned* __restrict__ ovfE,
                                                 int* __restrict__ ovfB) {
    int n = *ovfCnt; if (n > kOvfCap) n = kOvfCap;
    int i = blockIdx.x * 256 + threadIdx.x;
    if (i >= n) return;
    int bb = ovfB[i];
    int pos = atomicAdd(&bcur[bb], 1);
    if (pos < bb * kSegCap + kSegCap) { bin[pos] = ovfE[i]; ovfB[i] = -1; }
}

// ---- packed dual-chain 5-stage pipeline (kept from R11; compiler re-schedules anyway) ----
#define PK_PRO(sp_, OFS_, e2_, e3_, P2_, c0_, c1_, w00_, w01_, w02_, w10_, w11_, w12_)  \
  { unsigned e0_ = (sp_)[OFS_];                                                         \
    unsigned e1_ = (sp_)[(OFS_) + 4];                                                   \
    e2_ = (sp_)[(OFS_) + 8];                                                            \
    e3_ = (sp_)[(OFS_) + 12];                                                           \
    uint4 P0_ = pkp[e0_ & 0xffffu];                                                     \
    uint4 P1_ = pkp[e1_ & 0xffffu];                                                     \
    P2_ = pkp[e2_ & 0xffffu];                                                           \
    c0_ = __uint_as_float(P0_.w);                                                       \
    c1_ = __uint_as_float(P1_.w);                                                       \
    const float* W0_ = W + (((e0_ >> 16) & 1u) * (unsigned)(kIn * kMsg));               \
    const float* W1_ = W + (((e1_ >> 16) & 1u) * (unsigned)(kIn * kMsg));               \
    w00_ = W0_[P0_.x + fl]; w01_ = W0_[P0_.y + fl]; w02_ = W0_[P0_.z + fl];             \
    w10_ = W1_[P1_.x + fl]; w11_ = W1_[P1_.y + fl]; w12_ = W1_[P1_.z + fl]; }

#define PK_BODY(sp_, OFS_, tt_, e2_, e3_, P2_, c0_, c1_, w00_, w01_, w02_, w10_, w11_, w12_, a0_, a1_, a2_) \
  { unsigned e4_ = (sp_)[(OFS_) + 4*(tt_) + 16];                                        \
    uint4 P3_ = pkp[e3_ & 0xffffu];                                                     \
    const float* W2_ = W + (((e2_ >> 16) & 1u) * (unsigned)(kIn * kMsg));               \
    float w20_ = W2_[P2_.x + fl];                                                       \
    float w21_ = W2_[P2_.y + fl];                                                       \
    float w22_ = W2_[P2_.z + fl];                                                       \
    float c2_ = __uint_as_float(P2_.w);                                                 \
    a0_ = fmaf(w00_, c0_, a0_); a1_ = fmaf(w01_, c0_, a1_); a2_ = fmaf(w02_, c0_, a2_); \
    e2_ = e3_; e3_ = e4_; P2_ = P3_;                                                    \
    c0_ = c1_; c1_ = c2_;                                                               \
    w00_ = w10_; w01_ = w11_; w02_ = w12_;                                              \
    w10_ = w20_; w11_ = w21_; w12_ = w22_; }

// ---------------- pk gather: fused 1-read prologue, wave scan, hbuf epilogue ----------------
__global__ __launch_bounds__(512, 6) void gather_pk(
        const unsigned* __restrict__ bin,
        const int* __restrict__ bcur,
        const int* __restrict__ ovfCnt,
        const unsigned* __restrict__ ovfE,
        const int* __restrict__ ovfB,
        const float* __restrict__ W,
        const uint4* __restrict__ pk_drug, const uint4* __restrict__ pk_dis,
        const float* __restrict__ ci_drug, const float* __restrict__ ci_dis,
        const float* __restrict__ w_fc, const float* __restrict__ b_fc,
        float* __restrict__ out) {
    __shared__ float ws[kAgg * kOut];              // 24 KB
    __shared__ float bs[kOut];
    __shared__ unsigned stage[kSegCap + kSent];    // 14.2 KB
    __shared__ int h[kBNP], lb[kBNP];
    __shared__ int sbuf[kBNP];
    __shared__ float hbuf[8][kAgg];                // 3 KB, one row per wave
    __shared__ int sOvf;

    const int t = threadIdx.x;
    const int b = blockIdx.x;
    {   // ws staged via float4 (3 coalesced iterations)
        const float4* wf4 = (const float4*)w_fc;
        float4* ws4 = (float4*)ws;
        for (int i = t; i < kAgg * kOut / 4; i += 512) ws4[i] = wf4[i];
    }
    if (t < kOut) bs[t] = b_fc[t];
    if (t < kBNP) h[t] = 0;
    if (t == 0) sOvf = (ovfCnt[0] < kOvfCap) ? ovfCnt[0] : kOvfCap;

    const int sb = b * kSegCap;
    __syncthreads();
    int seg = bcur[b] - sb;
    if (seg > kSegCap) seg = kSegCap;

    // ---- single-pass prologue: read entries into registers, histogram ----
    unsigned myE[7];                               // static indices only (rule #20)
#pragma unroll
    for (int k = 0; k < 7; ++k) {
        int i = t + k * 512;
        myE[k] = (i < seg) ? bin[sb + i] : kInvE;
    }
#pragma unroll
    for (int k = 0; k < 7; ++k)
        if (myE[k] != kInvE) atomicAdd(&h[myE[k] >> 17], 1);
    __syncthreads();

    // ---- wave-0 shfl scan of 128 counters (2 per lane) ----
    if (t < 64) {
        int v0 = h[2 * t], v1 = h[2 * t + 1];
        int s = v0 + v1;
#pragma unroll
        for (int o = 1; o < 64; o <<= 1) {
            int x = __shfl_up(s, o);
            if (t >= o) s += x;
        }
        int ex = s - (v0 + v1);
        lb[2 * t] = ex;       lb[2 * t + 1] = ex + v0;
        sbuf[2 * t] = ex;     sbuf[2 * t + 1] = ex + v0;
    }
    if (t < kSent) stage[kSegCap + t] = 0;  // pre-clear pad region top
    __syncthreads();

    // ---- scatter from registers into per-node-ordered LDS staging ----
#pragma unroll
    for (int k = 0; k < 7; ++k)
        if (myE[k] != kInvE) {
            int pos = atomicAdd(&sbuf[myE[k] >> 17], 1);
            stage[pos] = myE[k];
        }
    if (t < kSent) stage[seg + t] = 0;      // sentinel entries (loaded, never FMA'd)
    __syncthreads();

    const int wid  = t >> 6;
    const int lane = t & 63;
    const int half = lane >> 5;
    const int fl   = lane & 31;

    for (int i = 0; i < kNPW; ++i) {
        const int nl = wid * kNPW + i;
        if (nl >= kBN) break;    // wave-uniform
        const int g  = b * kBN + nl;
        if (g >= kNTot) break;   // wave-uniform; no block syncs below

        const uint4* pkp;
        float civ;
        size_t orow;
        if (g < kNDis) {         // dis dst node: gathers DRUG feats
            pkp = pk_drug; civ = ci_dis[g];
            orow = (size_t)(kNDrug + g);
        } else {                 // drug dst node: gathers DIS feats
            pkp = pk_dis;  civ = ci_drug[g - kNDis];
            orow = (size_t)(g - kNDis);
        }

        const int base = lb[nl];
        const int deg  = h[nl];
        const unsigned* sp = stage + base + half;
        const int n  = (deg - half + 1) >> 1;   // this half's entry count
        const int nA = (n + 1) >> 1;            // chain A: half-entries 0,2,4,..
        const int nB = n >> 1;                  // chain B: half-entries 1,3,5,..

        float a0A = 0.f, a1A = 0.f, a2A = 0.f;
        float a0B = 0.f, a1B = 0.f, a2B = 0.f;
        unsigned eA2, eA3, eB2, eB3;
        uint4 PA2, PB2;
        float cA0, cA1, cB0, cB1;
        float wA00, wA01, wA02, wA10, wA11, wA12;
        float wB00, wB01, wB02, wB10, wB11, wB12;

        PK_PRO(sp, 0, eA2, eA3, PA2, cA0, cA1, wA00, wA01, wA02, wA10, wA11, wA12);
        PK_PRO(sp, 2, eB2, eB3, PB2, cB0, cB1, wB00, wB01, wB02, wB10, wB11, wB12);

        int tt = 0;
        for (; tt < nB; ++tt) {
            PK_BODY(sp, 0, tt, eA2, eA3, PA2, cA0, cA1,
                    wA00, wA01, wA02, wA10, wA11, wA12, a0A, a1A, a2A);
            PK_BODY(sp, 2, tt, eB2, eB3, PB2, cB0, cB1,
                    wB00, wB01, wB02, wB10, wB11, wB12, a0B, a1B, a2B);
        }
        if (tt < nA) {
            PK_BODY(sp, 0, tt, eA2, eA3, PA2, cA0, cA1,
                    wA00, wA01, wA02, wA10, wA11, wA12, a0A, a1A, a2A);
        }

        float a0 = a0A + a0B, a1 = a1A + a1B, a2 = a2A + a2B;

        if (sOvf > 0) {          // statistically never non-zero
            for (int j = half; j < sOvf; j += 2) {
                int bb = ovfB[j];
                if (bb == b && (int)(ovfE[j] >> 17) == nl) {
                    unsigned e = ovfE[j];
                    uint4 P = pkp[e & 0xffffu];
                    const float* Wr = W + (((e >> 16) & 1u) * (unsigned)(kIn * kMsg));
                    float c = __uint_as_float(P.w);
                    a0 = fmaf(Wr[P.x + fl], c, a0);
                    a1 = fmaf(Wr[P.y + fl], c, a1);
                    a2 = fmaf(Wr[P.z + fl], c, a2);
                }
            }
        }

        a0 += __shfl_xor(a0, 32);
        a1 += __shfl_xor(a1, 32);
        a2 += __shfl_xor(a2, 32);

        a0 *= civ; a1 *= civ; a2 *= civ;
        a0 = (a0 >= 0.f) ? a0 : kSlope * a0;
        a1 = (a1 >= 0.f) ? a1 : kSlope * a1;
        a2 = (a2 >= 0.f) ? a2 : kSlope * a2;

        // ---- FC epilogue: per-wave hbuf row (same-wave LDS write->read, in-order DS) ----
        // 24 uniform ds_read_b128 broadcasts replace 96 cross-lane shfls; accumulation
        // split into 3 independent 32-FMA chains (was one 96-deep serial chain).
        if (half == 0) {
            hbuf[wid][fl]          = a0;
            hbuf[wid][kMsg + fl]   = a1;
            hbuf[wid][2*kMsg + fl] = a2;
        }
        const float4* hv = (const float4*)(&hbuf[wid][0]);
        float acc0 = bs[lane], acc1 = 0.f, acc2 = 0.f;
#pragma unroll
        for (int q = 0; q < 8; ++q) {
            float4 h4 = hv[q];                       // features 4q..4q+3
            acc0 = fmaf(h4.x, ws[(4*q    ) * kOut + lane], acc0);
            acc0 = fmaf(h4.y, ws[(4*q + 1) * kOut + lane], acc0);
            acc0 = fmaf(h4.z, ws[(4*q + 2) * kOut + lane], acc0);
            acc0 = fmaf(h4.w, ws[(4*q + 3) * kOut + lane], acc0);
        }
#pragma unroll
        for (int q = 8; q < 16; ++q) {
            float4 h4 = hv[q];
            acc1 = fmaf(h4.x, ws[(4*q    ) * kOut + lane], acc1);
            acc1 = fmaf(h4.y, ws[(4*q + 1) * kOut + lane], acc1);
            acc1 = fmaf(h4.z, ws[(4*q + 2) * kOut + lane], acc1);
            acc1 = fmaf(h4.w, ws[(4*q + 3) * kOut + lane], acc1);
        }
#pragma unroll
        for (int q = 16; q < 24; ++q) {
            float4 h4 = hv[q];
            acc2 = fmaf(h4.x, ws[(4*q    ) * kOut + lane], acc2);
            acc2 = fmaf(h4.y, ws[(4*q + 1) * kOut + lane], acc2);
            acc2 = fmaf(h4.z, ws[(4*q + 2) * kOut + lane], acc2);
            acc2 = fmaf(h4.w, ws[(4*q + 3) * kOut + lane], acc2);
        }
        out[orow * kOut + lane] = acc0 + acc1 + acc2;
    }
}

// ---------------- fallback path (R1 atomic scatter, tiny-ws only) ----------------
__global__ __launch_bounds__(256) void build_W_fb(const float* __restrict__ att,
                                                  const float* __restrict__ basis,
                                                  float* __restrict__ W) {
    constexpr int per_r = kIn * kMsg;
    int idx = blockIdx.x * blockDim.x + threadIdx.x;
    if (idx >= kR * per_r) return;
    int r = idx / per_r;
    int ic = idx - r * per_r;
    float acc = 0.f;
#pragma unroll
    for (int b = 0; b < kBasis; ++b)
        acc += att[r * kBasis + b] * basis[b * per_r + ic];
    W[idx] = acc;
}

__global__ __launch_bounds__(256) void edge_scatter(
        const float* __restrict__ W,
        const int* __restrict__ gnode,
        const int* __restrict__ snode,
        const int* __restrict__ fidx,
        const float* __restrict__ cj,
        float* __restrict__ h) {
    const int r = blockIdx.y;
    long tid = (long)blockIdx.x * blockDim.x + threadIdx.x;
    const int lane = (int)(tid & 31);
    const long e = tid >> 5;
    if (e >= kE) return;
    const int g = gnode[(long)r * kE + e];
    const int s = snode[(long)r * kE + e];
    const int i0 = fidx[g * 3 + 0];
    const int i1 = fidx[g * 3 + 1];
    const int i2 = fidx[g * 3 + 2];
    const float c = cj[g];
    const float* Wr = W + (size_t)r * kIn * kMsg;
    float* outp = h + (size_t)s * kAgg;
    atomicAdd(&outp[lane],            Wr[(size_t)i0 * kMsg + lane] * c);
    atomicAdd(&outp[kMsg + lane],     Wr[(size_t)i1 * kMsg + lane] * c);
    atomicAdd(&outp[2 * kMsg + lane], Wr[(size_t)i2 * kMsg + lane] * c);
}

__global__ __launch_bounds__(256) void fc_fused(const float* __restrict__ h,
                                                const float* __restrict__ ci,
                                                const float* __restrict__ w_fc,
                                                const float* __restrict__ b_fc,
                                                float* __restrict__ out, int nrows) {
    __shared__ float ws[kAgg * kOut];
    __shared__ float bs[kOut];
    const int lt = threadIdx.y * blockDim.x + threadIdx.x;
    for (int i = lt; i < kAgg * kOut; i += blockDim.x * blockDim.y)
        ws[i] = w_fc[i];
    if (lt < kOut) bs[lt] = b_fc[lt];
    __syncthreads();
    const int row = blockIdx.x * blockDim.y + threadIdx.y;
    if (row >= nrows) return;
    const int col = threadIdx.x;
    const float c = ci[row];
    const float* hr = h + (size_t)row * kAgg;
    float acc = bs[col];
#pragma unroll 8
    for (int k = 0; k < kAgg; ++k) {
        float a = hr[k] * c;
        a = (a >= 0.f) ? a : kSlope * a;
        acc += a * ws[k * kOut + col];
    }
    out[(size_t)row * kOut + col] = acc;
}

extern "C" void kernel_launch(void* const* d_in, const int* in_sizes, int n_in,
                              void* d_out, int out_size, void* d_ws, size_t ws_size,
                              hipStream_t stream) {
    const int*   drug_idx = (const int*)d_in[0];
    const int*   dis_idx  = (const int*)d_in[1];
    const int*   edge_src = (const int*)d_in[2];
    const int*   edge_dst = (const int*)d_in[3];
    const float* cj_drug  = (const float*)d_in[4];
    const float* ci_drug  = (const float*)d_in[5];
    const float* cj_dis   = (const float*)d_in[6];
    const float* ci_dis   = (const float*)d_in[7];
    const float* att      = (const float*)d_in[8];
    const float* basis    = (const float*)d_in[9];
    const float* w_fc     = (const float*)d_in[10];
    const float* b_fc     = (const float*)d_in[11];
    float* out = (float*)d_out;

    auto align256 = [](size_t x) { return (x + 255) & ~(size_t)255; };
    const size_t Wb    = align256((size_t)kR * kIn * kMsg * sizeof(float));     // 512 KB
    const size_t pkB   = align256((size_t)kNDrug * sizeof(uint4));              // 800 KB each
    const size_t bcB   = align256((size_t)kNBuck * sizeof(int));
    const size_t ocB   = align256(sizeof(int));
    const size_t oeB   = align256((size_t)kOvfCap * sizeof(unsigned));          // 16 KB
    const size_t obB   = align256((size_t)kOvfCap * sizeof(int));               // 16 KB
    const size_t binB  = align256((size_t)kNBuck * kSegCap * sizeof(unsigned)); // ~13.88 MB
    const size_t needBase = Wb + bcB + ocB + oeB + obB + binB;                  // ~14.44 MB
    const size_t needPk   = needBase + 2 * pkB;                                 // ~16.04 MB

    if (ws_size >= needPk) {
        char* p = (char*)d_ws;
        float*    W       = (float*)p;     p += Wb;
        uint4*    pk_drug = (uint4*)p;     p += pkB;
        uint4*    pk_dis  = (uint4*)p;     p += pkB;
        int*      bcur   = (int*)p;        p += bcB;
        int*      ovfCnt = (int*)p;        p += ocB;
        unsigned* ovfE   = (unsigned*)p;   p += oeB;
        int*      ovfB   = (int*)p;        p += obB;
        unsigned* bin    = (unsigned*)p;

        setup_all<<<dim3(516), 256, 0, stream>>>(att, basis, W, bcur, ovfCnt);
        pack_nodes<<<dim3((kNDrug + 255) / 256), 256, 0, stream>>>(
            drug_idx, dis_idx, cj_drug, cj_dis, pk_drug, pk_dis);
        bin_pass<<<dim3(kBinBlocks), 1024, 0, stream>>>(edge_src, edge_dst,
                                                        bcur, bin, ovfCnt, ovfE, ovfB);
        ovf_drain<<<dim3((kOvfCap + 255) / 256), 256, 0, stream>>>(bcur, bin,
                                                                   ovfCnt, ovfE, ovfB);
        gather_pk<<<dim3(kNBuck), 512, 0, stream>>>(bin, bcur, ovfCnt, ovfE, ovfB,
                                                    W, pk_drug, pk_dis,
                                                    ci_drug, ci_dis,
                                                    w_fc, b_fc, out);
    } else {
        // fallback: R1 phased atomic-scatter path
        char* p = (char*)d_ws;
        float* W = (float*)p;
        build_W_fb<<<dim3((kR * kIn * kMsg + 255) / 256), 256, 0, stream>>>(att, basis, W);
        const size_t hB = (size_t)kNDrug * kAgg * sizeof(float);
        float* h = (float*)((char*)d_ws + Wb);
        const int scat_blocks = (int)(((long)kE * 32 + 255) / 256);
        const dim3 scat_grid(scat_blocks, kR);
        hipMemsetAsync(h, 0, hB, stream);
        edge_scatter<<<scat_grid, 256, 0, stream>>>(W, edge_dst, edge_src,
                                                    dis_idx, cj_dis, h);
        fc_fused<<<dim3((kNDrug + 3) / 4), dim3(64, 4), 0, stream>>>(
            h, ci_drug, w_fc, b_fc, out, kNDrug);
        hipMemsetAsync(h, 0, hB, stream);
        edge_scatter<<<scat_grid, 256, 0, stream>>>(W, edge_src, edge_dst,
                                                    drug_idx, cj_drug, h);
        fc_fused<<<dim3((kNDis + 3) / 4), dim3(64, 4), 0, stream>>>(
            h, ci_dis, w_fc, b_fc, out + (size_t)kNDrug * kOut, kNDis);
    }
}

// Round 13
// 184.093 us; speedup vs baseline: 1.3133x; 1.0384x over previous
//
#include <hip/hip_runtime.h>

namespace {
constexpr int kNDrug = 50000;
constexpr int kNDis  = 50000;
constexpr int kE     = 800000;
constexpr int kR     = 2;
constexpr int kIn    = 2048;   // IN_UNITS
constexpr int kMsg   = 32;     // AGG_UNITS / 3
constexpr int kAgg   = 96;     // AGG_UNITS
constexpr int kOut   = 64;     // OUT_UNITS
constexpr int kBasis = 4;
constexpr float kSlope = 0.1f; // LeakyReLU slope
constexpr int kNTot  = kNDis + kNDrug;            // [0,kNDis)=dis nodes, rest drug nodes
constexpr int kBN    = 131;                       // nodes per bucket -> 764 blocks <= 768
                                                  // (3-resident x 256 CU, LDS 48KB) => zero tail
constexpr int kBNP   = 192;                       // padded counter count (wave scan, 3/lane)
constexpr int kNBuck = (kNTot + kBN - 1) / kBN;   // 764
constexpr int kSegCap = 4448;                     // entries/bucket (mean 4188, +4.6 sigma), 16-mult
constexpr int kFifoCap = 44;                      // LDS FIFO depth per bucket in bin_pass
constexpr int kFlushThr = 16;                     // flush unit = 16 entries = 64B; slack 28 -> ovf
                                                  // statistically never (round-7/8 lesson)
constexpr int kBinBlocks = 128;                   // binning blocks (1024 thr each)
constexpr int kOvfCap = 4096;                     // overflow list capacity
constexpr int kNPW   = 17;                        // ceil(kBN/8) nodes per wave in gather
constexpr int kSent  = 20;                        // sentinel pad (covers 5-stage dual-chain lookahead)
constexpr int kEPT   = 9;                         // entries per thread in prologue (ceil(4448/512))
constexpr unsigned kInvE = 0xFFFFFFFFu;           // invalid-entry sentinel for register staging
}

// ---------------- one-shot init: W = att@basis, cursors ----------------
__global__ __launch_bounds__(256) void setup_all(const float* __restrict__ att,
                                                 const float* __restrict__ basis,
                                                 float* __restrict__ W,
                                                 int* __restrict__ bcur,
                                                 int* __restrict__ ovfCnt) {
    constexpr int per_r = kIn * kMsg;
    const int blk = blockIdx.x;
    const int t = threadIdx.x;
    if (blk < 512) {                       // W: 2*2048*32 = 131072 elems
        int idx = blk * 256 + t;
        int r = idx / per_r;
        int ic = idx - r * per_r;
        float acc = 0.f;
#pragma unroll
        for (int b = 0; b < kBasis; ++b)
            acc += att[r * kBasis + b] * basis[b * per_r + ic];
        W[idx] = acc;
    } else {                               // blocks 512..515: bcur init; 512/t0: ovfCnt
        int i = (blk - 512) * 256 + t;
        if (i < kNBuck) bcur[i] = i * kSegCap;
        if (blk == 512 && t == 0) *ovfCnt = 0;
    }
}

// ---------------- packed node table: pk[g] = {i0*32, i1*32, i2*32, bits(cj)} ----------------
__global__ __launch_bounds__(256) void pack_nodes(const int* __restrict__ drug_idx,
                                                  const int* __restrict__ dis_idx,
                                                  const float* __restrict__ cj_drug,
                                                  const float* __restrict__ cj_dis,
                                                  uint4* __restrict__ pk_drug,
                                                  uint4* __restrict__ pk_dis) {
    int g = blockIdx.x * 256 + threadIdx.x;
    if (g < kNDrug) {
        pk_drug[g] = make_uint4((unsigned)drug_idx[3 * g] << 5,
                                (unsigned)drug_idx[3 * g + 1] << 5,
                                (unsigned)drug_idx[3 * g + 2] << 5,
                                __float_as_uint(cj_drug[g]));
    }
    if (g < kNDis) {
        pk_dis[g] = make_uint4((unsigned)dis_idx[3 * g] << 5,
                               (unsigned)dis_idx[3 * g + 1] << 5,
                               (unsigned)dis_idx[3 * g + 2] << 5,
                               __float_as_uint(cj_dis[g]));
    }
}

// ---------------- LDS-FIFO binning (128 blocks x 1024 threads) ----------------
// entry = gnode (16b) | rating (bit16) | node-rel-in-bucket (bits 17..24)
__global__ __launch_bounds__(1024) void bin_pass(const int* __restrict__ esrc,
                                                 const int* __restrict__ edst,
                                                 int* __restrict__ bcur,
                                                 unsigned* __restrict__ bin,
                                                 int* __restrict__ ovfCnt,
                                                 unsigned* __restrict__ ovfE,
                                                 int* __restrict__ ovfB) {
    __shared__ unsigned fifo[kNBuck][kFifoCap];  // 134.5 KB
    __shared__ int fcnt[kNBuck];
    __shared__ int flList[kNBuck], flAmt[kNBuck], flPos[kNBuck];
    __shared__ int nFl;

    const int t = threadIdx.x;
    for (int i = t; i < kNBuck; i += 1024) fcnt[i] = 0;

    const int total = kR * kE;
    const int per = (total + kBinBlocks - 1) / kBinBlocks;   // 12500 edges
    const int e0 = blockIdx.x * per;
    const int e1 = (e0 + per < total) ? e0 + per : total;
    __syncthreads();

    auto place = [&](int node, int gn, int r) {
        int bb = node / kBN;
        int rel = node - bb * kBN;
        unsigned ent = (unsigned)gn | ((unsigned)r << 16) | ((unsigned)rel << 17);
        int pos = atomicAdd(&fcnt[bb], 1);
        if (pos < kFifoCap) {
            fifo[bb][pos] = ent;
        } else {  // statistically never (slack 28)
            int s = atomicAdd(ovfCnt, 1);
            if (s < kOvfCap) { ovfE[s] = ent; ovfB[s] = bb; }
        }
    };

    for (int base = e0; base < e1; base += 1024) {
        int idx = base + t;
        if (idx < e1) {
            int r = (idx >= kE) ? 1 : 0;
            int src = esrc[idx], dst = edst[idx];
            place(dst, src, r);            // dis-side entry
            place(kNDis + src, dst, r);    // drug-side entry
        }
        if (t == 0) nFl = 0;
        __syncthreads();
        for (int bb = t; bb < kNBuck; bb += 1024) {
            int c = fcnt[bb]; if (c > kFifoCap) c = kFifoCap;
            if (c >= kFlushThr) {
                int slot = atomicAdd(&nFl, 1);
                flList[slot] = bb;
                flPos[slot] = atomicAdd(&bcur[bb], kFlushThr);   // stays 16-aligned
            }
        }
        __syncthreads();
        {   // 64B-unit copies LDS -> bin (16-lane groups)
            const int n = nFl;
            const int grp = t >> 4, ln = t & 15;
            for (int it = grp; it < n; it += 64) {
                int bb = flList[it], gp = flPos[it];
                int capEnd = bb * kSegCap + kSegCap;
                unsigned ent = fifo[bb][ln];
                int d = gp + ln;
                if (d < capEnd) bin[d] = ent;
                else { int s = atomicAdd(ovfCnt, 1);
                       if (s < kOvfCap) { ovfE[s] = ent; ovfB[s] = bb; } }
            }
        }
        __syncthreads();
        for (int bb = t; bb < kNBuck; bb += 1024) {
            int c = fcnt[bb]; if (c > kFifoCap) c = kFifoCap;
            if (c >= kFlushThr) {
                for (int j = kFlushThr; j < c; ++j) fifo[bb][j - kFlushThr] = fifo[bb][j];
                fcnt[bb] = c - kFlushThr;
            } else {
                fcnt[bb] = c;
            }
        }
        __syncthreads();
    }

    // final drain: partial flushes of the <=kFifoCap-entry tails
    if (t == 0) nFl = 0;
    __syncthreads();
    for (int bb = t; bb < kNBuck; bb += 1024) {
        int c = fcnt[bb]; if (c > kFifoCap) c = kFifoCap;
        if (c) {
            int slot = atomicAdd(&nFl, 1);
            flList[slot] = bb; flAmt[slot] = c;
            flPos[slot] = atomicAdd(&bcur[bb], c);
        }
    }
    __syncthreads();
    const int n = nFl;
    const int grp = t >> 4, ln = t & 15;
    for (int it = grp; it < n; it += 64) {
        int bb = flList[it], f = flAmt[it], gp = flPos[it];
        int capEnd = bb * kSegCap + kSegCap;
        for (int j = ln; j < f; j += 16) {
            unsigned ent = fifo[bb][j];
            int d = gp + j;
            if (d < capEnd) bin[d] = ent;
            else { int s = atomicAdd(ovfCnt, 1);
                   if (s < kOvfCap) { ovfE[s] = ent; ovfB[s] = bb; } }
        }
    }
}

// ---------------- re-insert overflow entries into bin where room remains ----------------
__global__ __launch_bounds__(256) void ovf_drain(int* __restrict__ bcur,
                                                 unsigned* __restrict__ bin,
                                                 const int* __restrict__ ovfCnt,
                                                 const unsigned* __restrict__ ovfE,
                                                 int* __restrict__ ovfB) {
    int n = *ovfCnt; if (n > kOvfCap) n = kOvfCap;
    int i = blockIdx.x * 256 + threadIdx.x;
    if (i >= n) return;
    int bb = ovfB[i];
    int pos = atomicAdd(&bcur[bb], 1);
    if (pos < bb * kSegCap + kSegCap) { bin[pos] = ovfE[i]; ovfB[i] = -1; }
}

// ---- packed dual-chain 5-stage pipeline pieces ----
#define PK_PRO(sp_, OFS_, e2_, e3_, P2_, c0_, c1_, w00_, w01_, w02_, w10_, w11_, w12_)  \
  { unsigned e0_ = (sp_)[OFS_];                                                         \
    unsigned e1_ = (sp_)[(OFS_) + 4];                                                   \
    e2_ = (sp_)[(OFS_) + 8];                                                            \
    e3_ = (sp_)[(OFS_) + 12];                                                           \
    uint4 P0_ = pkp[e0_ & 0xffffu];                                                     \
    uint4 P1_ = pkp[e1_ & 0xffffu];                                                     \
    P2_ = pkp[e2_ & 0xffffu];                                                           \
    c0_ = __uint_as_float(P0_.w);                                                       \
    c1_ = __uint_as_float(P1_.w);                                                       \
    const float* W0_ = W + (((e0_ >> 16) & 1u) * (unsigned)(kIn * kMsg));               \
    const float* W1_ = W + (((e1_ >> 16) & 1u) * (unsigned)(kIn * kMsg));               \
    w00_ = W0_[P0_.x + fl]; w01_ = W0_[P0_.y + fl]; w02_ = W0_[P0_.z + fl];             \
    w10_ = W1_[P1_.x + fl]; w11_ = W1_[P1_.y + fl]; w12_ = W1_[P1_.z + fl]; }

#define PK_BODY(sp_, OFS_, tt_, e2_, e3_, P2_, c0_, c1_, w00_, w01_, w02_, w10_, w11_, w12_, a0_, a1_, a2_) \
  { unsigned e4_ = (sp_)[(OFS_) + 4*(tt_) + 16];                                        \
    uint4 P3_ = pkp[e3_ & 0xffffu];                                                     \
    const float* W2_ = W + (((e2_ >> 16) & 1u) * (unsigned)(kIn * kMsg));               \
    float w20_ = W2_[P2_.x + fl];                                                       \
    float w21_ = W2_[P2_.y + fl];                                                       \
    float w22_ = W2_[P2_.z + fl];                                                       \
    float c2_ = __uint_as_float(P2_.w);                                                 \
    a0_ = fmaf(w00_, c0_, a0_); a1_ = fmaf(w01_, c0_, a1_); a2_ = fmaf(w02_, c0_, a2_); \
    e2_ = e3_; e3_ = e4_; P2_ = P3_;                                                    \
    c0_ = c1_; c1_ = c2_;                                                               \
    w00_ = w10_; w01_ = w11_; w02_ = w12_;                                              \
    w10_ = w20_; w11_ = w21_; w12_ = w22_; }

// ---------------- pk gather: 1-read prologue, wave scan, hbuf epilogue ----------------
// One 512-thread block per 131-node bucket; LDS ~= 48.1 KB -> 3 blocks/CU;
// 764 blocks <= 768 slots -> zero tail (the R12 regression: 981 blocks on
// 768 slots = 213-block tail round at ~28% fill).
__global__ __launch_bounds__(512, 6) void gather_pk(
        const unsigned* __restrict__ bin,
        const int* __restrict__ bcur,
        const int* __restrict__ ovfCnt,
        const unsigned* __restrict__ ovfE,
        const int* __restrict__ ovfB,
        const float* __restrict__ W,
        const uint4* __restrict__ pk_drug, const uint4* __restrict__ pk_dis,
        const float* __restrict__ ci_drug, const float* __restrict__ ci_dis,
        const float* __restrict__ w_fc, const float* __restrict__ b_fc,
        float* __restrict__ out) {
    __shared__ float ws[kAgg * kOut];              // 24 KB
    __shared__ float bs[kOut];
    __shared__ unsigned stage[kSegCap + kSent];    // 17.9 KB
    __shared__ int h[kBNP], lb[kBNP];
    __shared__ int sbuf[kBNP];
    __shared__ float hbuf[8][kAgg];                // 3 KB, one row per wave
    __shared__ int sOvf;

    const int t = threadIdx.x;
    const int b = blockIdx.x;
    {   // ws staged via float4 (3 coalesced iterations)
        const float4* wf4 = (const float4*)w_fc;
        float4* ws4 = (float4*)ws;
        for (int i = t; i < kAgg * kOut / 4; i += 512) ws4[i] = wf4[i];
    }
    if (t < kOut) bs[t] = b_fc[t];
    if (t < kBNP) h[t] = 0;
    if (t == 0) sOvf = (ovfCnt[0] < kOvfCap) ? ovfCnt[0] : kOvfCap;

    const int sb = b * kSegCap;
    __syncthreads();
    int seg = bcur[b] - sb;
    if (seg > kSegCap) seg = kSegCap;

    // ---- single-pass prologue: read entries into registers, histogram ----
    unsigned myE[kEPT];                            // static indices only (rule #20)
#pragma unroll
    for (int k = 0; k < kEPT; ++k) {
        int i = t + k * 512;
        myE[k] = (i < seg) ? bin[sb + i] : kInvE;
    }
#pragma unroll
    for (int k = 0; k < kEPT; ++k)
        if (myE[k] != kInvE) atomicAdd(&h[myE[k] >> 17], 1);
    __syncthreads();

    // ---- wave-0 shfl scan of 192 counters (3 per lane) ----
    if (t < 64) {
        int v0 = h[3 * t], v1 = h[3 * t + 1], v2 = h[3 * t + 2];
        int s = v0 + v1 + v2;
#pragma unroll
        for (int o = 1; o < 64; o <<= 1) {
            int x = __shfl_up(s, o);
            if (t >= o) s += x;
        }
        int ex = s - (v0 + v1 + v2);
        lb[3 * t] = ex;           lb[3 * t + 1] = ex + v0;       lb[3 * t + 2] = ex + v0 + v1;
        sbuf[3 * t] = ex;         sbuf[3 * t + 1] = ex + v0;     sbuf[3 * t + 2] = ex + v0 + v1;
    }
    if (t < kSent) stage[kSegCap + t] = 0;  // pre-clear pad region top
    __syncthreads();

    // ---- scatter from registers into per-node-ordered LDS staging ----
#pragma unroll
    for (int k = 0; k < kEPT; ++k)
        if (myE[k] != kInvE) {
            int pos = atomicAdd(&sbuf[myE[k] >> 17], 1);
            stage[pos] = myE[k];
        }
    if (t < kSent) stage[seg + t] = 0;      // sentinel entries (loaded, never FMA'd)
    __syncthreads();

    const int wid  = t >> 6;
    const int lane = t & 63;
    const int half = lane >> 5;
    const int fl   = lane & 31;

    for (int i = 0; i < kNPW; ++i) {
        const int nl = wid * kNPW + i;
        if (nl >= kBN) break;    // wave-uniform
        const int g  = b * kBN + nl;
        if (g >= kNTot) break;   // wave-uniform; no block syncs below

        const uint4* pkp;
        float civ;
        size_t orow;
        if (g < kNDis) {         // dis dst node: gathers DRUG feats
            pkp = pk_drug; civ = ci_dis[g];
            orow = (size_t)(kNDrug + g);
        } else {                 // drug dst node: gathers DIS feats
            pkp = pk_dis;  civ = ci_drug[g - kNDis];
            orow = (size_t)(g - kNDis);
        }

        const int base = lb[nl];
        const int deg  = h[nl];
        const unsigned* sp = stage + base + half;
        const int n  = (deg - half + 1) >> 1;   // this half's entry count
        const int nA = (n + 1) >> 1;            // chain A: half-entries 0,2,4,..
        const int nB = n >> 1;                  // chain B: half-entries 1,3,5,..

        float a0A = 0.f, a1A = 0.f, a2A = 0.f;
        float a0B = 0.f, a1B = 0.f, a2B = 0.f;
        unsigned eA2, eA3, eB2, eB3;
        uint4 PA2, PB2;
        float cA0, cA1, cB0, cB1;
        float wA00, wA01, wA02, wA10, wA11, wA12;
        float wB00, wB01, wB02, wB10, wB11, wB12;

        PK_PRO(sp, 0, eA2, eA3, PA2, cA0, cA1, wA00, wA01, wA02, wA10, wA11, wA12);
        PK_PRO(sp, 2, eB2, eB3, PB2, cB0, cB1, wB00, wB01, wB02, wB10, wB11, wB12);

        int tt = 0;
        for (; tt < nB; ++tt) {
            PK_BODY(sp, 0, tt, eA2, eA3, PA2, cA0, cA1,
                    wA00, wA01, wA02, wA10, wA11, wA12, a0A, a1A, a2A);
            PK_BODY(sp, 2, tt, eB2, eB3, PB2, cB0, cB1,
                    wB00, wB01, wB02, wB10, wB11, wB12, a0B, a1B, a2B);
        }
        if (tt < nA) {
            PK_BODY(sp, 0, tt, eA2, eA3, PA2, cA0, cA1,
                    wA00, wA01, wA02, wA10, wA11, wA12, a0A, a1A, a2A);
        }

        float a0 = a0A + a0B, a1 = a1A + a1B, a2 = a2A + a2B;

        if (sOvf > 0) {          // statistically never non-zero
            for (int j = half; j < sOvf; j += 2) {
                int bb = ovfB[j];
                if (bb == b && (int)(ovfE[j] >> 17) == nl) {
                    unsigned e = ovfE[j];
                    uint4 P = pkp[e & 0xffffu];
                    const float* Wr = W + (((e >> 16) & 1u) * (unsigned)(kIn * kMsg));
                    float c = __uint_as_float(P.w);
                    a0 = fmaf(Wr[P.x + fl], c, a0);
                    a1 = fmaf(Wr[P.y + fl], c, a1);
                    a2 = fmaf(Wr[P.z + fl], c, a2);
                }
            }
        }

        a0 += __shfl_xor(a0, 32);
        a1 += __shfl_xor(a1, 32);
        a2 += __shfl_xor(a2, 32);

        a0 *= civ; a1 *= civ; a2 *= civ;
        a0 = (a0 >= 0.f) ? a0 : kSlope * a0;
        a1 = (a1 >= 0.f) ? a1 : kSlope * a1;
        a2 = (a2 >= 0.f) ? a2 : kSlope * a2;

        // ---- FC epilogue: per-wave hbuf row (same-wave LDS write->read, in-order DS) ----
        if (half == 0) {
            hbuf[wid][fl]          = a0;
            hbuf[wid][kMsg + fl]   = a1;
            hbuf[wid][2*kMsg + fl] = a2;
        }
        const float4* hv = (const float4*)(&hbuf[wid][0]);
        float acc0 = bs[lane], acc1 = 0.f, acc2 = 0.f;
#pragma unroll
        for (int q = 0; q < 8; ++q) {
            float4 h4 = hv[q];
            acc0 = fmaf(h4.x, ws[(4*q    ) * kOut + lane], acc0);
            acc0 = fmaf(h4.y, ws[(4*q + 1) * kOut + lane], acc0);
            acc0 = fmaf(h4.z, ws[(4*q + 2) * kOut + lane], acc0);
            acc0 = fmaf(h4.w, ws[(4*q + 3) * kOut + lane], acc0);
        }
#pragma unroll
        for (int q = 8; q < 16; ++q) {
            float4 h4 = hv[q];
            acc1 = fmaf(h4.x, ws[(4*q    ) * kOut + lane], acc1);
            acc1 = fmaf(h4.y, ws[(4*q + 1) * kOut + lane], acc1);
            acc1 = fmaf(h4.z, ws[(4*q + 2) * kOut + lane], acc1);
            acc1 = fmaf(h4.w, ws[(4*q + 3) * kOut + lane], acc1);
        }
#pragma unroll
        for (int q = 16; q < 24; ++q) {
            float4 h4 = hv[q];
            acc2 = fmaf(h4.x, ws[(4*q    ) * kOut + lane], acc2);
            acc2 = fmaf(h4.y, ws[(4*q + 1) * kOut + lane], acc2);
            acc2 = fmaf(h4.z, ws[(4*q + 2) * kOut + lane], acc2);
            acc2 = fmaf(h4.w, ws[(4*q + 3) * kOut + lane], acc2);
        }
        out[orow * kOut + lane] = acc0 + acc1 + acc2;
    }
}

// ---------------- fallback path (R1 atomic scatter, tiny-ws only) ----------------
__global__ __launch_bounds__(256) void build_W_fb(const float* __restrict__ att,
                                                  const float* __restrict__ basis,
                                                  float* __restrict__ W) {
    constexpr int per_r = kIn * kMsg;
    int idx = blockIdx.x * blockDim.x + threadIdx.x;
    if (idx >= kR * per_r) return;
    int r = idx / per_r;
    int ic = idx - r * per_r;
    float acc = 0.f;
#pragma unroll
    for (int b = 0; b < kBasis; ++b)
        acc += att[r * kBasis + b] * basis[b * per_r + ic];
    W[idx] = acc;
}

__global__ __launch_bounds__(256) void edge_scatter(
        const float* __restrict__ W,
        const int* __restrict__ gnode,
        const int* __restrict__ snode,
        const int* __restrict__ fidx,
        const float* __restrict__ cj,
        float* __restrict__ h) {
    const int r = blockIdx.y;
    long tid = (long)blockIdx.x * blockDim.x + threadIdx.x;
    const int lane = (int)(tid & 31);
    const long e = tid >> 5;
    if (e >= kE) return;
    const int g = gnode[(long)r * kE + e];
    const int s = snode[(long)r * kE + e];
    const int i0 = fidx[g * 3 + 0];
    const int i1 = fidx[g * 3 + 1];
    const int i2 = fidx[g * 3 + 2];
    const float c = cj[g];
    const float* Wr = W + (size_t)r * kIn * kMsg;
    float* outp = h + (size_t)s * kAgg;
    atomicAdd(&outp[lane],            Wr[(size_t)i0 * kMsg + lane] * c);
    atomicAdd(&outp[kMsg + lane],     Wr[(size_t)i1 * kMsg + lane] * c);
    atomicAdd(&outp[2 * kMsg + lane], Wr[(size_t)i2 * kMsg + lane] * c);
}

__global__ __launch_bounds__(256) void fc_fused(const float* __restrict__ h,
                                                const float* __restrict__ ci,
                                                const float* __restrict__ w_fc,
                                                const float* __restrict__ b_fc,
                                                float* __restrict__ out, int nrows) {
    __shared__ float ws[kAgg * kOut];
    __shared__ float bs[kOut];
    const int lt = threadIdx.y * blockDim.x + threadIdx.x;
    for (int i = lt; i < kAgg * kOut; i += blockDim.x * blockDim.y)
        ws[i] = w_fc[i];
    if (lt < kOut) bs[lt] = b_fc[lt];
    __syncthreads();
    const int row = blockIdx.x * blockDim.y + threadIdx.y;
    if (row >= nrows) return;
    const int col = threadIdx.x;
    const float c = ci[row];
    const float* hr = h + (size_t)row * kAgg;
    float acc = bs[col];
#pragma unroll 8
    for (int k = 0; k < kAgg; ++k) {
        float a = hr[k] * c;
        a = (a >= 0.f) ? a : kSlope * a;
        acc += a * ws[k * kOut + col];
    }
    out[(size_t)row * kOut + col] = acc;
}

extern "C" void kernel_launch(void* const* d_in, const int* in_sizes, int n_in,
                              void* d_out, int out_size, void* d_ws, size_t ws_size,
                              hipStream_t stream) {
    const int*   drug_idx = (const int*)d_in[0];
    const int*   dis_idx  = (const int*)d_in[1];
    const int*   edge_src = (const int*)d_in[2];
    const int*   edge_dst = (const int*)d_in[3];
    const float* cj_drug  = (const float*)d_in[4];
    const float* ci_drug  = (const float*)d_in[5];
    const float* cj_dis   = (const float*)d_in[6];
    const float* ci_dis   = (const float*)d_in[7];
    const float* att      = (const float*)d_in[8];
    const float* basis    = (const float*)d_in[9];
    const float* w_fc     = (const float*)d_in[10];
    const float* b_fc     = (const float*)d_in[11];
    float* out = (float*)d_out;

    auto align256 = [](size_t x) { return (x + 255) & ~(size_t)255; };
    const size_t Wb    = align256((size_t)kR * kIn * kMsg * sizeof(float));     // 512 KB
    const size_t pkB   = align256((size_t)kNDrug * sizeof(uint4));              // 800 KB each
    const size_t bcB   = align256((size_t)kNBuck * sizeof(int));
    const size_t ocB   = align256(sizeof(int));
    const size_t oeB   = align256((size_t)kOvfCap * sizeof(unsigned));          // 16 KB
    const size_t obB   = align256((size_t)kOvfCap * sizeof(int));               // 16 KB
    const size_t binB  = align256((size_t)kNBuck * kSegCap * sizeof(unsigned)); // ~13.6 MB
    const size_t needBase = Wb + bcB + ocB + oeB + obB + binB;                  // ~14.2 MB
    const size_t needPk   = needBase + 2 * pkB;                                 // ~15.8 MB

    if (ws_size >= needPk) {
        char* p = (char*)d_ws;
        float*    W       = (float*)p;     p += Wb;
        uint4*    pk_drug = (uint4*)p;     p += pkB;
        uint4*    pk_dis  = (uint4*)p;     p += pkB;
        int*      bcur   = (int*)p;        p += bcB;
        int*      ovfCnt = (int*)p;        p += ocB;
        unsigned* ovfE   = (unsigned*)p;   p += oeB;
        int*      ovfB   = (int*)p;        p += obB;
        unsigned* bin    = (unsigned*)p;

        setup_all<<<dim3(516), 256, 0, stream>>>(att, basis, W, bcur, ovfCnt);
        pack_nodes<<<dim3((kNDrug + 255) / 256), 256, 0, stream>>>(
            drug_idx, dis_idx, cj_drug, cj_dis, pk_drug, pk_dis);
        bin_pass<<<dim3(kBinBlocks), 1024, 0, stream>>>(edge_src, edge_dst,
                                                        bcur, bin, ovfCnt, ovfE, ovfB);
        ovf_drain<<<dim3((kOvfCap + 255) / 256), 256, 0, stream>>>(bcur, bin,
                                                                   ovfCnt, ovfE, ovfB);
        gather_pk<<<dim3(kNBuck), 512, 0, stream>>>(bin, bcur, ovfCnt, ovfE, ovfB,
                                                    W, pk_drug, pk_dis,
                                                    ci_drug, ci_dis,
                                                    w_fc, b_fc, out);
    } else {
        // fallback: R1 phased atomic-scatter path
        char* p = (char*)d_ws;
        float* W = (float*)p;
        build_W_fb<<<dim3((kR * kIn * kMsg + 255) / 256), 256, 0, stream>>>(att, basis, W);
        const size_t hB = (size_t)kNDrug * kAgg * sizeof(float);
        float* h = (float*)((char*)d_ws + Wb);
        const int scat_blocks = (int)(((long)kE * 32 + 255) / 256);
        const dim3 scat_grid(scat_blocks, kR);
        hipMemsetAsync(h, 0, hB, stream);
        edge_scatter<<<scat_grid, 256, 0, stream>>>(W, edge_dst, edge_src,
                                                    dis_idx, cj_dis, h);
        fc_fused<<<dim3((kNDrug + 3) / 4), dim3(64, 4), 0, stream>>>(
            h, ci_drug, w_fc, b_fc, out, kNDrug);
        hipMemsetAsync(h, 0, hB, stream);
        edge_scatter<<<scat_grid, 256, 0, stream>>>(W, edge_src, edge_dst,
                                                    drug_idx, cj_drug, h);
        fc_fused<<<dim3((kNDis + 3) / 4), dim3(64, 4), 0, stream>>>(
            h, ci_dis, w_fc, b_fc, out + (size_t)kNDrug * kOut, kNDis);
    }
}

// Round 14
// 173.675 us; speedup vs baseline: 1.3921x; 1.0600x over previous
//
#include <hip/hip_runtime.h>

namespace {
constexpr int kNDrug = 50000;
constexpr int kNDis  = 50000;
constexpr int kE     = 800000;
constexpr int kR     = 2;
constexpr int kIn    = 2048;   // IN_UNITS
constexpr int kMsg   = 32;     // AGG_UNITS / 3
constexpr int kAgg   = 96;     // AGG_UNITS
constexpr int kOut   = 64;     // OUT_UNITS
constexpr int kBasis = 4;
constexpr float kSlope = 0.1f; // LeakyReLU slope
constexpr int kNTot  = kNDis + kNDrug;            // [0,kNDis)=dis nodes, rest drug nodes
constexpr int kBN    = 131;                       // nodes per bucket -> 764 blocks <= 768
                                                  // (3-resident x 256 CU, LDS 48KB) => zero tail
constexpr int kBNP   = 192;                       // padded counter count (wave scan, 3/lane)
constexpr int kNBuck = (kNTot + kBN - 1) / kBN;   // 764
constexpr int kSegCap = 4448;                     // entries/bucket (mean 4188, +4.6 sigma), 16-mult
constexpr int kFifoCap = 44;                      // LDS FIFO depth per bucket in bin_pass
constexpr int kFlushThr = 16;                     // flush unit = 16 entries = 64B; slack 28 -> ovf
                                                  // statistically never (round-7/8 lesson)
constexpr int kBinBlocks = 128;                   // binning blocks (1024 thr each)
constexpr int kOvfCap = 4096;                     // overflow list capacity
constexpr int kNPW   = 17;                        // ceil(kBN/8) nodes per wave in gather
constexpr int kSent  = 20;                        // sentinel pad (covers 5-stage dual-chain lookahead)
constexpr int kEPT   = 9;                         // entries per thread in prologue (ceil(4448/512))
constexpr unsigned kInvE = 0xFFFFFFFFu;           // invalid-entry sentinel for register staging
// init_all block-range partition:
constexpr int kWB    = 512;                       // W-build blocks (131072 / 256)
constexpr int kPkBlk = (kNDrug + 255) / 256;      // 196 pack blocks
constexpr int kCurBlk = (kNBuck + 255) / 256;     // 3 cursor blocks
}

// ---------------- merged one-shot init: W = att@basis, pk tables, cursors ----------------
__global__ __launch_bounds__(256) void init_all(const float* __restrict__ att,
                                                const float* __restrict__ basis,
                                                const int* __restrict__ drug_idx,
                                                const int* __restrict__ dis_idx,
                                                const float* __restrict__ cj_drug,
                                                const float* __restrict__ cj_dis,
                                                float* __restrict__ W,
                                                uint4* __restrict__ pk_drug,
                                                uint4* __restrict__ pk_dis,
                                                int* __restrict__ bcur,
                                                int* __restrict__ ovfCnt) {
    constexpr int per_r = kIn * kMsg;
    const int blk = blockIdx.x;
    const int t = threadIdx.x;
    if (blk < kWB) {                        // W: 2*2048*32 = 131072 elems
        int idx = blk * 256 + t;
        int r = idx / per_r;
        int ic = idx - r * per_r;
        float acc = 0.f;
#pragma unroll
        for (int b = 0; b < kBasis; ++b)
            acc += att[r * kBasis + b] * basis[b * per_r + ic];
        W[idx] = acc;
    } else if (blk < kWB + kPkBlk) {        // packed node tables
        int g = (blk - kWB) * 256 + t;
        if (g < kNDrug) {
            pk_drug[g] = make_uint4((unsigned)drug_idx[3 * g] << 5,
                                    (unsigned)drug_idx[3 * g + 1] << 5,
                                    (unsigned)drug_idx[3 * g + 2] << 5,
                                    __float_as_uint(cj_drug[g]));
        }
        if (g < kNDis) {
            pk_dis[g] = make_uint4((unsigned)dis_idx[3 * g] << 5,
                                   (unsigned)dis_idx[3 * g + 1] << 5,
                                   (unsigned)dis_idx[3 * g + 2] << 5,
                                   __float_as_uint(cj_dis[g]));
        }
    } else {                                // segment cursors + ovf counter
        int i = (blk - kWB - kPkBlk) * 256 + t;
        if (i < kNBuck) bcur[i] = i * kSegCap;
        if (blk == kWB + kPkBlk && t == 0) *ovfCnt = 0;
    }
}

// ---------------- LDS-FIFO binning (128 blocks x 1024 threads) ----------------
// entry = gnode (16b) | rating (bit16) | node-rel-in-bucket (bits 17..24)
__global__ __launch_bounds__(1024) void bin_pass(const int* __restrict__ esrc,
                                                 const int* __restrict__ edst,
                                                 int* __restrict__ bcur,
                                                 unsigned* __restrict__ bin,
                                                 int* __restrict__ ovfCnt,
                                                 unsigned* __restrict__ ovfE,
                                                 int* __restrict__ ovfB) {
    __shared__ unsigned fifo[kNBuck][kFifoCap];  // 134.5 KB
    __shared__ int fcnt[kNBuck];
    __shared__ int flList[kNBuck], flAmt[kNBuck], flPos[kNBuck];
    __shared__ int nFl;

    const int t = threadIdx.x;
    for (int i = t; i < kNBuck; i += 1024) fcnt[i] = 0;

    const int total = kR * kE;
    const int per = (total + kBinBlocks - 1) / kBinBlocks;   // 12500 edges
    const int e0 = blockIdx.x * per;
    const int e1 = (e0 + per < total) ? e0 + per : total;
    __syncthreads();

    auto place = [&](int node, int gn, int r) {
        int bb = node / kBN;
        int rel = node - bb * kBN;
        unsigned ent = (unsigned)gn | ((unsigned)r << 16) | ((unsigned)rel << 17);
        int pos = atomicAdd(&fcnt[bb], 1);
        if (pos < kFifoCap) {
            fifo[bb][pos] = ent;
        } else {  // statistically never (slack 28)
            int s = atomicAdd(ovfCnt, 1);
            if (s < kOvfCap) { ovfE[s] = ent; ovfB[s] = bb; }
        }
    };

    for (int base = e0; base < e1; base += 1024) {
        int idx = base + t;
        if (idx < e1) {
            int r = (idx >= kE) ? 1 : 0;
            int src = esrc[idx], dst = edst[idx];
            place(dst, src, r);            // dis-side entry
            place(kNDis + src, dst, r);    // drug-side entry
        }
        if (t == 0) nFl = 0;
        __syncthreads();
        for (int bb = t; bb < kNBuck; bb += 1024) {
            int c = fcnt[bb]; if (c > kFifoCap) c = kFifoCap;
            if (c >= kFlushThr) {
                int slot = atomicAdd(&nFl, 1);
                flList[slot] = bb;
                flPos[slot] = atomicAdd(&bcur[bb], kFlushThr);   // stays 16-aligned
            }
        }
        __syncthreads();
        {   // 64B-unit copies LDS -> bin (16-lane groups)
            const int n = nFl;
            const int grp = t >> 4, ln = t & 15;
            for (int it = grp; it < n; it += 64) {
                int bb = flList[it], gp = flPos[it];
                int capEnd = bb * kSegCap + kSegCap;
                unsigned ent = fifo[bb][ln];
                int d = gp + ln;
                if (d < capEnd) bin[d] = ent;
                else { int s = atomicAdd(ovfCnt, 1);
                       if (s < kOvfCap) { ovfE[s] = ent; ovfB[s] = bb; } }
            }
        }
        __syncthreads();
        for (int bb = t; bb < kNBuck; bb += 1024) {
            int c = fcnt[bb]; if (c > kFifoCap) c = kFifoCap;
            if (c >= kFlushThr) {
                for (int j = kFlushThr; j < c; ++j) fifo[bb][j - kFlushThr] = fifo[bb][j];
                fcnt[bb] = c - kFlushThr;
            } else {
                fcnt[bb] = c;
            }
        }
        __syncthreads();
    }

    // final drain: partial flushes of the <=kFifoCap-entry tails
    if (t == 0) nFl = 0;
    __syncthreads();
    for (int bb = t; bb < kNBuck; bb += 1024) {
        int c = fcnt[bb]; if (c > kFifoCap) c = kFifoCap;
        if (c) {
            int slot = atomicAdd(&nFl, 1);
            flList[slot] = bb; flAmt[slot] = c;
            flPos[slot] = atomicAdd(&bcur[bb], c);
        }
    }
    __syncthreads();
    const int n = nFl;
    const int grp = t >> 4, ln = t & 15;
    for (int it = grp; it < n; it += 64) {
        int bb = flList[it], f = flAmt[it], gp = flPos[it];
        int capEnd = bb * kSegCap + kSegCap;
        for (int j = ln; j < f; j += 16) {
            unsigned ent = fifo[bb][j];
            int d = gp + j;
            if (d < capEnd) bin[d] = ent;
            else { int s = atomicAdd(ovfCnt, 1);
                   if (s < kOvfCap) { ovfE[s] = ent; ovfB[s] = bb; } }
        }
    }
}

// ---- packed dual-chain 5-stage pipeline pieces ----
#define PK_PRO(sp_, OFS_, e2_, e3_, P2_, c0_, c1_, w00_, w01_, w02_, w10_, w11_, w12_)  \
  { unsigned e0_ = (sp_)[OFS_];                                                         \
    unsigned e1_ = (sp_)[(OFS_) + 4];                                                   \
    e2_ = (sp_)[(OFS_) + 8];                                                            \
    e3_ = (sp_)[(OFS_) + 12];                                                           \
    uint4 P0_ = pkp[e0_ & 0xffffu];                                                     \
    uint4 P1_ = pkp[e1_ & 0xffffu];                                                     \
    P2_ = pkp[e2_ & 0xffffu];                                                           \
    c0_ = __uint_as_float(P0_.w);                                                       \
    c1_ = __uint_as_float(P1_.w);                                                       \
    const float* W0_ = W + (((e0_ >> 16) & 1u) * (unsigned)(kIn * kMsg));               \
    const float* W1_ = W + (((e1_ >> 16) & 1u) * (unsigned)(kIn * kMsg));               \
    w00_ = W0_[P0_.x + fl]; w01_ = W0_[P0_.y + fl]; w02_ = W0_[P0_.z + fl];             \
    w10_ = W1_[P1_.x + fl]; w11_ = W1_[P1_.y + fl]; w12_ = W1_[P1_.z + fl]; }

#define PK_BODY(sp_, OFS_, tt_, e2_, e3_, P2_, c0_, c1_, w00_, w01_, w02_, w10_, w11_, w12_, a0_, a1_, a2_) \
  { unsigned e4_ = (sp_)[(OFS_) + 4*(tt_) + 16];                                        \
    uint4 P3_ = pkp[e3_ & 0xffffu];                                                     \
    const float* W2_ = W + (((e2_ >> 16) & 1u) * (unsigned)(kIn * kMsg));               \
    float w20_ = W2_[P2_.x + fl];                                                       \
    float w21_ = W2_[P2_.y + fl];                                                       \
    float w22_ = W2_[P2_.z + fl];                                                       \
    float c2_ = __uint_as_float(P2_.w);                                                 \
    a0_ = fmaf(w00_, c0_, a0_); a1_ = fmaf(w01_, c0_, a1_); a2_ = fmaf(w02_, c0_, a2_); \
    e2_ = e3_; e3_ = e4_; P2_ = P3_;                                                    \
    c0_ = c1_; c1_ = c2_;                                                               \
    w00_ = w10_; w01_ = w11_; w02_ = w12_;                                              \
    w10_ = w20_; w11_ = w21_; w12_ = w22_; }

// ---------------- pk gather: 1-read prologue, wave scan, hbuf epilogue ----------------
// One 512-thread block per 131-node bucket; LDS ~= 48 KB -> 3 blocks/CU;
// 764 blocks <= 768 slots -> zero tail. Undrained ovf entries (statistically
// zero) are folded in via the per-node ovf scan -- no separate drain launch.
__global__ __launch_bounds__(512, 6) void gather_pk(
        const unsigned* __restrict__ bin,
        const int* __restrict__ bcur,
        const int* __restrict__ ovfCnt,
        const unsigned* __restrict__ ovfE,
        const int* __restrict__ ovfB,
        const float* __restrict__ W,
        const uint4* __restrict__ pk_drug, const uint4* __restrict__ pk_dis,
        const float* __restrict__ ci_drug, const float* __restrict__ ci_dis,
        const float* __restrict__ w_fc, const float* __restrict__ b_fc,
        float* __restrict__ out) {
    __shared__ float ws[kAgg * kOut];              // 24 KB
    __shared__ unsigned stage[kSegCap + kSent];    // 17.9 KB
    __shared__ int h[kBNP], lb[kBNP];
    __shared__ int sbuf[kBNP];
    __shared__ float hbuf[8][kAgg];                // 3 KB, one row per wave
    __shared__ int sOvf;

    const int t = threadIdx.x;
    const int b = blockIdx.x;
    {   // ws staged via float4 (3 coalesced iterations)
        const float4* wf4 = (const float4*)w_fc;
        float4* ws4 = (float4*)ws;
        for (int i = t; i < kAgg * kOut / 4; i += 512) ws4[i] = wf4[i];
    }
    if (t < kBNP) h[t] = 0;
    if (t == 0) sOvf = (ovfCnt[0] < kOvfCap) ? ovfCnt[0] : kOvfCap;
    const float bias = b_fc[t & 63];               // per-lane constant, register-resident

    const int sb = b * kSegCap;
    __syncthreads();
    int seg = bcur[b] - sb;
    if (seg > kSegCap) seg = kSegCap;

    // ---- single-pass prologue: read entries into registers, histogram ----
    unsigned myE[kEPT];                            // static indices only (rule #20)
#pragma unroll
    for (int k = 0; k < kEPT; ++k) {
        int i = t + k * 512;
        myE[k] = (i < seg) ? bin[sb + i] : kInvE;
    }
#pragma unroll
    for (int k = 0; k < kEPT; ++k)
        if (myE[k] != kInvE) atomicAdd(&h[myE[k] >> 17], 1);
    __syncthreads();

    // ---- wave-0 shfl scan of 192 counters (3 per lane) ----
    if (t < 64) {
        int v0 = h[3 * t], v1 = h[3 * t + 1], v2 = h[3 * t + 2];
        int s = v0 + v1 + v2;
#pragma unroll
        for (int o = 1; o < 64; o <<= 1) {
            int x = __shfl_up(s, o);
            if (t >= o) s += x;
        }
        int ex = s - (v0 + v1 + v2);
        lb[3 * t] = ex;           lb[3 * t + 1] = ex + v0;       lb[3 * t + 2] = ex + v0 + v1;
        sbuf[3 * t] = ex;         sbuf[3 * t + 1] = ex + v0;     sbuf[3 * t + 2] = ex + v0 + v1;
    }
    if (t < kSent) stage[kSegCap + t] = 0;  // pre-clear pad region top
    __syncthreads();

    // ---- scatter from registers into per-node-ordered LDS staging ----
#pragma unroll
    for (int k = 0; k < kEPT; ++k)
        if (myE[k] != kInvE) {
            int pos = atomicAdd(&sbuf[myE[k] >> 17], 1);
            stage[pos] = myE[k];
        }
    if (t < kSent) stage[seg + t] = 0;      // sentinel entries (loaded, never FMA'd)
    __syncthreads();

    const int wid  = t >> 6;
    const int lane = t & 63;
    const int half = lane >> 5;
    const int fl   = lane & 31;

    for (int i = 0; i < kNPW; ++i) {
        const int nl = wid * kNPW + i;
        if (nl >= kBN) break;    // wave-uniform
        const int g  = b * kBN + nl;
        if (g >= kNTot) break;   // wave-uniform; no block syncs below

        const uint4* pkp;
        float civ;
        size_t orow;
        if (g < kNDis) {         // dis dst node: gathers DRUG feats
            pkp = pk_drug; civ = ci_dis[g];
            orow = (size_t)(kNDrug + g);
        } else {                 // drug dst node: gathers DIS feats
            pkp = pk_dis;  civ = ci_drug[g - kNDis];
            orow = (size_t)(g - kNDis);
        }

        const int base = lb[nl];
        const int deg  = h[nl];
        const unsigned* sp = stage + base + half;
        const int n  = (deg - half + 1) >> 1;   // this half's entry count
        const int nA = (n + 1) >> 1;            // chain A: half-entries 0,2,4,..
        const int nB = n >> 1;                  // chain B: half-entries 1,3,5,..

        float a0A = 0.f, a1A = 0.f, a2A = 0.f;
        float a0B = 0.f, a1B = 0.f, a2B = 0.f;
        unsigned eA2, eA3, eB2, eB3;
        uint4 PA2, PB2;
        float cA0, cA1, cB0, cB1;
        float wA00, wA01, wA02, wA10, wA11, wA12;
        float wB00, wB01, wB02, wB10, wB11, wB12;

        PK_PRO(sp, 0, eA2, eA3, PA2, cA0, cA1, wA00, wA01, wA02, wA10, wA11, wA12);
        PK_PRO(sp, 2, eB2, eB3, PB2, cB0, cB1, wB00, wB01, wB02, wB10, wB11, wB12);

        int tt = 0;
        for (; tt < nB; ++tt) {
            PK_BODY(sp, 0, tt, eA2, eA3, PA2, cA0, cA1,
                    wA00, wA01, wA02, wA10, wA11, wA12, a0A, a1A, a2A);
            PK_BODY(sp, 2, tt, eB2, eB3, PB2, cB0, cB1,
                    wB00, wB01, wB02, wB10, wB11, wB12, a0B, a1B, a2B);
        }
        if (tt < nA) {
            PK_BODY(sp, 0, tt, eA2, eA3, PA2, cA0, cA1,
                    wA00, wA01, wA02, wA10, wA11, wA12, a0A, a1A, a2A);
        }

        float a0 = a0A + a0B, a1 = a1A + a1B, a2 = a2A + a2B;

        if (sOvf > 0) {          // statistically never non-zero
            for (int j = half; j < sOvf; j += 2) {
                int bb = ovfB[j];
                if (bb == b && (int)(ovfE[j] >> 17) == nl) {
                    unsigned e = ovfE[j];
                    uint4 P = pkp[e & 0xffffu];
                    const float* Wr = W + (((e >> 16) & 1u) * (unsigned)(kIn * kMsg));
                    float c = __uint_as_float(P.w);
                    a0 = fmaf(Wr[P.x + fl], c, a0);
                    a1 = fmaf(Wr[P.y + fl], c, a1);
                    a2 = fmaf(Wr[P.z + fl], c, a2);
                }
            }
        }

        a0 += __shfl_xor(a0, 32);
        a1 += __shfl_xor(a1, 32);
        a2 += __shfl_xor(a2, 32);

        a0 *= civ; a1 *= civ; a2 *= civ;
        a0 = (a0 >= 0.f) ? a0 : kSlope * a0;
        a1 = (a1 >= 0.f) ? a1 : kSlope * a1;
        a2 = (a2 >= 0.f) ? a2 : kSlope * a2;

        // ---- FC epilogue: per-wave hbuf row (same-wave LDS write->read, in-order DS) ----
        if (half == 0) {
            hbuf[wid][fl]          = a0;
            hbuf[wid][kMsg + fl]   = a1;
            hbuf[wid][2*kMsg + fl] = a2;
        }
        const float4* hv = (const float4*)(&hbuf[wid][0]);
        float acc0 = bias, acc1 = 0.f, acc2 = 0.f;
#pragma unroll
        for (int q = 0; q < 8; ++q) {
            float4 h4 = hv[q];
            acc0 = fmaf(h4.x, ws[(4*q    ) * kOut + lane], acc0);
            acc0 = fmaf(h4.y, ws[(4*q + 1) * kOut + lane], acc0);
            acc0 = fmaf(h4.z, ws[(4*q + 2) * kOut + lane], acc0);
            acc0 = fmaf(h4.w, ws[(4*q + 3) * kOut + lane], acc0);
        }
#pragma unroll
        for (int q = 8; q < 16; ++q) {
            float4 h4 = hv[q];
            acc1 = fmaf(h4.x, ws[(4*q    ) * kOut + lane], acc1);
            acc1 = fmaf(h4.y, ws[(4*q + 1) * kOut + lane], acc1);
            acc1 = fmaf(h4.z, ws[(4*q + 2) * kOut + lane], acc1);
            acc1 = fmaf(h4.w, ws[(4*q + 3) * kOut + lane], acc1);
        }
#pragma unroll
        for (int q = 16; q < 24; ++q) {
            float4 h4 = hv[q];
            acc2 = fmaf(h4.x, ws[(4*q    ) * kOut + lane], acc2);
            acc2 = fmaf(h4.y, ws[(4*q + 1) * kOut + lane], acc2);
            acc2 = fmaf(h4.z, ws[(4*q + 2) * kOut + lane], acc2);
            acc2 = fmaf(h4.w, ws[(4*q + 3) * kOut + lane], acc2);
        }
        out[orow * kOut + lane] = acc0 + acc1 + acc2;
    }
}

// ---------------- fallback path (R1 atomic scatter, tiny-ws only) ----------------
__global__ __launch_bounds__(256) void build_W_fb(const float* __restrict__ att,
                                                  const float* __restrict__ basis,
                                                  float* __restrict__ W) {
    constexpr int per_r = kIn * kMsg;
    int idx = blockIdx.x * blockDim.x + threadIdx.x;
    if (idx >= kR * per_r) return;
    int r = idx / per_r;
    int ic = idx - r * per_r;
    float acc = 0.f;
#pragma unroll
    for (int b = 0; b < kBasis; ++b)
        acc += att[r * kBasis + b] * basis[b * per_r + ic];
    W[idx] = acc;
}

__global__ __launch_bounds__(256) void edge_scatter(
        const float* __restrict__ W,
        const int* __restrict__ gnode,
        const int* __restrict__ snode,
        const int* __restrict__ fidx,
        const float* __restrict__ cj,
        float* __restrict__ h) {
    const int r = blockIdx.y;
    long tid = (long)blockIdx.x * blockDim.x + threadIdx.x;
    const int lane = (int)(tid & 31);
    const long e = tid >> 5;
    if (e >= kE) return;
    const int g = gnode[(long)r * kE + e];
    const int s = snode[(long)r * kE + e];
    const int i0 = fidx[g * 3 + 0];
    const int i1 = fidx[g * 3 + 1];
    const int i2 = fidx[g * 3 + 2];
    const float c = cj[g];
    const float* Wr = W + (size_t)r * kIn * kMsg;
    float* outp = h + (size_t)s * kAgg;
    atomicAdd(&outp[lane],            Wr[(size_t)i0 * kMsg + lane] * c);
    atomicAdd(&outp[kMsg + lane],     Wr[(size_t)i1 * kMsg + lane] * c);
    atomicAdd(&outp[2 * kMsg + lane], Wr[(size_t)i2 * kMsg + lane] * c);
}

__global__ __launch_bounds__(256) void fc_fused(const float* __restrict__ h,
                                                const float* __restrict__ ci,
                                                const float* __restrict__ w_fc,
                                                const float* __restrict__ b_fc,
                                                float* __restrict__ out, int nrows) {
    __shared__ float ws[kAgg * kOut];
    __shared__ float bs[kOut];
    const int lt = threadIdx.y * blockDim.x + threadIdx.x;
    for (int i = lt; i < kAgg * kOut; i += blockDim.x * blockDim.y)
        ws[i] = w_fc[i];
    if (lt < kOut) bs[lt] = b_fc[lt];
    __syncthreads();
    const int row = blockIdx.x * blockDim.y + threadIdx.y;
    if (row >= nrows) return;
    const int col = threadIdx.x;
    const float c = ci[row];
    const float* hr = h + (size_t)row * kAgg;
    float acc = bs[col];
#pragma unroll 8
    for (int k = 0; k < kAgg; ++k) {
        float a = hr[k] * c;
        a = (a >= 0.f) ? a : kSlope * a;
        acc += a * ws[k * kOut + col];
    }
    out[(size_t)row * kOut + col] = acc;
}

extern "C" void kernel_launch(void* const* d_in, const int* in_sizes, int n_in,
                              void* d_out, int out_size, void* d_ws, size_t ws_size,
                              hipStream_t stream) {
    const int*   drug_idx = (const int*)d_in[0];
    const int*   dis_idx  = (const int*)d_in[1];
    const int*   edge_src = (const int*)d_in[2];
    const int*   edge_dst = (const int*)d_in[3];
    const float* cj_drug  = (const float*)d_in[4];
    const float* ci_drug  = (const float*)d_in[5];
    const float* cj_dis   = (const float*)d_in[6];
    const float* ci_dis   = (const float*)d_in[7];
    const float* att      = (const float*)d_in[8];
    const float* basis    = (const float*)d_in[9];
    const float* w_fc     = (const float*)d_in[10];
    const float* b_fc     = (const float*)d_in[11];
    float* out = (float*)d_out;

    auto align256 = [](size_t x) { return (x + 255) & ~(size_t)255; };
    const size_t Wb    = align256((size_t)kR * kIn * kMsg * sizeof(float));     // 512 KB
    const size_t pkB   = align256((size_t)kNDrug * sizeof(uint4));              // 800 KB each
    const size_t bcB   = align256((size_t)kNBuck * sizeof(int));
    const size_t ocB   = align256(sizeof(int));
    const size_t oeB   = align256((size_t)kOvfCap * sizeof(unsigned));          // 16 KB
    const size_t obB   = align256((size_t)kOvfCap * sizeof(int));               // 16 KB
    const size_t binB  = align256((size_t)kNBuck * kSegCap * sizeof(unsigned)); // ~13.6 MB
    const size_t needBase = Wb + bcB + ocB + oeB + obB + binB;                  // ~14.2 MB
    const size_t needPk   = needBase + 2 * pkB;                                 // ~15.8 MB

    if (ws_size >= needPk) {
        char* p = (char*)d_ws;
        float*    W       = (float*)p;     p += Wb;
        uint4*    pk_drug = (uint4*)p;     p += pkB;
        uint4*    pk_dis  = (uint4*)p;     p += pkB;
        int*      bcur   = (int*)p;        p += bcB;
        int*      ovfCnt = (int*)p;        p += ocB;
        unsigned* ovfE   = (unsigned*)p;   p += oeB;
        int*      ovfB   = (int*)p;        p += obB;
        unsigned* bin    = (unsigned*)p;

        init_all<<<dim3(kWB + kPkBlk + kCurBlk), 256, 0, stream>>>(
            att, basis, drug_idx, dis_idx, cj_drug, cj_dis,
            W, pk_drug, pk_dis, bcur, ovfCnt);
        bin_pass<<<dim3(kBinBlocks), 1024, 0, stream>>>(edge_src, edge_dst,
                                                        bcur, bin, ovfCnt, ovfE, ovfB);
        gather_pk<<<dim3(kNBuck), 512, 0, stream>>>(bin, bcur, ovfCnt, ovfE, ovfB,
                                                    W, pk_drug, pk_dis,
                                                    ci_drug, ci_dis,
                                                    w_fc, b_fc, out);
    } else {
        // fallback: R1 phased atomic-scatter path
        char* p = (char*)d_ws;
        float* W = (float*)p;
        build_W_fb<<<dim3((kR * kIn * kMsg + 255) / 256), 256, 0, stream>>>(att, basis, W);
        const size_t hB = (size_t)kNDrug * kAgg * sizeof(float);
        float* h = (float*)((char*)d_ws + Wb);
        const int scat_blocks = (int)(((long)kE * 32 + 255) / 256);
        const dim3 scat_grid(scat_blocks, kR);
        hipMemsetAsync(h, 0, hB, stream);
        edge_scatter<<<scat_grid, 256, 0, stream>>>(W, edge_dst, edge_src,
                                                    dis_idx, cj_dis, h);
        fc_fused<<<dim3((kNDrug + 3) / 4), dim3(64, 4), 0, stream>>>(
            h, ci_drug, w_fc, b_fc, out, kNDrug);
        hipMemsetAsync(h, 0, hB, stream);
        edge_scatter<<<scat_grid, 256, 0, stream>>>(W, edge_src, edge_dst,
                                                    drug_idx, cj_drug, h);
        fc_fused<<<dim3((kNDis + 3) / 4), dim3(64, 4), 0, stream>>>(
            h, ci_dis, w_fc, b_fc, out + (size_t)kNDrug * kOut, kNDis);
    }
}

// Round 15
// 167.606 us; speedup vs baseline: 1.4425x; 1.0362x over previous
//
#include <hip/hip_runtime.h>

namespace {
constexpr int kNDrug = 50000;
constexpr int kNDis  = 50000;
constexpr int kE     = 800000;
constexpr int kR     = 2;
constexpr int kIn    = 2048;   // IN_UNITS
constexpr int kMsg   = 32;     // AGG_UNITS / 3
constexpr int kAgg   = 96;     // AGG_UNITS
constexpr int kOut   = 64;     // OUT_UNITS
constexpr int kBasis = 4;
constexpr float kSlope = 0.1f; // LeakyReLU slope
constexpr int kNTot  = kNDis + kNDrug;            // [0,kNDis)=dis nodes, rest drug nodes
constexpr int kBN    = 131;                       // nodes per bucket -> 764 blocks <= 768
                                                  // (3-resident x 256 CU, LDS 48KB) => zero tail
constexpr int kBNP   = 192;                       // padded counter count (wave scan, 3/lane)
constexpr int kNBuck = (kNTot + kBN - 1) / kBN;   // 764
constexpr int kSegCap = 4448;                     // entries/bucket (mean 4188, +4.6 sigma), 16-mult
constexpr int kFifoCap = 44;                      // LDS FIFO depth per bucket in bin_pass
constexpr int kFlushThr = 16;                     // flush unit = 16 entries = 64B; slack 28 -> ovf
                                                  // statistically never (round-7/8 lesson)
constexpr int kBinBlocks = 128;                   // binning blocks (1024 thr each)
constexpr int kOvfCap = 4096;                     // overflow list capacity
constexpr int kNPW   = 17;                        // ceil(kBN/8) nodes per wave in gather
constexpr int kSent  = 20;                        // sentinel pad
constexpr int kEPT   = 9;                         // entries per thread in prologue (ceil(4448/512))
constexpr unsigned kInvE = 0xFFFFFFFFu;           // invalid-entry sentinel for register staging
// init_all block-range partition:
constexpr int kWB    = 512;                       // W-build blocks (131072 / 256)
constexpr int kPkBlk = (kNDrug + 255) / 256;      // 196 pack blocks
constexpr int kCurBlk = (kNBuck + 255) / 256;     // 3 cursor blocks
}

// ---------------- merged one-shot init: W = att@basis, pk tables, cursors ----------------
__global__ __launch_bounds__(256) void init_all(const float* __restrict__ att,
                                                const float* __restrict__ basis,
                                                const int* __restrict__ drug_idx,
                                                const int* __restrict__ dis_idx,
                                                const float* __restrict__ cj_drug,
                                                const float* __restrict__ cj_dis,
                                                float* __restrict__ W,
                                                uint4* __restrict__ pk_drug,
                                                uint4* __restrict__ pk_dis,
                                                int* __restrict__ bcur,
                                                int* __restrict__ ovfCnt) {
    constexpr int per_r = kIn * kMsg;
    const int blk = blockIdx.x;
    const int t = threadIdx.x;
    if (blk < kWB) {                        // W: 2*2048*32 = 131072 elems
        int idx = blk * 256 + t;
        int r = idx / per_r;
        int ic = idx - r * per_r;
        float acc = 0.f;
#pragma unroll
        for (int b = 0; b < kBasis; ++b)
            acc += att[r * kBasis + b] * basis[b * per_r + ic];
        W[idx] = acc;
    } else if (blk < kWB + kPkBlk) {        // packed node tables
        int g = (blk - kWB) * 256 + t;
        if (g < kNDrug) {
            pk_drug[g] = make_uint4((unsigned)drug_idx[3 * g] << 5,
                                    (unsigned)drug_idx[3 * g + 1] << 5,
                                    (unsigned)drug_idx[3 * g + 2] << 5,
                                    __float_as_uint(cj_drug[g]));
        }
        if (g < kNDis) {
            pk_dis[g] = make_uint4((unsigned)dis_idx[3 * g] << 5,
                                   (unsigned)dis_idx[3 * g + 1] << 5,
                                   (unsigned)dis_idx[3 * g + 2] << 5,
                                   __float_as_uint(cj_dis[g]));
        }
    } else {                                // segment cursors + ovf counter
        int i = (blk - kWB - kPkBlk) * 256 + t;
        if (i < kNBuck) bcur[i] = i * kSegCap;
        if (blk == kWB + kPkBlk && t == 0) *ovfCnt = 0;
    }
}

// ---------------- LDS-FIFO binning (128 blocks x 1024 threads) ----------------
// entry = gnode (16b) | rating (bit16) | node-rel-in-bucket (bits 17..24)
__global__ __launch_bounds__(1024) void bin_pass(const int* __restrict__ esrc,
                                                 const int* __restrict__ edst,
                                                 int* __restrict__ bcur,
                                                 unsigned* __restrict__ bin,
                                                 int* __restrict__ ovfCnt,
                                                 unsigned* __restrict__ ovfE,
                                                 int* __restrict__ ovfB) {
    __shared__ unsigned fifo[kNBuck][kFifoCap];  // 134.5 KB
    __shared__ int fcnt[kNBuck];
    __shared__ int flList[kNBuck], flAmt[kNBuck], flPos[kNBuck];
    __shared__ int nFl;

    const int t = threadIdx.x;
    for (int i = t; i < kNBuck; i += 1024) fcnt[i] = 0;

    const int total = kR * kE;
    const int per = (total + kBinBlocks - 1) / kBinBlocks;   // 12500 edges
    const int e0 = blockIdx.x * per;
    const int e1 = (e0 + per < total) ? e0 + per : total;
    __syncthreads();

    auto place = [&](int node, int gn, int r) {
        int bb = node / kBN;
        int rel = node - bb * kBN;
        unsigned ent = (unsigned)gn | ((unsigned)r << 16) | ((unsigned)rel << 17);
        int pos = atomicAdd(&fcnt[bb], 1);
        if (pos < kFifoCap) {
            fifo[bb][pos] = ent;
        } else {  // statistically never (slack 28)
            int s = atomicAdd(ovfCnt, 1);
            if (s < kOvfCap) { ovfE[s] = ent; ovfB[s] = bb; }
        }
    };

    for (int base = e0; base < e1; base += 1024) {
        int idx = base + t;
        if (idx < e1) {
            int r = (idx >= kE) ? 1 : 0;
            int src = esrc[idx], dst = edst[idx];
            place(dst, src, r);            // dis-side entry
            place(kNDis + src, dst, r);    // drug-side entry
        }
        if (t == 0) nFl = 0;
        __syncthreads();
        for (int bb = t; bb < kNBuck; bb += 1024) {
            int c = fcnt[bb]; if (c > kFifoCap) c = kFifoCap;
            if (c >= kFlushThr) {
                int slot = atomicAdd(&nFl, 1);
                flList[slot] = bb;
                flPos[slot] = atomicAdd(&bcur[bb], kFlushThr);   // stays 16-aligned
            }
        }
        __syncthreads();
        {   // 64B-unit copies LDS -> bin (16-lane groups)
            const int n = nFl;
            const int grp = t >> 4, ln = t & 15;
            for (int it = grp; it < n; it += 64) {
                int bb = flList[it], gp = flPos[it];
                int capEnd = bb * kSegCap + kSegCap;
                unsigned ent = fifo[bb][ln];
                int d = gp + ln;
                if (d < capEnd) bin[d] = ent;
                else { int s = atomicAdd(ovfCnt, 1);
                       if (s < kOvfCap) { ovfE[s] = ent; ovfB[s] = bb; } }
            }
        }
        __syncthreads();
        for (int bb = t; bb < kNBuck; bb += 1024) {
            int c = fcnt[bb]; if (c > kFifoCap) c = kFifoCap;
            if (c >= kFlushThr) {
                for (int j = kFlushThr; j < c; ++j) fifo[bb][j - kFlushThr] = fifo[bb][j];
                fcnt[bb] = c - kFlushThr;
            } else {
                fcnt[bb] = c;
            }
        }
        __syncthreads();
    }

    // final drain: partial flushes of the <=kFifoCap-entry tails
    if (t == 0) nFl = 0;
    __syncthreads();
    for (int bb = t; bb < kNBuck; bb += 1024) {
        int c = fcnt[bb]; if (c > kFifoCap) c = kFifoCap;
        if (c) {
            int slot = atomicAdd(&nFl, 1);
            flList[slot] = bb; flAmt[slot] = c;
            flPos[slot] = atomicAdd(&bcur[bb], c);
        }
    }
    __syncthreads();
    const int n = nFl;
    const int grp = t >> 4, ln = t & 15;
    for (int it = grp; it < n; it += 64) {
        int bb = flList[it], f = flAmt[it], gp = flPos[it];
        int capEnd = bb * kSegCap + kSegCap;
        for (int j = ln; j < f; j += 16) {
            unsigned ent = fifo[bb][j];
            int d = gp + j;
            if (d < capEnd) bin[d] = ent;
            else { int s = atomicAdd(ovfCnt, 1);
                   if (s < kOvfCap) { ovfE[s] = ent; ovfB[s] = bb; } }
        }
    }
}

// ---------------- pk gather: 1-read prologue, wave scan, quad-batch body, hbuf epilogue ----
// One 512-thread block per 131-node bucket; LDS ~= 48 KB -> 3 blocks/CU;
// 764 blocks <= 768 slots -> zero tail. Accumulate loop processes FOUR entries
// per iteration with 12 independent accumulators and direct loads -- no
// software-pipeline rotation movs (the R3-R11 macros cost ~12-15 VALU/entry in
// loop-carried renaming; at VALUBusy 64% those movs were the binding term).
__global__ __launch_bounds__(512, 6) void gather_pk(
        const unsigned* __restrict__ bin,
        const int* __restrict__ bcur,
        const int* __restrict__ ovfCnt,
        const unsigned* __restrict__ ovfE,
        const int* __restrict__ ovfB,
        const float* __restrict__ W,
        const uint4* __restrict__ pk_drug, const uint4* __restrict__ pk_dis,
        const float* __restrict__ ci_drug, const float* __restrict__ ci_dis,
        const float* __restrict__ w_fc, const float* __restrict__ b_fc,
        float* __restrict__ out) {
    __shared__ float ws[kAgg * kOut];              // 24 KB
    __shared__ unsigned stage[kSegCap + kSent];    // 17.9 KB
    __shared__ int h[kBNP], lb[kBNP];
    __shared__ int sbuf[kBNP];
    __shared__ float hbuf[8][kAgg];                // 3 KB, one row per wave
    __shared__ int sOvf;

    const int t = threadIdx.x;
    const int b = blockIdx.x;
    {   // ws staged via float4 (3 coalesced iterations)
        const float4* wf4 = (const float4*)w_fc;
        float4* ws4 = (float4*)ws;
        for (int i = t; i < kAgg * kOut / 4; i += 512) ws4[i] = wf4[i];
    }
    if (t < kBNP) h[t] = 0;
    if (t == 0) sOvf = (ovfCnt[0] < kOvfCap) ? ovfCnt[0] : kOvfCap;
    const float bias = b_fc[t & 63];               // per-lane constant, register-resident

    const int sb = b * kSegCap;
    __syncthreads();
    int seg = bcur[b] - sb;
    if (seg > kSegCap) seg = kSegCap;

    // ---- single-pass prologue: read entries into registers, histogram ----
    unsigned myE[kEPT];                            // static indices only (rule #20)
#pragma unroll
    for (int k = 0; k < kEPT; ++k) {
        int i = t + k * 512;
        myE[k] = (i < seg) ? bin[sb + i] : kInvE;
    }
#pragma unroll
    for (int k = 0; k < kEPT; ++k)
        if (myE[k] != kInvE) atomicAdd(&h[myE[k] >> 17], 1);
    __syncthreads();

    // ---- wave-0 shfl scan of 192 counters (3 per lane) ----
    if (t < 64) {
        int v0 = h[3 * t], v1 = h[3 * t + 1], v2 = h[3 * t + 2];
        int s = v0 + v1 + v2;
#pragma unroll
        for (int o = 1; o < 64; o <<= 1) {
            int x = __shfl_up(s, o);
            if (t >= o) s += x;
        }
        int ex = s - (v0 + v1 + v2);
        lb[3 * t] = ex;           lb[3 * t + 1] = ex + v0;       lb[3 * t + 2] = ex + v0 + v1;
        sbuf[3 * t] = ex;         sbuf[3 * t + 1] = ex + v0;     sbuf[3 * t + 2] = ex + v0 + v1;
    }
    if (t < kSent) stage[kSegCap + t] = 0;  // pre-clear pad region top
    __syncthreads();

    // ---- scatter from registers into per-node-ordered LDS staging ----
#pragma unroll
    for (int k = 0; k < kEPT; ++k)
        if (myE[k] != kInvE) {
            int pos = atomicAdd(&sbuf[myE[k] >> 17], 1);
            stage[pos] = myE[k];
        }
    if (t < kSent) stage[seg + t] = 0;      // sentinel entries
    __syncthreads();

    const int wid  = t >> 6;
    const int lane = t & 63;
    const int half = lane >> 5;
    const int fl   = lane & 31;

    for (int i = 0; i < kNPW; ++i) {
        const int nl = wid * kNPW + i;
        if (nl >= kBN) break;    // wave-uniform
        const int g  = b * kBN + nl;
        if (g >= kNTot) break;   // wave-uniform; no block syncs below

        const uint4* pkp;
        float civ;
        size_t orow;
        if (g < kNDis) {         // dis dst node: gathers DRUG feats
            pkp = pk_drug; civ = ci_dis[g];
            orow = (size_t)(kNDrug + g);
        } else {                 // drug dst node: gathers DIS feats
            pkp = pk_dis;  civ = ci_drug[g - kNDis];
            orow = (size_t)(g - kNDis);
        }

        const int base = lb[nl];
        const int deg  = h[nl];
        const unsigned* sp = stage + base + half;   // this half's entries at sp[2*j]
        const int n  = (deg - half + 1) >> 1;       // this half's entry count

        // ---- quad-batch accumulate: 4 entries/iter, 12 accumulators, no movs ----
        float a00 = 0.f, a01 = 0.f, a02 = 0.f;
        float a10 = 0.f, a11 = 0.f, a12 = 0.f;
        float a20 = 0.f, a21 = 0.f, a22 = 0.f;
        float a30 = 0.f, a31 = 0.f, a32 = 0.f;
        int j = 0;
        for (; j + 3 < n; j += 4) {
            unsigned e0 = sp[2 * j];
            unsigned e1 = sp[2 * j + 2];
            unsigned e2 = sp[2 * j + 4];
            unsigned e3 = sp[2 * j + 6];
            uint4 P0 = pkp[e0 & 0xffffu];
            uint4 P1 = pkp[e1 & 0xffffu];
            uint4 P2 = pkp[e2 & 0xffffu];
            uint4 P3 = pkp[e3 & 0xffffu];
            const float* W0 = W + (((e0 >> 16) & 1u) * (unsigned)(kIn * kMsg));
            const float* W1 = W + (((e1 >> 16) & 1u) * (unsigned)(kIn * kMsg));
            const float* W2 = W + (((e2 >> 16) & 1u) * (unsigned)(kIn * kMsg));
            const float* W3 = W + (((e3 >> 16) & 1u) * (unsigned)(kIn * kMsg));
            float c0 = __uint_as_float(P0.w);
            float c1 = __uint_as_float(P1.w);
            float c2 = __uint_as_float(P2.w);
            float c3 = __uint_as_float(P3.w);
            a00 = fmaf(W0[P0.x + fl], c0, a00);
            a01 = fmaf(W0[P0.y + fl], c0, a01);
            a02 = fmaf(W0[P0.z + fl], c0, a02);
            a10 = fmaf(W1[P1.x + fl], c1, a10);
            a11 = fmaf(W1[P1.y + fl], c1, a11);
            a12 = fmaf(W1[P1.z + fl], c1, a12);
            a20 = fmaf(W2[P2.x + fl], c2, a20);
            a21 = fmaf(W2[P2.y + fl], c2, a21);
            a22 = fmaf(W2[P2.z + fl], c2, a22);
            a30 = fmaf(W3[P3.x + fl], c3, a30);
            a31 = fmaf(W3[P3.y + fl], c3, a31);
            a32 = fmaf(W3[P3.z + fl], c3, a32);
        }
        for (; j < n; ++j) {     // remainder (<=3 entries)
            unsigned e = sp[2 * j];
            uint4 P = pkp[e & 0xffffu];
            const float* Wr = W + (((e >> 16) & 1u) * (unsigned)(kIn * kMsg));
            float c = __uint_as_float(P.w);
            a00 = fmaf(Wr[P.x + fl], c, a00);
            a01 = fmaf(Wr[P.y + fl], c, a01);
            a02 = fmaf(Wr[P.z + fl], c, a02);
        }
        float a0 = (a00 + a10) + (a20 + a30);
        float a1 = (a01 + a11) + (a21 + a31);
        float a2 = (a02 + a12) + (a22 + a32);

        if (sOvf > 0) {          // statistically never non-zero
            for (int jj = half; jj < sOvf; jj += 2) {
                int bb = ovfB[jj];
                if (bb == b && (int)(ovfE[jj] >> 17) == nl) {
                    unsigned e = ovfE[jj];
                    uint4 P = pkp[e & 0xffffu];
                    const float* Wr = W + (((e >> 16) & 1u) * (unsigned)(kIn * kMsg));
                    float c = __uint_as_float(P.w);
                    a0 = fmaf(Wr[P.x + fl], c, a0);
                    a1 = fmaf(Wr[P.y + fl], c, a1);
                    a2 = fmaf(Wr[P.z + fl], c, a2);
                }
            }
        }

        a0 += __shfl_xor(a0, 32);
        a1 += __shfl_xor(a1, 32);
        a2 += __shfl_xor(a2, 32);

        a0 *= civ; a1 *= civ; a2 *= civ;
        a0 = (a0 >= 0.f) ? a0 : kSlope * a0;
        a1 = (a1 >= 0.f) ? a1 : kSlope * a1;
        a2 = (a2 >= 0.f) ? a2 : kSlope * a2;

        // ---- FC epilogue: per-wave hbuf row (same-wave LDS write->read, in-order DS) ----
        if (half == 0) {
            hbuf[wid][fl]          = a0;
            hbuf[wid][kMsg + fl]   = a1;
            hbuf[wid][2*kMsg + fl] = a2;
        }
        const float4* hv = (const float4*)(&hbuf[wid][0]);
        float acc0 = bias, acc1 = 0.f, acc2 = 0.f;
#pragma unroll
        for (int q = 0; q < 8; ++q) {
            float4 h4 = hv[q];
            acc0 = fmaf(h4.x, ws[(4*q    ) * kOut + lane], acc0);
            acc0 = fmaf(h4.y, ws[(4*q + 1) * kOut + lane], acc0);
            acc0 = fmaf(h4.z, ws[(4*q + 2) * kOut + lane], acc0);
            acc0 = fmaf(h4.w, ws[(4*q + 3) * kOut + lane], acc0);
        }
#pragma unroll
        for (int q = 8; q < 16; ++q) {
            float4 h4 = hv[q];
            acc1 = fmaf(h4.x, ws[(4*q    ) * kOut + lane], acc1);
            acc1 = fmaf(h4.y, ws[(4*q + 1) * kOut + lane], acc1);
            acc1 = fmaf(h4.z, ws[(4*q + 2) * kOut + lane], acc1);
            acc1 = fmaf(h4.w, ws[(4*q + 3) * kOut + lane], acc1);
        }
#pragma unroll
        for (int q = 16; q < 24; ++q) {
            float4 h4 = hv[q];
            acc2 = fmaf(h4.x, ws[(4*q    ) * kOut + lane], acc2);
            acc2 = fmaf(h4.y, ws[(4*q + 1) * kOut + lane], acc2);
            acc2 = fmaf(h4.z, ws[(4*q + 2) * kOut + lane], acc2);
            acc2 = fmaf(h4.w, ws[(4*q + 3) * kOut + lane], acc2);
        }
        out[orow * kOut + lane] = acc0 + acc1 + acc2;
    }
}

// ---------------- fallback path (R1 atomic scatter, tiny-ws only) ----------------
__global__ __launch_bounds__(256) void build_W_fb(const float* __restrict__ att,
                                                  const float* __restrict__ basis,
                                                  float* __restrict__ W) {
    constexpr int per_r = kIn * kMsg;
    int idx = blockIdx.x * blockDim.x + threadIdx.x;
    if (idx >= kR * per_r) return;
    int r = idx / per_r;
    int ic = idx - r * per_r;
    float acc = 0.f;
#pragma unroll
    for (int b = 0; b < kBasis; ++b)
        acc += att[r * kBasis + b] * basis[b * per_r + ic];
    W[idx] = acc;
}

__global__ __launch_bounds__(256) void edge_scatter(
        const float* __restrict__ W,
        const int* __restrict__ gnode,
        const int* __restrict__ snode,
        const int* __restrict__ fidx,
        const float* __restrict__ cj,
        float* __restrict__ h) {
    const int r = blockIdx.y;
    long tid = (long)blockIdx.x * blockDim.x + threadIdx.x;
    const int lane = (int)(tid & 31);
    const long e = tid >> 5;
    if (e >= kE) return;
    const int g = gnode[(long)r * kE + e];
    const int s = snode[(long)r * kE + e];
    const int i0 = fidx[g * 3 + 0];
    const int i1 = fidx[g * 3 + 1];
    const int i2 = fidx[g * 3 + 2];
    const float c = cj[g];
    const float* Wr = W + (size_t)r * kIn * kMsg;
    float* outp = h + (size_t)s * kAgg;
    atomicAdd(&outp[lane],            Wr[(size_t)i0 * kMsg + lane] * c);
    atomicAdd(&outp[kMsg + lane],     Wr[(size_t)i1 * kMsg + lane] * c);
    atomicAdd(&outp[2 * kMsg + lane], Wr[(size_t)i2 * kMsg + lane] * c);
}

__global__ __launch_bounds__(256) void fc_fused(const float* __restrict__ h,
                                                const float* __restrict__ ci,
                                                const float* __restrict__ w_fc,
                                                const float* __restrict__ b_fc,
                                                float* __restrict__ out, int nrows) {
    __shared__ float ws[kAgg * kOut];
    __shared__ float bs[kOut];
    const int lt = threadIdx.y * blockDim.x + threadIdx.x;
    for (int i = lt; i < kAgg * kOut; i += blockDim.x * blockDim.y)
        ws[i] = w_fc[i];
    if (lt < kOut) bs[lt] = b_fc[lt];
    __syncthreads();
    const int row = blockIdx.x * blockDim.y + threadIdx.y;
    if (row >= nrows) return;
    const int col = threadIdx.x;
    const float c = ci[row];
    const float* hr = h + (size_t)row * kAgg;
    float acc = bs[col];
#pragma unroll 8
    for (int k = 0; k < kAgg; ++k) {
        float a = hr[k] * c;
        a = (a >= 0.f) ? a : kSlope * a;
        acc += a * ws[k * kOut + col];
    }
    out[(size_t)row * kOut + col] = acc;
}

extern "C" void kernel_launch(void* const* d_in, const int* in_sizes, int n_in,
                              void* d_out, int out_size, void* d_ws, size_t ws_size,
                              hipStream_t stream) {
    const int*   drug_idx = (const int*)d_in[0];
    const int*   dis_idx  = (const int*)d_in[1];
    const int*   edge_src = (const int*)d_in[2];
    const int*   edge_dst = (const int*)d_in[3];
    const float* cj_drug  = (const float*)d_in[4];
    const float* ci_drug  = (const float*)d_in[5];
    const float* cj_dis   = (const float*)d_in[6];
    const float* ci_dis   = (const float*)d_in[7];
    const float* att      = (const float*)d_in[8];
    const float* basis    = (const float*)d_in[9];
    const float* w_fc     = (const float*)d_in[10];
    const float* b_fc     = (const float*)d_in[11];
    float* out = (float*)d_out;

    auto align256 = [](size_t x) { return (x + 255) & ~(size_t)255; };
    const size_t Wb    = align256((size_t)kR * kIn * kMsg * sizeof(float));     // 512 KB
    const size_t pkB   = align256((size_t)kNDrug * sizeof(uint4));              // 800 KB each
    const size_t bcB   = align256((size_t)kNBuck * sizeof(int));
    const size_t ocB   = align256(sizeof(int));
    const size_t oeB   = align256((size_t)kOvfCap * sizeof(unsigned));          // 16 KB
    const size_t obB   = align256((size_t)kOvfCap * sizeof(int));               // 16 KB
    const size_t binB  = align256((size_t)kNBuck * kSegCap * sizeof(unsigned)); // ~13.6 MB
    const size_t needBase = Wb + bcB + ocB + oeB + obB + binB;                  // ~14.2 MB
    const size_t needPk   = needBase + 2 * pkB;                                 // ~15.8 MB

    if (ws_size >= needPk) {
        char* p = (char*)d_ws;
        float*    W       = (float*)p;     p += Wb;
        uint4*    pk_drug = (uint4*)p;     p += pkB;
        uint4*    pk_dis  = (uint4*)p;     p += pkB;
        int*      bcur   = (int*)p;        p += bcB;
        int*      ovfCnt = (int*)p;        p += ocB;
        unsigned* ovfE   = (unsigned*)p;   p += oeB;
        int*      ovfB   = (int*)p;        p += obB;
        unsigned* bin    = (unsigned*)p;

        init_all<<<dim3(kWB + kPkBlk + kCurBlk), 256, 0, stream>>>(
            att, basis, drug_idx, dis_idx, cj_drug, cj_dis,
            W, pk_drug, pk_dis, bcur, ovfCnt);
        bin_pass<<<dim3(kBinBlocks), 1024, 0, stream>>>(edge_src, edge_dst,
                                                        bcur, bin, ovfCnt, ovfE, ovfB);
        gather_pk<<<dim3(kNBuck), 512, 0, stream>>>(bin, bcur, ovfCnt, ovfE, ovfB,
                                                    W, pk_drug, pk_dis,
                                                    ci_drug, ci_dis,
                                                    w_fc, b_fc, out);
    } else {
        // fallback: R1 phased atomic-scatter path
        char* p = (char*)d_ws;
        float* W = (float*)p;
        build_W_fb<<<dim3((kR * kIn * kMsg + 255) / 256), 256, 0, stream>>>(att, basis, W);
        const size_t hB = (size_t)kNDrug * kAgg * sizeof(float);
        float* h = (float*)((char*)d_ws + Wb);
        const int scat_blocks = (int)(((long)kE * 32 + 255) / 256);
        const dim3 scat_grid(scat_blocks, kR);
        hipMemsetAsync(h, 0, hB, stream);
        edge_scatter<<<scat_grid, 256, 0, stream>>>(W, edge_dst, edge_src,
                                                    dis_idx, cj_dis, h);
        fc_fused<<<dim3((kNDrug + 3) / 4), dim3(64, 4), 0, stream>>>(
            h, ci_drug, w_fc, b_fc, out, kNDrug);
        hipMemsetAsync(h, 0, hB, stream);
        edge_scatter<<<scat_grid, 256, 0, stream>>>(W, edge_src, edge_dst,
                                                    drug_idx, cj_drug, h);
        fc_fused<<<dim3((kNDis + 3) / 4), dim3(64, 4), 0, stream>>>(
            h, ci_dis, w_fc, b_fc, out + (size_t)kNDrug * kOut, kNDis);
    }
}

// Round 16
// 165.160 us; speedup vs baseline: 1.4639x; 1.0148x over previous
//
#include <hip/hip_runtime.h>

namespace {
constexpr int kNDrug = 50000;
constexpr int kNDis  = 50000;
constexpr int kE     = 800000;
constexpr int kR     = 2;
constexpr int kIn    = 2048;   // IN_UNITS
constexpr int kMsg   = 32;     // AGG_UNITS / 3
constexpr int kAgg   = 96;     // AGG_UNITS
constexpr int kOut   = 64;     // OUT_UNITS
constexpr int kBasis = 4;
constexpr float kSlope = 0.1f; // LeakyReLU slope
constexpr int kNTot  = kNDis + kNDrug;            // [0,kNDis)=dis nodes, rest drug nodes
constexpr int kBN    = 131;                       // nodes per bucket -> 764 blocks <= 768
                                                  // (3-resident x 256 CU, LDS 48KB) => zero tail
constexpr int kBNP   = 192;                       // padded counter count (wave scan, 3/lane)
constexpr int kNBuck = (kNTot + kBN - 1) / kBN;   // 764
constexpr int kSegCap = 4448;                     // entries/bucket (mean 4188, +4.6 sigma), 16-mult
constexpr int kFifoCap = 44;                      // LDS FIFO depth per bucket in bin_pass
constexpr int kFlushThr = 16;                     // flush unit = 16 entries = 64B; slack 28 -> ovf
                                                  // statistically never (round-7/8 lesson)
constexpr int kBinBlocks = 128;                   // binning blocks (1024 thr each)
constexpr int kOvfCap = 4096;                     // overflow list capacity
constexpr int kNPW   = 17;                        // ceil(kBN/8) nodes per wave in gather
constexpr int kSent  = 20;                        // sentinel pad
constexpr int kEPT   = 9;                         // entries per thread in prologue (ceil(4448/512))
constexpr unsigned kInvE = 0xFFFFFFFFu;           // invalid-entry sentinel for register staging
// init_all block-range partition:
constexpr int kWB    = 512;                       // W-build blocks (131072 / 256)
constexpr int kPkBlk = (kNDrug + 255) / 256;      // 196 pack blocks
constexpr int kCurBlk = (kNBuck + 255) / 256;     // 3 cursor blocks
// NOTE: kIn*kMsg == 65536 == 1<<16, and entries carry rating in bit 16, so the
// W element base for an entry e is simply (e & 0x10000u). [round-16 micro-opt]
}

// ---------------- merged one-shot init: W = att@basis, pk tables, cursors ----------------
__global__ __launch_bounds__(256) void init_all(const float* __restrict__ att,
                                                const float* __restrict__ basis,
                                                const int* __restrict__ drug_idx,
                                                const int* __restrict__ dis_idx,
                                                const float* __restrict__ cj_drug,
                                                const float* __restrict__ cj_dis,
                                                float* __restrict__ W,
                                                uint4* __restrict__ pk_drug,
                                                uint4* __restrict__ pk_dis,
                                                int* __restrict__ bcur,
                                                int* __restrict__ ovfCnt) {
    constexpr int per_r = kIn * kMsg;
    const int blk = blockIdx.x;
    const int t = threadIdx.x;
    if (blk < kWB) {                        // W: 2*2048*32 = 131072 elems
        int idx = blk * 256 + t;
        int r = idx / per_r;
        int ic = idx - r * per_r;
        float acc = 0.f;
#pragma unroll
        for (int b = 0; b < kBasis; ++b)
            acc += att[r * kBasis + b] * basis[b * per_r + ic];
        W[idx] = acc;
    } else if (blk < kWB + kPkBlk) {        // packed node tables
        int g = (blk - kWB) * 256 + t;
        if (g < kNDrug) {
            pk_drug[g] = make_uint4((unsigned)drug_idx[3 * g] << 5,
                                    (unsigned)drug_idx[3 * g + 1] << 5,
                                    (unsigned)drug_idx[3 * g + 2] << 5,
                                    __float_as_uint(cj_drug[g]));
        }
        if (g < kNDis) {
            pk_dis[g] = make_uint4((unsigned)dis_idx[3 * g] << 5,
                                   (unsigned)dis_idx[3 * g + 1] << 5,
                                   (unsigned)dis_idx[3 * g + 2] << 5,
                                   __float_as_uint(cj_dis[g]));
        }
    } else {                                // segment cursors + ovf counter
        int i = (blk - kWB - kPkBlk) * 256 + t;
        if (i < kNBuck) bcur[i] = i * kSegCap;
        if (blk == kWB + kPkBlk && t == 0) *ovfCnt = 0;
    }
}

// ---------------- LDS-FIFO binning (128 blocks x 1024 threads) ----------------
// entry = gnode (16b) | rating (bit16) | node-rel-in-bucket (bits 17..24)
__global__ __launch_bounds__(1024) void bin_pass(const int* __restrict__ esrc,
                                                 const int* __restrict__ edst,
                                                 int* __restrict__ bcur,
                                                 unsigned* __restrict__ bin,
                                                 int* __restrict__ ovfCnt,
                                                 unsigned* __restrict__ ovfE,
                                                 int* __restrict__ ovfB) {
    __shared__ unsigned fifo[kNBuck][kFifoCap];  // 134.5 KB
    __shared__ int fcnt[kNBuck];
    __shared__ int flList[kNBuck], flAmt[kNBuck], flPos[kNBuck];
    __shared__ int nFl;

    const int t = threadIdx.x;
    for (int i = t; i < kNBuck; i += 1024) fcnt[i] = 0;

    const int total = kR * kE;
    const int per = (total + kBinBlocks - 1) / kBinBlocks;   // 12500 edges
    const int e0 = blockIdx.x * per;
    const int e1 = (e0 + per < total) ? e0 + per : total;
    __syncthreads();

    auto place = [&](int node, int gn, int r) {
        int bb = node / kBN;
        int rel = node - bb * kBN;
        unsigned ent = (unsigned)gn | ((unsigned)r << 16) | ((unsigned)rel << 17);
        int pos = atomicAdd(&fcnt[bb], 1);
        if (pos < kFifoCap) {
            fifo[bb][pos] = ent;
        } else {  // statistically never (slack 28)
            int s = atomicAdd(ovfCnt, 1);
            if (s < kOvfCap) { ovfE[s] = ent; ovfB[s] = bb; }
        }
    };

    for (int base = e0; base < e1; base += 1024) {
        int idx = base + t;
        if (idx < e1) {
            int r = (idx >= kE) ? 1 : 0;
            int src = esrc[idx], dst = edst[idx];
            place(dst, src, r);            // dis-side entry
            place(kNDis + src, dst, r);    // drug-side entry
        }
        if (t == 0) nFl = 0;
        __syncthreads();
        for (int bb = t; bb < kNBuck; bb += 1024) {
            int c = fcnt[bb]; if (c > kFifoCap) c = kFifoCap;
            if (c >= kFlushThr) {
                int slot = atomicAdd(&nFl, 1);
                flList[slot] = bb;
                flPos[slot] = atomicAdd(&bcur[bb], kFlushThr);   // stays 16-aligned
            }
        }
        __syncthreads();
        {   // 64B-unit copies LDS -> bin (16-lane groups)
            const int n = nFl;
            const int grp = t >> 4, ln = t & 15;
            for (int it = grp; it < n; it += 64) {
                int bb = flList[it], gp = flPos[it];
                int capEnd = bb * kSegCap + kSegCap;
                unsigned ent = fifo[bb][ln];
                int d = gp + ln;
                if (d < capEnd) bin[d] = ent;
                else { int s = atomicAdd(ovfCnt, 1);
                       if (s < kOvfCap) { ovfE[s] = ent; ovfB[s] = bb; } }
            }
        }
        __syncthreads();
        for (int bb = t; bb < kNBuck; bb += 1024) {
            int c = fcnt[bb]; if (c > kFifoCap) c = kFifoCap;
            if (c >= kFlushThr) {
                for (int j = kFlushThr; j < c; ++j) fifo[bb][j - kFlushThr] = fifo[bb][j];
                fcnt[bb] = c - kFlushThr;
            } else {
                fcnt[bb] = c;
            }
        }
        __syncthreads();
    }

    // final drain: partial flushes of the <=kFifoCap-entry tails
    if (t == 0) nFl = 0;
    __syncthreads();
    for (int bb = t; bb < kNBuck; bb += 1024) {
        int c = fcnt[bb]; if (c > kFifoCap) c = kFifoCap;
        if (c) {
            int slot = atomicAdd(&nFl, 1);
            flList[slot] = bb; flAmt[slot] = c;
            flPos[slot] = atomicAdd(&bcur[bb], c);
        }
    }
    __syncthreads();
    const int n = nFl;
    const int grp = t >> 4, ln = t & 15;
    for (int it = grp; it < n; it += 64) {
        int bb = flList[it], f = flAmt[it], gp = flPos[it];
        int capEnd = bb * kSegCap + kSegCap;
        for (int j = ln; j < f; j += 16) {
            unsigned ent = fifo[bb][j];
            int d = gp + j;
            if (d < capEnd) bin[d] = ent;
            else { int s = atomicAdd(ovfCnt, 1);
                   if (s < kOvfCap) { ovfE[s] = ent; ovfB[s] = bb; } }
        }
    }
}

// ---------------- pk gather: 1-read prologue, wave scan, quad-batch body, hbuf epilogue ----
// One 512-thread block per 131-node bucket; LDS ~= 48 KB -> 3 blocks/CU;
// 764 blocks <= 768 slots -> zero tail. Quad-batch accumulate (R15) plus two
// issue-count cuts: W base = (e & 0x10000) [kIn*kMsg == 1<<16], and contiguous
// half-split (sp[j], not sp[2j]) so stage indices carry no x2 scaling.
__global__ __launch_bounds__(512, 6) void gather_pk(
        const unsigned* __restrict__ bin,
        const int* __restrict__ bcur,
        const int* __restrict__ ovfCnt,
        const unsigned* __restrict__ ovfE,
        const int* __restrict__ ovfB,
        const float* __restrict__ W,
        const uint4* __restrict__ pk_drug, const uint4* __restrict__ pk_dis,
        const float* __restrict__ ci_drug, const float* __restrict__ ci_dis,
        const float* __restrict__ w_fc, const float* __restrict__ b_fc,
        float* __restrict__ out) {
    __shared__ float ws[kAgg * kOut];              // 24 KB
    __shared__ unsigned stage[kSegCap + kSent];    // 17.9 KB
    __shared__ int h[kBNP], lb[kBNP];
    __shared__ int sbuf[kBNP];
    __shared__ float hbuf[8][kAgg];                // 3 KB, one row per wave
    __shared__ int sOvf;

    const int t = threadIdx.x;
    const int b = blockIdx.x;
    {   // ws staged via float4 (3 coalesced iterations)
        const float4* wf4 = (const float4*)w_fc;
        float4* ws4 = (float4*)ws;
        for (int i = t; i < kAgg * kOut / 4; i += 512) ws4[i] = wf4[i];
    }
    if (t < kBNP) h[t] = 0;
    if (t == 0) sOvf = (ovfCnt[0] < kOvfCap) ? ovfCnt[0] : kOvfCap;
    const float bias = b_fc[t & 63];               // per-lane constant, register-resident

    const int sb = b * kSegCap;
    __syncthreads();
    int seg = bcur[b] - sb;
    if (seg > kSegCap) seg = kSegCap;

    // ---- single-pass prologue: read entries into registers, histogram ----
    unsigned myE[kEPT];                            // static indices only (rule #20)
#pragma unroll
    for (int k = 0; k < kEPT; ++k) {
        int i = t + k * 512;
        myE[k] = (i < seg) ? bin[sb + i] : kInvE;
    }
#pragma unroll
    for (int k = 0; k < kEPT; ++k)
        if (myE[k] != kInvE) atomicAdd(&h[myE[k] >> 17], 1);
    __syncthreads();

    // ---- wave-0 shfl scan of 192 counters (3 per lane) ----
    if (t < 64) {
        int v0 = h[3 * t], v1 = h[3 * t + 1], v2 = h[3 * t + 2];
        int s = v0 + v1 + v2;
#pragma unroll
        for (int o = 1; o < 64; o <<= 1) {
            int x = __shfl_up(s, o);
            if (t >= o) s += x;
        }
        int ex = s - (v0 + v1 + v2);
        lb[3 * t] = ex;           lb[3 * t + 1] = ex + v0;       lb[3 * t + 2] = ex + v0 + v1;
        sbuf[3 * t] = ex;         sbuf[3 * t + 1] = ex + v0;     sbuf[3 * t + 2] = ex + v0 + v1;
    }
    if (t < kSent) stage[kSegCap + t] = 0;  // pre-clear pad region top
    __syncthreads();

    // ---- scatter from registers into per-node-ordered LDS staging ----
#pragma unroll
    for (int k = 0; k < kEPT; ++k)
        if (myE[k] != kInvE) {
            int pos = atomicAdd(&sbuf[myE[k] >> 17], 1);
            stage[pos] = myE[k];
        }
    if (t < kSent) stage[seg + t] = 0;      // sentinel entries
    __syncthreads();

    const int wid  = t >> 6;
    const int lane = t & 63;
    const int half = lane >> 5;
    const int fl   = lane & 31;

    for (int i = 0; i < kNPW; ++i) {
        const int nl = wid * kNPW + i;
        if (nl >= kBN) break;    // wave-uniform
        const int g  = b * kBN + nl;
        if (g >= kNTot) break;   // wave-uniform; no block syncs below

        const uint4* pkp;
        float civ;
        size_t orow;
        if (g < kNDis) {         // dis dst node: gathers DRUG feats
            pkp = pk_drug; civ = ci_dis[g];
            orow = (size_t)(kNDrug + g);
        } else {                 // drug dst node: gathers DIS feats
            pkp = pk_dis;  civ = ci_drug[g - kNDis];
            orow = (size_t)(g - kNDis);
        }

        const int base = lb[nl];
        const int deg  = h[nl];
        // contiguous half-split: half0 = [0, nh), half1 = [nh, deg)
        const int nh = (deg + 1) >> 1;
        const unsigned* sp = stage + base + (half ? nh : 0);
        const int n = half ? (deg - nh) : nh;

        // ---- quad-batch accumulate: 4 entries/iter, 12 accumulators, no movs ----
        float a00 = 0.f, a01 = 0.f, a02 = 0.f;
        float a10 = 0.f, a11 = 0.f, a12 = 0.f;
        float a20 = 0.f, a21 = 0.f, a22 = 0.f;
        float a30 = 0.f, a31 = 0.f, a32 = 0.f;
        int j = 0;
        for (; j + 3 < n; j += 4) {
            unsigned e0 = sp[j];
            unsigned e1 = sp[j + 1];
            unsigned e2 = sp[j + 2];
            unsigned e3 = sp[j + 3];
            uint4 P0 = pkp[e0 & 0xffffu];
            uint4 P1 = pkp[e1 & 0xffffu];
            uint4 P2 = pkp[e2 & 0xffffu];
            uint4 P3 = pkp[e3 & 0xffffu];
            float c0 = __uint_as_float(P0.w);
            float c1 = __uint_as_float(P1.w);
            float c2 = __uint_as_float(P2.w);
            float c3 = __uint_as_float(P3.w);
            // W element base == (e & 0x10000): kIn*kMsg == 1<<16 and rating is bit 16
            a00 = fmaf(W[(e0 & 0x10000u) + P0.x + fl], c0, a00);
            a01 = fmaf(W[(e0 & 0x10000u) + P0.y + fl], c0, a01);
            a02 = fmaf(W[(e0 & 0x10000u) + P0.z + fl], c0, a02);
            a10 = fmaf(W[(e1 & 0x10000u) + P1.x + fl], c1, a10);
            a11 = fmaf(W[(e1 & 0x10000u) + P1.y + fl], c1, a11);
            a12 = fmaf(W[(e1 & 0x10000u) + P1.z + fl], c1, a12);
            a20 = fmaf(W[(e2 & 0x10000u) + P2.x + fl], c2, a20);
            a21 = fmaf(W[(e2 & 0x10000u) + P2.y + fl], c2, a21);
            a22 = fmaf(W[(e2 & 0x10000u) + P2.z + fl], c2, a22);
            a30 = fmaf(W[(e3 & 0x10000u) + P3.x + fl], c3, a30);
            a31 = fmaf(W[(e3 & 0x10000u) + P3.y + fl], c3, a31);
            a32 = fmaf(W[(e3 & 0x10000u) + P3.z + fl], c3, a32);
        }
        for (; j < n; ++j) {     // remainder (<=3 entries)
            unsigned e = sp[j];
            uint4 P = pkp[e & 0xffffu];
            float c = __uint_as_float(P.w);
            a00 = fmaf(W[(e & 0x10000u) + P.x + fl], c, a00);
            a01 = fmaf(W[(e & 0x10000u) + P.y + fl], c, a01);
            a02 = fmaf(W[(e & 0x10000u) + P.z + fl], c, a02);
        }
        float a0 = (a00 + a10) + (a20 + a30);
        float a1 = (a01 + a11) + (a21 + a31);
        float a2 = (a02 + a12) + (a22 + a32);

        if (sOvf > 0) {          // statistically never non-zero
            for (int jj = half; jj < sOvf; jj += 2) {
                int bb = ovfB[jj];
                if (bb == b && (int)(ovfE[jj] >> 17) == nl) {
                    unsigned e = ovfE[jj];
                    uint4 P = pkp[e & 0xffffu];
                    float c = __uint_as_float(P.w);
                    a0 = fmaf(W[(e & 0x10000u) + P.x + fl], c, a0);
                    a1 = fmaf(W[(e & 0x10000u) + P.y + fl], c, a1);
                    a2 = fmaf(W[(e & 0x10000u) + P.z + fl], c, a2);
                }
            }
        }

        a0 += __shfl_xor(a0, 32);
        a1 += __shfl_xor(a1, 32);
        a2 += __shfl_xor(a2, 32);

        a0 *= civ; a1 *= civ; a2 *= civ;
        a0 = (a0 >= 0.f) ? a0 : kSlope * a0;
        a1 = (a1 >= 0.f) ? a1 : kSlope * a1;
        a2 = (a2 >= 0.f) ? a2 : kSlope * a2;

        // ---- FC epilogue: per-wave hbuf row (same-wave LDS write->read, in-order DS) ----
        if (half == 0) {
            hbuf[wid][fl]          = a0;
            hbuf[wid][kMsg + fl]   = a1;
            hbuf[wid][2*kMsg + fl] = a2;
        }
        const float4* hv = (const float4*)(&hbuf[wid][0]);
        float acc0 = bias, acc1 = 0.f, acc2 = 0.f;
#pragma unroll
        for (int q = 0; q < 8; ++q) {
            float4 h4 = hv[q];
            acc0 = fmaf(h4.x, ws[(4*q    ) * kOut + lane], acc0);
            acc0 = fmaf(h4.y, ws[(4*q + 1) * kOut + lane], acc0);
            acc0 = fmaf(h4.z, ws[(4*q + 2) * kOut + lane], acc0);
            acc0 = fmaf(h4.w, ws[(4*q + 3) * kOut + lane], acc0);
        }
#pragma unroll
        for (int q = 8; q < 16; ++q) {
            float4 h4 = hv[q];
            acc1 = fmaf(h4.x, ws[(4*q    ) * kOut + lane], acc1);
            acc1 = fmaf(h4.y, ws[(4*q + 1) * kOut + lane], acc1);
            acc1 = fmaf(h4.z, ws[(4*q + 2) * kOut + lane], acc1);
            acc1 = fmaf(h4.w, ws[(4*q + 3) * kOut + lane], acc1);
        }
#pragma unroll
        for (int q = 16; q < 24; ++q) {
            float4 h4 = hv[q];
            acc2 = fmaf(h4.x, ws[(4*q    ) * kOut + lane], acc2);
            acc2 = fmaf(h4.y, ws[(4*q + 1) * kOut + lane], acc2);
            acc2 = fmaf(h4.z, ws[(4*q + 2) * kOut + lane], acc2);
            acc2 = fmaf(h4.w, ws[(4*q + 3) * kOut + lane], acc2);
        }
        out[orow * kOut + lane] = acc0 + acc1 + acc2;
    }
}

// ---------------- fallback path (R1 atomic scatter, tiny-ws only) ----------------
__global__ __launch_bounds__(256) void build_W_fb(const float* __restrict__ att,
                                                  const float* __restrict__ basis,
                                                  float* __restrict__ W) {
    constexpr int per_r = kIn * kMsg;
    int idx = blockIdx.x * blockDim.x + threadIdx.x;
    if (idx >= kR * per_r) return;
    int r = idx / per_r;
    int ic = idx - r * per_r;
    float acc = 0.f;
#pragma unroll
    for (int b = 0; b < kBasis; ++b)
        acc += att[r * kBasis + b] * basis[b * per_r + ic];
    W[idx] = acc;
}

__global__ __launch_bounds__(256) void edge_scatter(
        const float* __restrict__ W,
        const int* __restrict__ gnode,
        const int* __restrict__ snode,
        const int* __restrict__ fidx,
        const float* __restrict__ cj,
        float* __restrict__ h) {
    const int r = blockIdx.y;
    long tid = (long)blockIdx.x * blockDim.x + threadIdx.x;
    const int lane = (int)(tid & 31);
    const long e = tid >> 5;
    if (e >= kE) return;
    const int g = gnode[(long)r * kE + e];
    const int s = snode[(long)r * kE + e];
    const int i0 = fidx[g * 3 + 0];
    const int i1 = fidx[g * 3 + 1];
    const int i2 = fidx[g * 3 + 2];
    const float c = cj[g];
    const float* Wr = W + (size_t)r * kIn * kMsg;
    float* outp = h + (size_t)s * kAgg;
    atomicAdd(&outp[lane],            Wr[(size_t)i0 * kMsg + lane] * c);
    atomicAdd(&outp[kMsg + lane],     Wr[(size_t)i1 * kMsg + lane] * c);
    atomicAdd(&outp[2 * kMsg + lane], Wr[(size_t)i2 * kMsg + lane] * c);
}

__global__ __launch_bounds__(256) void fc_fused(const float* __restrict__ h,
                                                const float* __restrict__ ci,
                                                const float* __restrict__ w_fc,
                                                const float* __restrict__ b_fc,
                                                float* __restrict__ out, int nrows) {
    __shared__ float ws[kAgg * kOut];
    __shared__ float bs[kOut];
    const int lt = threadIdx.y * blockDim.x + threadIdx.x;
    for (int i = lt; i < kAgg * kOut; i += blockDim.x * blockDim.y)
        ws[i] = w_fc[i];
    if (lt < kOut) bs[lt] = b_fc[lt];
    __syncthreads();
    const int row = blockIdx.x * blockDim.y + threadIdx.y;
    if (row >= nrows) return;
    const int col = threadIdx.x;
    const float c = ci[row];
    const float* hr = h + (size_t)row * kAgg;
    float acc = bs[col];
#pragma unroll 8
    for (int k = 0; k < kAgg; ++k) {
        float a = hr[k] * c;
        a = (a >= 0.f) ? a : kSlope * a;
        acc += a * ws[k * kOut + col];
    }
    out[(size_t)row * kOut + col] = acc;
}

extern "C" void kernel_launch(void* const* d_in, const int* in_sizes, int n_in,
                              void* d_out, int out_size, void* d_ws, size_t ws_size,
                              hipStream_t stream) {
    const int*   drug_idx = (const int*)d_in[0];
    const int*   dis_idx  = (const int*)d_in[1];
    const int*   edge_src = (const int*)d_in[2];
    const int*   edge_dst = (const int*)d_in[3];
    const float* cj_drug  = (const float*)d_in[4];
    const float* ci_drug  = (const float*)d_in[5];
    const float* cj_dis   = (const float*)d_in[6];
    const float* ci_dis   = (const float*)d_in[7];
    const float* att      = (const float*)d_in[8];
    const float* basis    = (const float*)d_in[9];
    const float* w_fc     = (const float*)d_in[10];
    const float* b_fc     = (const float*)d_in[11];
    float* out = (float*)d_out;

    auto align256 = [](size_t x) { return (x + 255) & ~(size_t)255; };
    const size_t Wb    = align256((size_t)kR * kIn * kMsg * sizeof(float));     // 512 KB
    const size_t pkB   = align256((size_t)kNDrug * sizeof(uint4));              // 800 KB each
    const size_t bcB   = align256((size_t)kNBuck * sizeof(int));
    const size_t ocB   = align256(sizeof(int));
    const size_t oeB   = align256((size_t)kOvfCap * sizeof(unsigned));          // 16 KB
    const size_t obB   = align256((size_t)kOvfCap * sizeof(int));               // 16 KB
    const size_t binB  = align256((size_t)kNBuck * kSegCap * sizeof(unsigned)); // ~13.6 MB
    const size_t needBase = Wb + bcB + ocB + oeB + obB + binB;                  // ~14.2 MB
    const size_t needPk   = needBase + 2 * pkB;                                 // ~15.8 MB

    if (ws_size >= needPk) {
        char* p = (char*)d_ws;
        float*    W       = (float*)p;     p += Wb;
        uint4*    pk_drug = (uint4*)p;     p += pkB;
        uint4*    pk_dis  = (uint4*)p;     p += pkB;
        int*      bcur   = (int*)p;        p += bcB;
        int*      ovfCnt = (int*)p;        p += ocB;
        unsigned* ovfE   = (unsigned*)p;   p += oeB;
        int*      ovfB   = (int*)p;        p += obB;
        unsigned* bin    = (unsigned*)p;

        init_all<<<dim3(kWB + kPkBlk + kCurBlk), 256, 0, stream>>>(
            att, basis, drug_idx, dis_idx, cj_drug, cj_dis,
            W, pk_drug, pk_dis, bcur, ovfCnt);
        bin_pass<<<dim3(kBinBlocks), 1024, 0, stream>>>(edge_src, edge_dst,
                                                        bcur, bin, ovfCnt, ovfE, ovfB);
        gather_pk<<<dim3(kNBuck), 512, 0, stream>>>(bin, bcur, ovfCnt, ovfE, ovfB,
                                                    W, pk_drug, pk_dis,
                                                    ci_drug, ci_dis,
                                                    w_fc, b_fc, out);
    } else {
        // fallback: R1 phased atomic-scatter path
        char* p = (char*)d_ws;
        float* W = (float*)p;
        build_W_fb<<<dim3((kR * kIn * kMsg + 255) / 256), 256, 0, stream>>>(att, basis, W);
        const size_t hB = (size_t)kNDrug * kAgg * sizeof(float);
        float* h = (float*)((char*)d_ws + Wb);
        const int scat_blocks = (int)(((long)kE * 32 + 255) / 256);
        const dim3 scat_grid(scat_blocks, kR);
        hipMemsetAsync(h, 0, hB, stream);
        edge_scatter<<<scat_grid, 256, 0, stream>>>(W, edge_dst, edge_src,
                                                    dis_idx, cj_dis, h);
        fc_fused<<<dim3((kNDrug + 3) / 4), dim3(64, 4), 0, stream>>>(
            h, ci_drug, w_fc, b_fc, out, kNDrug);
        hipMemsetAsync(h, 0, hB, stream);
        edge_scatter<<<scat_grid, 256, 0, stream>>>(W, edge_src, edge_dst,
                                                    drug_idx, cj_drug, h);
        fc_fused<<<dim3((kNDis + 3) / 4), dim3(64, 4), 0, stream>>>(
            h, ci_dis, w_fc, b_fc, out + (size_t)kNDrug * kOut, kNDis);
    }
}